// Round 1
// baseline (5756.144 us; speedup 1.0000x reference)
//
#include <hip/hip_runtime.h>
#include <hip/hip_bf16.h>

// GINE 3-conv GNN, fused. N=100000 nodes, E=3200000 edges, H=16.
// All float inputs/outputs fp32; edge_index int32 (2 rows: src then dst).
// Workspace layout (needs ~128.4 MB):
//   agg  [N*16] f32, bsrc [N*32] f32 ({x_l | Pa}), bdst [N*16] f32 (Pc),
//   ebuf [E*16] bf16 (edge features between convs, in-place updated).

#define NN 100000
#define NE 3200000

__device__ __forceinline__ float bf2f(unsigned short h) {
    unsigned int u = ((unsigned int)h) << 16;
    float f; __builtin_memcpy(&f, &u, 4); return f;
}
__device__ __forceinline__ unsigned short f2bf(float f) {
    unsigned int u; __builtin_memcpy(&u, &f, 4);
    u += 0x7fffu + ((u >> 16) & 1u);          // RNE
    return (unsigned short)(u >> 16);
}

__device__ __forceinline__ void ld16(const float* __restrict__ p, float* r) {
    const float4* q = reinterpret_cast<const float4*>(p);
    float4 a = q[0], b = q[1], c = q[2], d = q[3];
    r[0]=a.x; r[1]=a.y; r[2]=a.z; r[3]=a.w;
    r[4]=b.x; r[5]=b.y; r[6]=b.z; r[7]=b.w;
    r[8]=c.x; r[9]=c.y; r[10]=c.z; r[11]=c.w;
    r[12]=d.x; r[13]=d.y; r[14]=d.z; r[15]=d.w;
}
__device__ __forceinline__ void st16(float* p, const float* r) {
    float4* q = reinterpret_cast<float4*>(p);
    q[0] = make_float4(r[0], r[1], r[2], r[3]);
    q[1] = make_float4(r[4], r[5], r[6], r[7]);
    q[2] = make_float4(r[8], r[9], r[10], r[11]);
    q[3] = make_float4(r[12], r[13], r[14], r[15]);
}
__device__ __forceinline__ void ldbf16x16(const unsigned short* p, float* r) {
    const uint4* q = reinterpret_cast<const uint4*>(p);
    uint4 a = q[0], b = q[1];
    unsigned int w[8] = {a.x, a.y, a.z, a.w, b.x, b.y, b.z, b.w};
    #pragma unroll
    for (int k = 0; k < 8; ++k) {
        r[2*k]   = bf2f((unsigned short)(w[k] & 0xffffu));
        r[2*k+1] = bf2f((unsigned short)(w[k] >> 16));
    }
}
__device__ __forceinline__ void stbf16x16(unsigned short* p, const float* r) {
    unsigned int w[8];
    #pragma unroll
    for (int k = 0; k < 8; ++k)
        w[k] = (unsigned int)f2bf(r[2*k]) | ((unsigned int)f2bf(r[2*k+1]) << 16);
    uint4* q = reinterpret_cast<uint4*>(p);
    q[0] = make_uint4(w[0], w[1], w[2], w[3]);
    q[1] = make_uint4(w[4], w[5], w[6], w[7]);
}

__global__ void kzero(float4* p, int n4) {
    int i = blockIdx.x * blockDim.x + threadIdx.x;
    if (i < n4) p[i] = make_float4(0.f, 0.f, 0.f, 0.f);
}

// conv1 prep: bsrc[n] = {x3 (cols 0..2), Pa = x3@ew1[0:3] (cols 16..31)}, bdst[n] = Pc = x3@ew1[6:9]
__global__ void prep1(const float* __restrict__ x, const float* __restrict__ ew1,
                      float* __restrict__ bsrc, float* __restrict__ bdst) {
    int n = blockIdx.x * blockDim.x + threadIdx.x;
    if (n >= NN) return;
    float x0 = x[3*n], x1 = x[3*n+1], x2 = x[3*n+2];
    bsrc[(size_t)n*32 + 0] = x0;
    bsrc[(size_t)n*32 + 1] = x1;
    bsrc[(size_t)n*32 + 2] = x2;
    float pa[16], pc[16];
    #pragma unroll
    for (int j = 0; j < 16; ++j) {
        pa[j] = x0*ew1[0*16+j] + x1*ew1[1*16+j] + x2*ew1[2*16+j];
        pc[j] = x0*ew1[6*16+j] + x1*ew1[7*16+j] + x2*ew1[8*16+j];
    }
    st16(bsrc + (size_t)n*32 + 16, pa);
    st16(bdst + (size_t)n*16, pc);
}

// conv1 edge: e in [E,3] fp32; h1 = relu(Pa[s]+Pc[t]+b1 + e@ew1[3:6]); h2 = relu(h1@ew2+b2) -> ebuf bf16
// msg = relu(xs3 + e3) scatter-added to agg[dst*16 + k], k<3
__global__ void conv1_edge(const int* __restrict__ ei, const float* __restrict__ ea,
                           const float* __restrict__ bsrc, const float* __restrict__ bdst,
                           const float* __restrict__ ew1, const float* __restrict__ eb1,
                           const float* __restrict__ ew2, const float* __restrict__ eb2,
                           unsigned short* __restrict__ ebuf, float* agg) {
    int e = blockIdx.x * blockDim.x + threadIdx.x;
    if (e >= NE) return;
    int s = ei[e], t = ei[NE + e];
    float e0 = ea[(size_t)3*e], e1 = ea[(size_t)3*e+1], e2 = ea[(size_t)3*e+2];
    const float* ps = bsrc + (size_t)s*32;
    float h[16];
    ld16(ps + 16, h);                       // Pa
    {
        float pc[16]; ld16(bdst + (size_t)t*16, pc);
        #pragma unroll
        for (int j = 0; j < 16; ++j)
            h[j] = h[j] + pc[j] + eb1[j]
                 + e0*ew1[3*16+j] + e1*ew1[4*16+j] + e2*ew1[5*16+j];
    }
    #pragma unroll
    for (int j = 0; j < 16; ++j) h[j] = fmaxf(h[j], 0.f);
    float h2[16];
    #pragma unroll
    for (int j = 0; j < 16; ++j) {
        float a = eb2[j];
        #pragma unroll
        for (int i = 0; i < 16; ++i) a = fmaf(h[i], ew2[i*16+j], a);
        h2[j] = fmaxf(a, 0.f);
    }
    stbf16x16(ebuf + (size_t)e*16, h2);
    float xs0 = ps[0], xs1 = ps[1], xs2 = ps[2];
    atomicAdd(&agg[(size_t)t*16 + 0], fmaxf(xs0 + e0, 0.f));
    atomicAdd(&agg[(size_t)t*16 + 1], fmaxf(xs1 + e1, 0.f));
    atomicAdd(&agg[(size_t)t*16 + 2], fmaxf(xs2 + e2, 0.f));
}

// conv2/3 edge. LAST=false: write new edge feats (in-place on ebuf is safe, own row).
// LAST=true: fuse edge head, write out_e[e*3..] directly.
template <bool LAST>
__global__ void conv_edge16(const int* __restrict__ ei, const unsigned short* __restrict__ ein_buf,
                            const float* __restrict__ bsrc, const float* __restrict__ bdst,
                            const float* __restrict__ ew1, const float* __restrict__ eb1,
                            const float* __restrict__ ew2, const float* __restrict__ eb2,
                            unsigned short* eout, float* agg,
                            const float* __restrict__ hw1, const float* __restrict__ hb1,
                            const float* __restrict__ hw2, const float* __restrict__ hb2,
                            float* __restrict__ out_e) {
    int e = blockIdx.x * blockDim.x + threadIdx.x;
    if (e >= NE) return;
    int s = ei[e], t = ei[NE + e];
    float ein[16];
    ldbf16x16(ein_buf + (size_t)e*16, ein);
    float h[16];
    ld16(bsrc + (size_t)s*32 + 16, h);      // Pa
    {
        float pc[16]; ld16(bdst + (size_t)t*16, pc);
        #pragma unroll
        for (int j = 0; j < 16; ++j) h[j] = h[j] + pc[j] + eb1[j];
    }
    #pragma unroll
    for (int i = 0; i < 16; ++i) {
        #pragma unroll
        for (int j = 0; j < 16; ++j) h[j] = fmaf(ein[i], ew1[(16+i)*16+j], h[j]);
    }
    #pragma unroll
    for (int j = 0; j < 16; ++j) h[j] = fmaxf(h[j], 0.f);
    float h2[16];
    #pragma unroll
    for (int j = 0; j < 16; ++j) {
        float a = eb2[j];
        #pragma unroll
        for (int i = 0; i < 16; ++i) a = fmaf(h[i], ew2[i*16+j], a);
        h2[j] = fmaxf(a, 0.f);
    }
    if (!LAST) {
        stbf16x16(eout + (size_t)e*16, h2);
    } else {
        float g[16];
        #pragma unroll
        for (int j = 0; j < 16; ++j) {
            float a = hb1[j];
            #pragma unroll
            for (int i = 0; i < 16; ++i) a = fmaf(h2[i], hw1[i*16+j], a);
            g[j] = fmaxf(a, 0.f);
        }
        #pragma unroll
        for (int k = 0; k < 3; ++k) {
            float a = hb2[k];
            #pragma unroll
            for (int i = 0; i < 16; ++i) a = fmaf(g[i], hw2[i*3+k], a);
            out_e[(size_t)e*3 + k] = a;
        }
    }
    float xs[16];
    ld16(bsrc + (size_t)s*32, xs);
    #pragma unroll
    for (int k = 0; k < 16; ++k)
        atomicAdd(&agg[(size_t)t*16 + k], fmaxf(xs[k] + ein[k], 0.f));
}

// conv1 node: out3 = agg[:3] + x3; node MLP (3->16->16, relu both); then prep for conv2:
// bsrc = {xn, xn@c2_ew1[0:16]}, bdst = xn@c2_ew1[32:48]
__global__ void conv1_node(const float* __restrict__ agg, const float* __restrict__ x,
                           const float* __restrict__ nw1, const float* __restrict__ nb1,
                           const float* __restrict__ nw2, const float* __restrict__ nb2,
                           const float* __restrict__ next_ew1,
                           float* __restrict__ bsrc, float* __restrict__ bdst) {
    int n = blockIdx.x * blockDim.x + threadIdx.x;
    if (n >= NN) return;
    float o0 = agg[(size_t)n*16+0] + x[3*n];
    float o1 = agg[(size_t)n*16+1] + x[3*n+1];
    float o2 = agg[(size_t)n*16+2] + x[3*n+2];
    float h[16];
    #pragma unroll
    for (int j = 0; j < 16; ++j) {
        float a = nb1[j] + o0*nw1[0*16+j] + o1*nw1[1*16+j] + o2*nw1[2*16+j];
        h[j] = fmaxf(a, 0.f);
    }
    float xn[16];
    #pragma unroll
    for (int j = 0; j < 16; ++j) {
        float a = nb2[j];
        #pragma unroll
        for (int i = 0; i < 16; ++i) a = fmaf(h[i], nw2[i*16+j], a);
        xn[j] = fmaxf(a, 0.f);
    }
    float pa[16], pc[16];
    #pragma unroll
    for (int j = 0; j < 16; ++j) {
        float sa = 0.f, sc = 0.f;
        #pragma unroll
        for (int i = 0; i < 16; ++i) {
            sa = fmaf(xn[i], next_ew1[i*16+j], sa);
            sc = fmaf(xn[i], next_ew1[(32+i)*16+j], sc);
        }
        pa[j] = sa; pc[j] = sc;
    }
    st16(bsrc + (size_t)n*32, xn);
    st16(bsrc + (size_t)n*32 + 16, pa);
    st16(bdst + (size_t)n*16, pc);
}

// conv2 node: out = agg + xn_prev (bsrc cols 0..15); node MLP; prep for conv3.
__global__ void node_mid(const float* __restrict__ agg,
                         const float* __restrict__ nw1, const float* __restrict__ nb1,
                         const float* __restrict__ nw2, const float* __restrict__ nb2,
                         const float* __restrict__ next_ew1,
                         float* bsrc, float* __restrict__ bdst) {
    int n = blockIdx.x * blockDim.x + threadIdx.x;
    if (n >= NN) return;
    float o[16];
    ld16(bsrc + (size_t)n*32, o);
    {
        float a[16]; ld16(agg + (size_t)n*16, a);
        #pragma unroll
        for (int j = 0; j < 16; ++j) o[j] += a[j];
    }
    float h[16];
    #pragma unroll
    for (int j = 0; j < 16; ++j) {
        float a = nb1[j];
        #pragma unroll
        for (int i = 0; i < 16; ++i) a = fmaf(o[i], nw1[i*16+j], a);
        h[j] = fmaxf(a, 0.f);
    }
    float xn[16];
    #pragma unroll
    for (int j = 0; j < 16; ++j) {
        float a = nb2[j];
        #pragma unroll
        for (int i = 0; i < 16; ++i) a = fmaf(h[i], nw2[i*16+j], a);
        xn[j] = fmaxf(a, 0.f);
    }
    float pa[16], pc[16];
    #pragma unroll
    for (int j = 0; j < 16; ++j) {
        float sa = 0.f, sc = 0.f;
        #pragma unroll
        for (int i = 0; i < 16; ++i) {
            sa = fmaf(xn[i], next_ew1[i*16+j], sa);
            sc = fmaf(xn[i], next_ew1[(32+i)*16+j], sc);
        }
        pa[j] = sa; pc[j] = sc;
    }
    st16(bsrc + (size_t)n*32, xn);
    st16(bsrc + (size_t)n*32 + 16, pa);
    st16(bdst + (size_t)n*16, pc);
}

// conv3 node: out = agg + xn_prev; node MLP; fused node head (16->16 relu ->3) -> d_out nodes.
__global__ void node_last(const float* __restrict__ agg, const float* __restrict__ bsrc,
                          const float* __restrict__ nw1, const float* __restrict__ nb1,
                          const float* __restrict__ nw2, const float* __restrict__ nb2,
                          const float* __restrict__ hw1, const float* __restrict__ hb1,
                          const float* __restrict__ hw2, const float* __restrict__ hb2,
                          float* __restrict__ out_n) {
    int n = blockIdx.x * blockDim.x + threadIdx.x;
    if (n >= NN) return;
    float o[16];
    ld16(bsrc + (size_t)n*32, o);
    {
        float a[16]; ld16(agg + (size_t)n*16, a);
        #pragma unroll
        for (int j = 0; j < 16; ++j) o[j] += a[j];
    }
    float h[16];
    #pragma unroll
    for (int j = 0; j < 16; ++j) {
        float a = nb1[j];
        #pragma unroll
        for (int i = 0; i < 16; ++i) a = fmaf(o[i], nw1[i*16+j], a);
        h[j] = fmaxf(a, 0.f);
    }
    float xn[16];
    #pragma unroll
    for (int j = 0; j < 16; ++j) {
        float a = nb2[j];
        #pragma unroll
        for (int i = 0; i < 16; ++i) a = fmaf(h[i], nw2[i*16+j], a);
        xn[j] = fmaxf(a, 0.f);
    }
    float g[16];
    #pragma unroll
    for (int j = 0; j < 16; ++j) {
        float a = hb1[j];
        #pragma unroll
        for (int i = 0; i < 16; ++i) a = fmaf(xn[i], hw1[i*16+j], a);
        g[j] = fmaxf(a, 0.f);
    }
    #pragma unroll
    for (int k = 0; k < 3; ++k) {
        float a = hb2[k];
        #pragma unroll
        for (int i = 0; i < 16; ++i) a = fmaf(g[i], hw2[i*3+k], a);
        out_n[(size_t)n*3 + k] = a;
    }
}

extern "C" void kernel_launch(void* const* d_in, const int* in_sizes, int n_in,
                              void* d_out, int out_size, void* d_ws, size_t ws_size,
                              hipStream_t stream) {
    const float* x  = (const float*)d_in[0];
    const float* ea = (const float*)d_in[1];
    const int*   ei = (const int*)d_in[2];
    const float *c1_ew1 = (const float*)d_in[3],  *c1_eb1 = (const float*)d_in[4];
    const float *c1_ew2 = (const float*)d_in[5],  *c1_eb2 = (const float*)d_in[6];
    const float *c1_nw1 = (const float*)d_in[7],  *c1_nb1 = (const float*)d_in[8];
    const float *c1_nw2 = (const float*)d_in[9],  *c1_nb2 = (const float*)d_in[10];
    const float *c2_ew1 = (const float*)d_in[11], *c2_eb1 = (const float*)d_in[12];
    const float *c2_ew2 = (const float*)d_in[13], *c2_eb2 = (const float*)d_in[14];
    const float *c2_nw1 = (const float*)d_in[15], *c2_nb1 = (const float*)d_in[16];
    const float *c2_nw2 = (const float*)d_in[17], *c2_nb2 = (const float*)d_in[18];
    const float *c3_ew1 = (const float*)d_in[19], *c3_eb1 = (const float*)d_in[20];
    const float *c3_ew2 = (const float*)d_in[21], *c3_eb2 = (const float*)d_in[22];
    const float *c3_nw1 = (const float*)d_in[23], *c3_nb1 = (const float*)d_in[24];
    const float *c3_nw2 = (const float*)d_in[25], *c3_nb2 = (const float*)d_in[26];
    const float *node_w1 = (const float*)d_in[27], *node_b1 = (const float*)d_in[28];
    const float *node_w2 = (const float*)d_in[29], *node_b2 = (const float*)d_in[30];
    const float *edge_w1 = (const float*)d_in[31], *edge_b1 = (const float*)d_in[32];
    const float *edge_w2 = (const float*)d_in[33], *edge_b2 = (const float*)d_in[34];

    float* ws   = (float*)d_ws;
    float* agg  = ws;                                   // N*16 f32
    float* bsrc = agg  + (size_t)NN * 16;               // N*32 f32
    float* bdst = bsrc + (size_t)NN * 32;               // N*16 f32
    unsigned short* ebuf = (unsigned short*)(bdst + (size_t)NN * 16);  // E*16 bf16

    float* out_n = (float*)d_out;                       // N*3
    float* out_e = out_n + (size_t)NN * 3;              // E*3

    const int B = 256;
    const int gz = (NN * 16 / 4 + B - 1) / B;   // zero kernel (float4)
    const int gn = (NN + B - 1) / B;
    const int ge = (NE + B - 1) / B;            // exact: 12500

    // conv1
    kzero<<<gz, B, 0, stream>>>((float4*)agg, NN * 16 / 4);
    prep1<<<gn, B, 0, stream>>>(x, c1_ew1, bsrc, bdst);
    conv1_edge<<<ge, B, 0, stream>>>(ei, ea, bsrc, bdst,
                                     c1_ew1, c1_eb1, c1_ew2, c1_eb2, ebuf, agg);
    conv1_node<<<gn, B, 0, stream>>>(agg, x, c1_nw1, c1_nb1, c1_nw2, c1_nb2,
                                     c2_ew1, bsrc, bdst);
    // conv2
    kzero<<<gz, B, 0, stream>>>((float4*)agg, NN * 16 / 4);
    conv_edge16<false><<<ge, B, 0, stream>>>(ei, ebuf, bsrc, bdst,
                                             c2_ew1, c2_eb1, c2_ew2, c2_eb2, ebuf, agg,
                                             nullptr, nullptr, nullptr, nullptr, nullptr);
    node_mid<<<gn, B, 0, stream>>>(agg, c2_nw1, c2_nb1, c2_nw2, c2_nb2,
                                   c3_ew1, bsrc, bdst);
    // conv3 (heads fused)
    kzero<<<gz, B, 0, stream>>>((float4*)agg, NN * 16 / 4);
    conv_edge16<true><<<ge, B, 0, stream>>>(ei, ebuf, bsrc, bdst,
                                            c3_ew1, c3_eb1, c3_ew2, c3_eb2, nullptr, agg,
                                            edge_w1, edge_b1, edge_w2, edge_b2, out_e);
    node_last<<<gn, B, 0, stream>>>(agg, bsrc, c3_nw1, c3_nb1, c3_nw2, c3_nb2,
                                    node_w1, node_b1, node_w2, node_b2, out_n);
}

// Round 2
// 1281.026 us; speedup vs baseline: 4.4934x; 4.4934x over previous
//
#include <hip/hip_runtime.h>
#include <hip/hip_bf16.h>

// GINE 3-conv GNN. Atomic-free aggregation via per-call CSR (dst-sorted adjacency).
// N=100000, E=3200000, H=16. fp32 in/out; edge_index int32 rows [src | dst].
//
// ws layout (125.6 MB total, proven ws_size >= 128 MB):
//   ebuf  [E][16] bf16   edge features between convs (in-place updated)
//   adj   [E] int        CSR edge ids grouped by dst
//   start [N+1] int      CSR offsets
//   cursor[N+1] int      (aliases former deg) histogram + scatter cursors
//   Pa,Pc [N][16] bf16   per-node projections x@W1_src / x@W1_dst for next conv
//   xnbf  [N][16] bf16   current node features (for msg gather)
//   bsum  [256] int      scan partials
// agg [N][16] f32 lives in d_out's edge region (overwritten last by conv3_edge).

#define NN 100000
#define NE 3200000
#define SCAN_B 512
#define NB_SCAN ((NN + SCAN_B - 1) / SCAN_B)   // 196

__device__ __forceinline__ float bf2f(unsigned int h) {
    unsigned int u = h << 16;
    float f; __builtin_memcpy(&f, &u, 4); return f;
}
__device__ __forceinline__ unsigned short f2bf(float f) {
    unsigned int u; __builtin_memcpy(&u, &f, 4);
    u += 0x7fffu + ((u >> 16) & 1u);          // RNE
    return (unsigned short)(u >> 16);
}
__device__ __forceinline__ void ldbf16x16(const unsigned short* p, float* r) {
    const uint4* q = reinterpret_cast<const uint4*>(p);
    uint4 a = q[0], b = q[1];
    unsigned int w[8] = {a.x, a.y, a.z, a.w, b.x, b.y, b.z, b.w};
    #pragma unroll
    for (int k = 0; k < 8; ++k) {
        r[2*k]   = bf2f(w[k] & 0xffffu);
        r[2*k+1] = bf2f(w[k] >> 16);
    }
}
__device__ __forceinline__ void stbf16x16(unsigned short* p, const float* r) {
    unsigned int w[8];
    #pragma unroll
    for (int k = 0; k < 8; ++k)
        w[k] = (unsigned int)f2bf(r[2*k]) | ((unsigned int)f2bf(r[2*k+1]) << 16);
    uint4* q = reinterpret_cast<uint4*>(p);
    q[0] = make_uint4(w[0], w[1], w[2], w[3]);
    q[1] = make_uint4(w[4], w[5], w[6], w[7]);
}

// ---------------- CSR build ----------------

__global__ void kz_int(int* p, int n) {
    int i = blockIdx.x * blockDim.x + threadIdx.x;
    if (i < n) p[i] = 0;
}

__global__ void khist(const int* __restrict__ ei, int* deg) {
    int e = blockIdx.x * blockDim.x + threadIdx.x;
    if (e < NE) atomicAdd(&deg[ei[NE + e]], 1);
}

// per-block inclusive scan of deg -> start[i+1]; block totals -> bsum[b]
__global__ void kscan1(const int* __restrict__ deg, int* __restrict__ start, int* __restrict__ bsum) {
    int t = threadIdx.x, b = blockIdx.x;
    int i = b * SCAN_B + t;
    int v = (i < NN) ? deg[i] : 0;
    int lane = t & 63, wid = t >> 6;
    #pragma unroll
    for (int off = 1; off < 64; off <<= 1) {
        int u = __shfl_up(v, off);
        if (lane >= off) v += u;
    }
    __shared__ int wsum[8];
    if (lane == 63) wsum[wid] = v;
    __syncthreads();
    if (t < 8) {
        int w = wsum[t];
        #pragma unroll
        for (int off = 1; off < 8; off <<= 1) {
            int u = __shfl_up(w, off);
            if (t >= off) w += u;
        }
        wsum[t] = w;
    }
    __syncthreads();
    if (wid > 0) v += wsum[wid - 1];
    if (i < NN) start[i + 1] = v;
    if (t == SCAN_B - 1) bsum[b] = v;
}

// inclusive scan of bsum[NB_SCAN] in one block of 256
__global__ void kscan2(int* bsum) {
    __shared__ int s[256];
    int t = threadIdx.x;
    s[t] = (t < NB_SCAN) ? bsum[t] : 0;
    __syncthreads();
    for (int off = 1; off < 256; off <<= 1) {
        int u = (t >= off) ? s[t - off] : 0;
        __syncthreads();
        s[t] += u;
        __syncthreads();
    }
    if (t < NB_SCAN) bsum[t] = s[t];
}

// add block offsets; init cursor = final start
__global__ void kscan3(int* __restrict__ start, const int* __restrict__ bsum, int* __restrict__ cursor) {
    int i = blockIdx.x * blockDim.x + threadIdx.x;
    if (i >= NN) return;
    int b = i >> 9;                 // SCAN_B = 512
    int off = (b > 0) ? bsum[b - 1] : 0;
    int v = start[i + 1] + off;
    start[i + 1] = v;
    cursor[i + 1] = v;
    if (i == 0) { start[0] = 0; cursor[0] = 0; }
}

__global__ void kscatter(const int* __restrict__ ei, int* cursor, int* __restrict__ adj) {
    int e = blockIdx.x * blockDim.x + threadIdx.x;
    if (e >= NE) return;
    int d = ei[NE + e];
    int pos = atomicAdd(&cursor[d], 1);
    adj[pos] = e;
}

// ---------------- conv kernels ----------------

// Pa1 = x3 @ ew1[0:3], Pc1 = x3 @ ew1[6:9]   (bf16 rows)
__global__ void prep1(const float* __restrict__ x, const float* __restrict__ ew1,
                      unsigned short* __restrict__ Pa, unsigned short* __restrict__ Pc) {
    int n = blockIdx.x * blockDim.x + threadIdx.x;
    if (n >= NN) return;
    float x0 = x[3*n], x1 = x[3*n+1], x2 = x[3*n+2];
    float pa[16], pc[16];
    #pragma unroll
    for (int j = 0; j < 16; ++j) {
        pa[j] = x0*ew1[0*16+j] + x1*ew1[1*16+j] + x2*ew1[2*16+j];
        pc[j] = x0*ew1[6*16+j] + x1*ew1[7*16+j] + x2*ew1[8*16+j];
    }
    stbf16x16(Pa + (size_t)n*16, pa);
    stbf16x16(Pc + (size_t)n*16, pc);
}

// conv1 aggregation: agg3[n] = sum_{e->n} relu(x[src]+ea[e])   (gather, no atomics)
__global__ void kagg3(const int* __restrict__ adj, const int* __restrict__ start,
                      const int* __restrict__ ei, const float* __restrict__ x,
                      const float* __restrict__ ea, float* __restrict__ agg) {
    int n = blockIdx.x * blockDim.x + threadIdx.x;
    if (n >= NN) return;
    int j0 = start[n], j1 = start[n+1];
    float a0 = 0.f, a1 = 0.f, a2 = 0.f;
    for (int j = j0; j < j1; ++j) {
        int e = adj[j];
        int s = ei[e];
        a0 += fmaxf(x[3*s  ] + ea[(size_t)3*e  ], 0.f);
        a1 += fmaxf(x[3*s+1] + ea[(size_t)3*e+1], 0.f);
        a2 += fmaxf(x[3*s+2] + ea[(size_t)3*e+2], 0.f);
    }
    float* p = agg + (size_t)n*16;
    p[0] = a0; p[1] = a1; p[2] = a2;
}

// conv2/3 aggregation: 4 threads per node, 4 dims each. agg[n] = sum relu(xn[src]+ein[e])
__global__ void kagg16(const int* __restrict__ adj, const int* __restrict__ start,
                       const int* __restrict__ ei, const unsigned short* __restrict__ ebuf,
                       const unsigned short* __restrict__ xnbf, float* __restrict__ agg) {
    int t = blockIdx.x * blockDim.x + threadIdx.x;
    int n = t >> 2, q = t & 3;
    if (n >= NN) return;
    int j0 = start[n], j1 = start[n+1];
    float a0 = 0.f, a1 = 0.f, a2 = 0.f, a3 = 0.f;
    for (int j = j0; j < j1; ++j) {
        int e = adj[j];
        int s = ei[e];
        uint2 w  = *reinterpret_cast<const uint2*>(ebuf + (size_t)e*16 + q*4);
        uint2 xw = *reinterpret_cast<const uint2*>(xnbf + (size_t)s*16 + q*4);
        a0 += fmaxf(bf2f(xw.x & 0xffffu) + bf2f(w.x & 0xffffu), 0.f);
        a1 += fmaxf(bf2f(xw.x >> 16)     + bf2f(w.x >> 16),     0.f);
        a2 += fmaxf(bf2f(xw.y & 0xffffu) + bf2f(w.y & 0xffffu), 0.f);
        a3 += fmaxf(bf2f(xw.y >> 16)     + bf2f(w.y >> 16),     0.f);
    }
    *reinterpret_cast<float4*>(agg + (size_t)n*16 + q*4) = make_float4(a0, a1, a2, a3);
}

// conv1 edge MLP: h=relu(Pa[s]+Pc[t]+b1+ea@W1mid); ebuf = relu(h@W2+b2)
__global__ void conv1_edge(const int* __restrict__ ei, const float* __restrict__ ea,
                           const unsigned short* __restrict__ Pa, const unsigned short* __restrict__ Pc,
                           const float* __restrict__ ew1, const float* __restrict__ eb1,
                           const float* __restrict__ ew2, const float* __restrict__ eb2,
                           unsigned short* __restrict__ ebuf) {
    int e = blockIdx.x * blockDim.x + threadIdx.x;
    if (e >= NE) return;
    int s = ei[e], t = ei[NE + e];
    float e0 = ea[(size_t)3*e], e1 = ea[(size_t)3*e+1], e2 = ea[(size_t)3*e+2];
    float h[16], pc[16];
    ldbf16x16(Pa + (size_t)s*16, h);
    ldbf16x16(Pc + (size_t)t*16, pc);
    #pragma unroll
    for (int j = 0; j < 16; ++j) {
        float a = h[j] + pc[j] + eb1[j]
                + e0*ew1[3*16+j] + e1*ew1[4*16+j] + e2*ew1[5*16+j];
        h[j] = fmaxf(a, 0.f);
    }
    float h2[16];
    #pragma unroll
    for (int j = 0; j < 16; ++j) {
        float a = eb2[j];
        #pragma unroll
        for (int i = 0; i < 16; ++i) a = fmaf(h[i], ew2[i*16+j], a);
        h2[j] = fmaxf(a, 0.f);
    }
    stbf16x16(ebuf + (size_t)e*16, h2);
}

// conv2/3 edge MLP. LAST=false: ebuf updated in place. LAST=true: fused edge head -> out_e.
template <bool LAST>
__global__ void conv_edge16(const int* __restrict__ ei, const unsigned short* __restrict__ ebuf_in,
                            const unsigned short* __restrict__ Pa, const unsigned short* __restrict__ Pc,
                            const float* __restrict__ ew1, const float* __restrict__ eb1,
                            const float* __restrict__ ew2, const float* __restrict__ eb2,
                            unsigned short* ebuf_out,
                            const float* __restrict__ hw1, const float* __restrict__ hb1,
                            const float* __restrict__ hw2, const float* __restrict__ hb2,
                            float* __restrict__ out_e) {
    int e = blockIdx.x * blockDim.x + threadIdx.x;
    if (e >= NE) return;
    int s = ei[e], t = ei[NE + e];
    float ein[16], h[16], pc[16];
    ldbf16x16(ebuf_in + (size_t)e*16, ein);
    ldbf16x16(Pa + (size_t)s*16, h);
    ldbf16x16(Pc + (size_t)t*16, pc);
    #pragma unroll
    for (int j = 0; j < 16; ++j) h[j] = h[j] + pc[j] + eb1[j];
    #pragma unroll
    for (int i = 0; i < 16; ++i) {
        #pragma unroll
        for (int j = 0; j < 16; ++j) h[j] = fmaf(ein[i], ew1[(16+i)*16+j], h[j]);
    }
    #pragma unroll
    for (int j = 0; j < 16; ++j) h[j] = fmaxf(h[j], 0.f);
    float h2[16];
    #pragma unroll
    for (int j = 0; j < 16; ++j) {
        float a = eb2[j];
        #pragma unroll
        for (int i = 0; i < 16; ++i) a = fmaf(h[i], ew2[i*16+j], a);
        h2[j] = fmaxf(a, 0.f);
    }
    if (!LAST) {
        stbf16x16(ebuf_out + (size_t)e*16, h2);
    } else {
        float g[16];
        #pragma unroll
        for (int j = 0; j < 16; ++j) {
            float a = hb1[j];
            #pragma unroll
            for (int i = 0; i < 16; ++i) a = fmaf(h2[i], hw1[i*16+j], a);
            g[j] = fmaxf(a, 0.f);
        }
        #pragma unroll
        for (int k = 0; k < 3; ++k) {
            float a = hb2[k];
            #pragma unroll
            for (int i = 0; i < 16; ++i) a = fmaf(g[i], hw2[i*3+k], a);
            out_e[(size_t)e*3 + k] = a;
        }
    }
}

// conv1 node MLP (+ prep for conv2)
__global__ void conv1_node(const float* __restrict__ agg, const float* __restrict__ x,
                           const float* __restrict__ nw1, const float* __restrict__ nb1,
                           const float* __restrict__ nw2, const float* __restrict__ nb2,
                           const float* __restrict__ next_ew1,
                           unsigned short* __restrict__ Pa, unsigned short* __restrict__ Pc,
                           unsigned short* __restrict__ xnbf) {
    int n = blockIdx.x * blockDim.x + threadIdx.x;
    if (n >= NN) return;
    float o0 = agg[(size_t)n*16+0] + x[3*n];
    float o1 = agg[(size_t)n*16+1] + x[3*n+1];
    float o2 = agg[(size_t)n*16+2] + x[3*n+2];
    float h[16];
    #pragma unroll
    for (int j = 0; j < 16; ++j)
        h[j] = fmaxf(nb1[j] + o0*nw1[0*16+j] + o1*nw1[1*16+j] + o2*nw1[2*16+j], 0.f);
    float xn[16];
    #pragma unroll
    for (int j = 0; j < 16; ++j) {
        float a = nb2[j];
        #pragma unroll
        for (int i = 0; i < 16; ++i) a = fmaf(h[i], nw2[i*16+j], a);
        xn[j] = fmaxf(a, 0.f);
    }
    float pa[16], pc[16];
    #pragma unroll
    for (int j = 0; j < 16; ++j) {
        float sa = 0.f, sc = 0.f;
        #pragma unroll
        for (int i = 0; i < 16; ++i) {
            sa = fmaf(xn[i], next_ew1[i*16+j], sa);
            sc = fmaf(xn[i], next_ew1[(32+i)*16+j], sc);
        }
        pa[j] = sa; pc[j] = sc;
    }
    stbf16x16(xnbf + (size_t)n*16, xn);
    stbf16x16(Pa + (size_t)n*16, pa);
    stbf16x16(Pc + (size_t)n*16, pc);
}

// conv2 node MLP (+ prep for conv3). Reads/writes own xnbf row only (safe in place).
__global__ void node_mid(const float* __restrict__ agg,
                         const float* __restrict__ nw1, const float* __restrict__ nb1,
                         const float* __restrict__ nw2, const float* __restrict__ nb2,
                         const float* __restrict__ next_ew1,
                         unsigned short* __restrict__ Pa, unsigned short* __restrict__ Pc,
                         unsigned short* xnbf) {
    int n = blockIdx.x * blockDim.x + threadIdx.x;
    if (n >= NN) return;
    float o[16];
    ldbf16x16(xnbf + (size_t)n*16, o);
    #pragma unroll
    for (int j = 0; j < 16; ++j) o[j] += agg[(size_t)n*16 + j];
    float h[16];
    #pragma unroll
    for (int j = 0; j < 16; ++j) {
        float a = nb1[j];
        #pragma unroll
        for (int i = 0; i < 16; ++i) a = fmaf(o[i], nw1[i*16+j], a);
        h[j] = fmaxf(a, 0.f);
    }
    float xn[16];
    #pragma unroll
    for (int j = 0; j < 16; ++j) {
        float a = nb2[j];
        #pragma unroll
        for (int i = 0; i < 16; ++i) a = fmaf(h[i], nw2[i*16+j], a);
        xn[j] = fmaxf(a, 0.f);
    }
    float pa[16], pc[16];
    #pragma unroll
    for (int j = 0; j < 16; ++j) {
        float sa = 0.f, sc = 0.f;
        #pragma unroll
        for (int i = 0; i < 16; ++i) {
            sa = fmaf(xn[i], next_ew1[i*16+j], sa);
            sc = fmaf(xn[i], next_ew1[(32+i)*16+j], sc);
        }
        pa[j] = sa; pc[j] = sc;
    }
    stbf16x16(xnbf + (size_t)n*16, xn);
    stbf16x16(Pa + (size_t)n*16, pa);
    stbf16x16(Pc + (size_t)n*16, pc);
}

// conv3 node MLP + node head -> out_n
__global__ void node_last(const float* __restrict__ agg, const unsigned short* __restrict__ xnbf,
                          const float* __restrict__ nw1, const float* __restrict__ nb1,
                          const float* __restrict__ nw2, const float* __restrict__ nb2,
                          const float* __restrict__ hw1, const float* __restrict__ hb1,
                          const float* __restrict__ hw2, const float* __restrict__ hb2,
                          float* __restrict__ out_n) {
    int n = blockIdx.x * blockDim.x + threadIdx.x;
    if (n >= NN) return;
    float o[16];
    ldbf16x16(xnbf + (size_t)n*16, o);
    #pragma unroll
    for (int j = 0; j < 16; ++j) o[j] += agg[(size_t)n*16 + j];
    float h[16];
    #pragma unroll
    for (int j = 0; j < 16; ++j) {
        float a = nb1[j];
        #pragma unroll
        for (int i = 0; i < 16; ++i) a = fmaf(o[i], nw1[i*16+j], a);
        h[j] = fmaxf(a, 0.f);
    }
    float xn[16];
    #pragma unroll
    for (int j = 0; j < 16; ++j) {
        float a = nb2[j];
        #pragma unroll
        for (int i = 0; i < 16; ++i) a = fmaf(h[i], nw2[i*16+j], a);
        xn[j] = fmaxf(a, 0.f);
    }
    float g[16];
    #pragma unroll
    for (int j = 0; j < 16; ++j) {
        float a = hb1[j];
        #pragma unroll
        for (int i = 0; i < 16; ++i) a = fmaf(xn[i], hw1[i*16+j], a);
        g[j] = fmaxf(a, 0.f);
    }
    #pragma unroll
    for (int k = 0; k < 3; ++k) {
        float a = hb2[k];
        #pragma unroll
        for (int i = 0; i < 16; ++i) a = fmaf(g[i], hw2[i*3+k], a);
        out_n[(size_t)n*3 + k] = a;
    }
}

extern "C" void kernel_launch(void* const* d_in, const int* in_sizes, int n_in,
                              void* d_out, int out_size, void* d_ws, size_t ws_size,
                              hipStream_t stream) {
    const float* x  = (const float*)d_in[0];
    const float* ea = (const float*)d_in[1];
    const int*   ei = (const int*)d_in[2];
    const float *c1_ew1 = (const float*)d_in[3],  *c1_eb1 = (const float*)d_in[4];
    const float *c1_ew2 = (const float*)d_in[5],  *c1_eb2 = (const float*)d_in[6];
    const float *c1_nw1 = (const float*)d_in[7],  *c1_nb1 = (const float*)d_in[8];
    const float *c1_nw2 = (const float*)d_in[9],  *c1_nb2 = (const float*)d_in[10];
    const float *c2_ew1 = (const float*)d_in[11], *c2_eb1 = (const float*)d_in[12];
    const float *c2_ew2 = (const float*)d_in[13], *c2_eb2 = (const float*)d_in[14];
    const float *c2_nw1 = (const float*)d_in[15], *c2_nb1 = (const float*)d_in[16];
    const float *c2_nw2 = (const float*)d_in[17], *c2_nb2 = (const float*)d_in[18];
    const float *c3_ew1 = (const float*)d_in[19], *c3_eb1 = (const float*)d_in[20];
    const float *c3_ew2 = (const float*)d_in[21], *c3_eb2 = (const float*)d_in[22];
    const float *c3_nw1 = (const float*)d_in[23], *c3_nb1 = (const float*)d_in[24];
    const float *c3_nw2 = (const float*)d_in[25], *c3_nb2 = (const float*)d_in[26];
    const float *node_w1 = (const float*)d_in[27], *node_b1 = (const float*)d_in[28];
    const float *node_w2 = (const float*)d_in[29], *node_b2 = (const float*)d_in[30];
    const float *edge_w1 = (const float*)d_in[31], *edge_b1 = (const float*)d_in[32];
    const float *edge_w2 = (const float*)d_in[33], *edge_b2 = (const float*)d_in[34];

    // ws carve-up (64B-aligned chunks)
    char* w = (char*)d_ws;
    unsigned short* ebuf = (unsigned short*)w;            w += (size_t)NE * 16 * 2;          // 102.4 MB
    int* adj    = (int*)w;                                w += (size_t)NE * 4;               // 12.8 MB
    int* start  = (int*)w;                                w += ((size_t)(NN + 1) * 4 + 63) & ~63ull;
    int* cursor = (int*)w;                                w += ((size_t)(NN + 1) * 4 + 63) & ~63ull;
    unsigned short* Pa   = (unsigned short*)w;            w += (size_t)NN * 16 * 2;          // 3.2 MB
    unsigned short* Pc   = (unsigned short*)w;            w += (size_t)NN * 16 * 2;
    unsigned short* xnbf = (unsigned short*)w;            w += (size_t)NN * 16 * 2;
    int* bsum = (int*)w;                                  w += 256 * 4;

    float* out_n = (float*)d_out;                         // N*3
    float* out_e = out_n + (size_t)NN * 3;                // E*3
    float* agg   = out_e;                                 // N*16 f32 scratch inside edge-out region

    const int B = 256;
    const int gn  = (NN + B - 1) / B;            // 391
    const int gn1 = (NN + 1 + B - 1) / B;        // 392
    const int ge  = (NE + B - 1) / B;            // 12500
    const int gq  = (NN * 4 + B - 1) / B;        // 1563

    // --- CSR build (deterministic set; intra-segment order is atomic-race but only
    //     perturbs fp summation order, ~1e-6) ---
    kz_int<<<gn1, B, 0, stream>>>(cursor, NN + 1);       // cursor doubles as deg
    khist<<<ge, B, 0, stream>>>(ei, cursor);
    kscan1<<<NB_SCAN, SCAN_B, 0, stream>>>(cursor, start, bsum);
    kscan2<<<1, 256, 0, stream>>>(bsum);
    kscan3<<<gn, B, 0, stream>>>(start, bsum, cursor);   // finalizes start, re-inits cursor
    kscatter<<<ge, B, 0, stream>>>(ei, cursor, adj);

    // --- conv1 ---
    prep1<<<gn, B, 0, stream>>>(x, c1_ew1, Pa, Pc);
    kagg3<<<gn, B, 0, stream>>>(adj, start, ei, x, ea, agg);
    conv1_edge<<<ge, B, 0, stream>>>(ei, ea, Pa, Pc, c1_ew1, c1_eb1, c1_ew2, c1_eb2, ebuf);
    conv1_node<<<gn, B, 0, stream>>>(agg, x, c1_nw1, c1_nb1, c1_nw2, c1_nb2,
                                     c2_ew1, Pa, Pc, xnbf);

    // --- conv2 (agg reads old ebuf BEFORE edge kernel overwrites it) ---
    kagg16<<<gq, B, 0, stream>>>(adj, start, ei, ebuf, xnbf, agg);
    conv_edge16<false><<<ge, B, 0, stream>>>(ei, ebuf, Pa, Pc,
                                             c2_ew1, c2_eb1, c2_ew2, c2_eb2, ebuf,
                                             nullptr, nullptr, nullptr, nullptr, nullptr);
    node_mid<<<gn, B, 0, stream>>>(agg, c2_nw1, c2_nb1, c2_nw2, c2_nb2,
                                   c3_ew1, Pa, Pc, xnbf);

    // --- conv3 (agg scratch lives in out_e region: node kernel consumes it, then
    //     the edge kernel overwrites the whole region with real outputs) ---
    kagg16<<<gq, B, 0, stream>>>(adj, start, ei, ebuf, xnbf, agg);
    node_last<<<gn, B, 0, stream>>>(agg, xnbf, c3_nw1, c3_nb1, c3_nw2, c3_nb2,
                                    node_w1, node_b1, node_w2, node_b2, out_n);
    conv_edge16<true><<<ge, B, 0, stream>>>(ei, ebuf, Pa, Pc,
                                            c3_ew1, c3_eb1, c3_ew2, c3_eb2, nullptr,
                                            edge_w1, edge_b1, edge_w2, edge_b2, out_e);
}

// Round 3
// 1013.486 us; speedup vs baseline: 5.6795x; 1.2640x over previous
//
#include <hip/hip_runtime.h>
#include <hip/hip_bf16.h>

// GINE 3-conv GNN. Atomic-light aggregation via per-node linked lists
// (head[n] -> chain over next[e]), rebuilt per call (deterministic inputs).
// N=100000, E=3200000, H=16. fp32 in/out; edge_index int32 rows [src | dst].
//
// ws layout (~125.2 MB):
//   ebuf [E][16] bf16   edge features between convs (in-place updated)  102.4 MB
//   next [E] int        linked-list next pointers (coalesced writes)     12.8 MB
//   head [N] int        list heads (atomicExch target, 0.4 MB L2-hot)
//   Pa,Pc [N][16] bf16  per-node projections for next conv's edge MLP
//   xnbf [N][16] bf16   current node features (for msg gather)
// agg [N][16] f32 lives in d_out's edge region (overwritten last by conv3 edge).

#define NN 100000
#define NE 3200000

__device__ __forceinline__ float bf2f(unsigned int h) {
    unsigned int u = h << 16;
    float f; __builtin_memcpy(&f, &u, 4); return f;
}
__device__ __forceinline__ unsigned short f2bf(float f) {
    unsigned int u; __builtin_memcpy(&u, &f, 4);
    u += 0x7fffu + ((u >> 16) & 1u);          // RNE
    return (unsigned short)(u >> 16);
}
__device__ __forceinline__ void ldbf16x16(const unsigned short* p, float* r) {
    const uint4* q = reinterpret_cast<const uint4*>(p);
    uint4 a = q[0], b = q[1];
    unsigned int w[8] = {a.x, a.y, a.z, a.w, b.x, b.y, b.z, b.w};
    #pragma unroll
    for (int k = 0; k < 8; ++k) {
        r[2*k]   = bf2f(w[k] & 0xffffu);
        r[2*k+1] = bf2f(w[k] >> 16);
    }
}
__device__ __forceinline__ void stbf16x16(unsigned short* p, const float* r) {
    unsigned int w[8];
    #pragma unroll
    for (int k = 0; k < 8; ++k)
        w[k] = (unsigned int)f2bf(r[2*k]) | ((unsigned int)f2bf(r[2*k+1]) << 16);
    uint4* q = reinterpret_cast<uint4*>(p);
    q[0] = make_uint4(w[0], w[1], w[2], w[3]);
    q[1] = make_uint4(w[4], w[5], w[6], w[7]);
}

// ---------------- adjacency build (linked lists) ----------------

__global__ void kinit_head(int* head) {
    int i = blockIdx.x * blockDim.x + threadIdx.x;
    if (i < NN) head[i] = -1;
}

__global__ void kbuild(const int* __restrict__ ei, int* head, int* __restrict__ next) {
    int e = blockIdx.x * blockDim.x + threadIdx.x;
    if (e >= NE) return;
    int d = ei[NE + e];
    int old = atomicExch(&head[d], e);
    next[e] = old;                      // sequential, coalesced
}

// ---------------- conv kernels ----------------

// Pa1 = x3 @ ew1[0:3], Pc1 = x3 @ ew1[6:9]   (bf16 rows)
__global__ void prep1(const float* __restrict__ x, const float* __restrict__ ew1,
                      unsigned short* __restrict__ Pa, unsigned short* __restrict__ Pc) {
    int n = blockIdx.x * blockDim.x + threadIdx.x;
    if (n >= NN) return;
    float x0 = x[3*n], x1 = x[3*n+1], x2 = x[3*n+2];
    float pa[16], pc[16];
    #pragma unroll
    for (int j = 0; j < 16; ++j) {
        pa[j] = x0*ew1[0*16+j] + x1*ew1[1*16+j] + x2*ew1[2*16+j];
        pc[j] = x0*ew1[6*16+j] + x1*ew1[7*16+j] + x2*ew1[8*16+j];
    }
    stbf16x16(Pa + (size_t)n*16, pa);
    stbf16x16(Pc + (size_t)n*16, pc);
}

// conv1 aggregation via list walk: agg3[n] = sum relu(x[src]+ea[e]). 4 threads/node.
__global__ void kagg3_list(const int* __restrict__ head, const int* __restrict__ next,
                           const int* __restrict__ ei, const float* __restrict__ x,
                           const float* __restrict__ ea, float* __restrict__ agg) {
    int t = blockIdx.x * blockDim.x + threadIdx.x;
    int n = t >> 2, q = t & 3;
    if (n >= NN) return;
    float a = 0.f;
    int e = head[n];
    while (e >= 0) {
        int s = ei[e];
        if (q < 3) a += fmaxf(x[3*s + q] + ea[(size_t)3*e + q], 0.f);
        e = next[e];
    }
    if (q < 3) agg[(size_t)n*16 + q] = a;
}

// conv2/3 aggregation via list walk: 4 threads/node, 4 dims each (8B per lane per hop).
__global__ void kagg16_list(const int* __restrict__ head, const int* __restrict__ next,
                            const int* __restrict__ ei, const unsigned short* __restrict__ ebuf,
                            const unsigned short* __restrict__ xnbf, float* __restrict__ agg) {
    int t = blockIdx.x * blockDim.x + threadIdx.x;
    int n = t >> 2, q = t & 3;
    if (n >= NN) return;
    float a0 = 0.f, a1 = 0.f, a2 = 0.f, a3 = 0.f;
    int e = head[n];
    while (e >= 0) {
        int s = ei[e];
        uint2 w  = *reinterpret_cast<const uint2*>(ebuf + (size_t)e*16 + q*4);
        uint2 xw = *reinterpret_cast<const uint2*>(xnbf + (size_t)s*16 + q*4);
        a0 += fmaxf(bf2f(xw.x & 0xffffu) + bf2f(w.x & 0xffffu), 0.f);
        a1 += fmaxf(bf2f(xw.x >> 16)     + bf2f(w.x >> 16),     0.f);
        a2 += fmaxf(bf2f(xw.y & 0xffffu) + bf2f(w.y & 0xffffu), 0.f);
        a3 += fmaxf(bf2f(xw.y >> 16)     + bf2f(w.y >> 16),     0.f);
        e = next[e];
    }
    *reinterpret_cast<float4*>(agg + (size_t)n*16 + q*4) = make_float4(a0, a1, a2, a3);
}

// conv1 edge MLP: h=relu(Pa[s]+Pc[t]+b1+ea@W1mid); ebuf = relu(h@W2+b2)
__global__ void conv1_edge(const int* __restrict__ ei, const float* __restrict__ ea,
                           const unsigned short* __restrict__ Pa, const unsigned short* __restrict__ Pc,
                           const float* __restrict__ ew1, const float* __restrict__ eb1,
                           const float* __restrict__ ew2, const float* __restrict__ eb2,
                           unsigned short* __restrict__ ebuf) {
    int e = blockIdx.x * blockDim.x + threadIdx.x;
    if (e >= NE) return;
    int s = ei[e], t = ei[NE + e];
    float e0 = ea[(size_t)3*e], e1 = ea[(size_t)3*e+1], e2 = ea[(size_t)3*e+2];
    float h[16], pc[16];
    ldbf16x16(Pa + (size_t)s*16, h);
    ldbf16x16(Pc + (size_t)t*16, pc);
    #pragma unroll
    for (int j = 0; j < 16; ++j) {
        float a = h[j] + pc[j] + eb1[j]
                + e0*ew1[3*16+j] + e1*ew1[4*16+j] + e2*ew1[5*16+j];
        h[j] = fmaxf(a, 0.f);
    }
    float h2[16];
    #pragma unroll
    for (int j = 0; j < 16; ++j) {
        float a = eb2[j];
        #pragma unroll
        for (int i = 0; i < 16; ++i) a = fmaf(h[i], ew2[i*16+j], a);
        h2[j] = fmaxf(a, 0.f);
    }
    stbf16x16(ebuf + (size_t)e*16, h2);
}

// conv2/3 edge MLP. LAST=false: ebuf updated in place. LAST=true: fused edge head -> out_e.
template <bool LAST>
__global__ void conv_edge16(const int* __restrict__ ei, const unsigned short* __restrict__ ebuf_in,
                            const unsigned short* __restrict__ Pa, const unsigned short* __restrict__ Pc,
                            const float* __restrict__ ew1, const float* __restrict__ eb1,
                            const float* __restrict__ ew2, const float* __restrict__ eb2,
                            unsigned short* ebuf_out,
                            const float* __restrict__ hw1, const float* __restrict__ hb1,
                            const float* __restrict__ hw2, const float* __restrict__ hb2,
                            float* __restrict__ out_e) {
    int e = blockIdx.x * blockDim.x + threadIdx.x;
    if (e >= NE) return;
    int s = ei[e], t = ei[NE + e];
    float ein[16], h[16], pc[16];
    ldbf16x16(ebuf_in + (size_t)e*16, ein);
    ldbf16x16(Pa + (size_t)s*16, h);
    ldbf16x16(Pc + (size_t)t*16, pc);
    #pragma unroll
    for (int j = 0; j < 16; ++j) h[j] = h[j] + pc[j] + eb1[j];
    #pragma unroll
    for (int i = 0; i < 16; ++i) {
        #pragma unroll
        for (int j = 0; j < 16; ++j) h[j] = fmaf(ein[i], ew1[(16+i)*16+j], h[j]);
    }
    #pragma unroll
    for (int j = 0; j < 16; ++j) h[j] = fmaxf(h[j], 0.f);
    float h2[16];
    #pragma unroll
    for (int j = 0; j < 16; ++j) {
        float a = eb2[j];
        #pragma unroll
        for (int i = 0; i < 16; ++i) a = fmaf(h[i], ew2[i*16+j], a);
        h2[j] = fmaxf(a, 0.f);
    }
    if (!LAST) {
        stbf16x16(ebuf_out + (size_t)e*16, h2);
    } else {
        float g[16];
        #pragma unroll
        for (int j = 0; j < 16; ++j) {
            float a = hb1[j];
            #pragma unroll
            for (int i = 0; i < 16; ++i) a = fmaf(h2[i], hw1[i*16+j], a);
            g[j] = fmaxf(a, 0.f);
        }
        #pragma unroll
        for (int k = 0; k < 3; ++k) {
            float a = hb2[k];
            #pragma unroll
            for (int i = 0; i < 16; ++i) a = fmaf(g[i], hw2[i*3+k], a);
            out_e[(size_t)e*3 + k] = a;
        }
    }
}

// conv1 node MLP (+ prep for conv2)
__global__ void conv1_node(const float* __restrict__ agg, const float* __restrict__ x,
                           const float* __restrict__ nw1, const float* __restrict__ nb1,
                           const float* __restrict__ nw2, const float* __restrict__ nb2,
                           const float* __restrict__ next_ew1,
                           unsigned short* __restrict__ Pa, unsigned short* __restrict__ Pc,
                           unsigned short* __restrict__ xnbf) {
    int n = blockIdx.x * blockDim.x + threadIdx.x;
    if (n >= NN) return;
    float o0 = agg[(size_t)n*16+0] + x[3*n];
    float o1 = agg[(size_t)n*16+1] + x[3*n+1];
    float o2 = agg[(size_t)n*16+2] + x[3*n+2];
    float h[16];
    #pragma unroll
    for (int j = 0; j < 16; ++j)
        h[j] = fmaxf(nb1[j] + o0*nw1[0*16+j] + o1*nw1[1*16+j] + o2*nw1[2*16+j], 0.f);
    float xn[16];
    #pragma unroll
    for (int j = 0; j < 16; ++j) {
        float a = nb2[j];
        #pragma unroll
        for (int i = 0; i < 16; ++i) a = fmaf(h[i], nw2[i*16+j], a);
        xn[j] = fmaxf(a, 0.f);
    }
    float pa[16], pc[16];
    #pragma unroll
    for (int j = 0; j < 16; ++j) {
        float sa = 0.f, sc = 0.f;
        #pragma unroll
        for (int i = 0; i < 16; ++i) {
            sa = fmaf(xn[i], next_ew1[i*16+j], sa);
            sc = fmaf(xn[i], next_ew1[(32+i)*16+j], sc);
        }
        pa[j] = sa; pc[j] = sc;
    }
    stbf16x16(xnbf + (size_t)n*16, xn);
    stbf16x16(Pa + (size_t)n*16, pa);
    stbf16x16(Pc + (size_t)n*16, pc);
}

// conv2 node MLP (+ prep for conv3). Reads/writes own xnbf row only (safe in place).
__global__ void node_mid(const float* __restrict__ agg,
                         const float* __restrict__ nw1, const float* __restrict__ nb1,
                         const float* __restrict__ nw2, const float* __restrict__ nb2,
                         const float* __restrict__ next_ew1,
                         unsigned short* __restrict__ Pa, unsigned short* __restrict__ Pc,
                         unsigned short* xnbf) {
    int n = blockIdx.x * blockDim.x + threadIdx.x;
    if (n >= NN) return;
    float o[16];
    ldbf16x16(xnbf + (size_t)n*16, o);
    #pragma unroll
    for (int j = 0; j < 16; ++j) o[j] += agg[(size_t)n*16 + j];
    float h[16];
    #pragma unroll
    for (int j = 0; j < 16; ++j) {
        float a = nb1[j];
        #pragma unroll
        for (int i = 0; i < 16; ++i) a = fmaf(o[i], nw1[i*16+j], a);
        h[j] = fmaxf(a, 0.f);
    }
    float xn[16];
    #pragma unroll
    for (int j = 0; j < 16; ++j) {
        float a = nb2[j];
        #pragma unroll
        for (int i = 0; i < 16; ++i) a = fmaf(h[i], nw2[i*16+j], a);
        xn[j] = fmaxf(a, 0.f);
    }
    float pa[16], pc[16];
    #pragma unroll
    for (int j = 0; j < 16; ++j) {
        float sa = 0.f, sc = 0.f;
        #pragma unroll
        for (int i = 0; i < 16; ++i) {
            sa = fmaf(xn[i], next_ew1[i*16+j], sa);
            sc = fmaf(xn[i], next_ew1[(32+i)*16+j], sc);
        }
        pa[j] = sa; pc[j] = sc;
    }
    stbf16x16(xnbf + (size_t)n*16, xn);
    stbf16x16(Pa + (size_t)n*16, pa);
    stbf16x16(Pc + (size_t)n*16, pc);
}

// conv3 node MLP + node head -> out_n
__global__ void node_last(const float* __restrict__ agg, const unsigned short* __restrict__ xnbf,
                          const float* __restrict__ nw1, const float* __restrict__ nb1,
                          const float* __restrict__ nw2, const float* __restrict__ nb2,
                          const float* __restrict__ hw1, const float* __restrict__ hb1,
                          const float* __restrict__ hw2, const float* __restrict__ hb2,
                          float* __restrict__ out_n) {
    int n = blockIdx.x * blockDim.x + threadIdx.x;
    if (n >= NN) return;
    float o[16];
    ldbf16x16(xnbf + (size_t)n*16, o);
    #pragma unroll
    for (int j = 0; j < 16; ++j) o[j] += agg[(size_t)n*16 + j];
    float h[16];
    #pragma unroll
    for (int j = 0; j < 16; ++j) {
        float a = nb1[j];
        #pragma unroll
        for (int i = 0; i < 16; ++i) a = fmaf(o[i], nw1[i*16+j], a);
        h[j] = fmaxf(a, 0.f);
    }
    float xn[16];
    #pragma unroll
    for (int j = 0; j < 16; ++j) {
        float a = nb2[j];
        #pragma unroll
        for (int i = 0; i < 16; ++i) a = fmaf(h[i], nw2[i*16+j], a);
        xn[j] = fmaxf(a, 0.f);
    }
    float g[16];
    #pragma unroll
    for (int j = 0; j < 16; ++j) {
        float a = hb1[j];
        #pragma unroll
        for (int i = 0; i < 16; ++i) a = fmaf(xn[i], hw1[i*16+j], a);
        g[j] = fmaxf(a, 0.f);
    }
    #pragma unroll
    for (int k = 0; k < 3; ++k) {
        float a = hb2[k];
        #pragma unroll
        for (int i = 0; i < 16; ++i) a = fmaf(g[i], hw2[i*3+k], a);
        out_n[(size_t)n*3 + k] = a;
    }
}

extern "C" void kernel_launch(void* const* d_in, const int* in_sizes, int n_in,
                              void* d_out, int out_size, void* d_ws, size_t ws_size,
                              hipStream_t stream) {
    const float* x  = (const float*)d_in[0];
    const float* ea = (const float*)d_in[1];
    const int*   ei = (const int*)d_in[2];
    const float *c1_ew1 = (const float*)d_in[3],  *c1_eb1 = (const float*)d_in[4];
    const float *c1_ew2 = (const float*)d_in[5],  *c1_eb2 = (const float*)d_in[6];
    const float *c1_nw1 = (const float*)d_in[7],  *c1_nb1 = (const float*)d_in[8];
    const float *c1_nw2 = (const float*)d_in[9],  *c1_nb2 = (const float*)d_in[10];
    const float *c2_ew1 = (const float*)d_in[11], *c2_eb1 = (const float*)d_in[12];
    const float *c2_ew2 = (const float*)d_in[13], *c2_eb2 = (const float*)d_in[14];
    const float *c2_nw1 = (const float*)d_in[15], *c2_nb1 = (const float*)d_in[16];
    const float *c2_nw2 = (const float*)d_in[17], *c2_nb2 = (const float*)d_in[18];
    const float *c3_ew1 = (const float*)d_in[19], *c3_eb1 = (const float*)d_in[20];
    const float *c3_ew2 = (const float*)d_in[21], *c3_eb2 = (const float*)d_in[22];
    const float *c3_nw1 = (const float*)d_in[23], *c3_nb1 = (const float*)d_in[24];
    const float *c3_nw2 = (const float*)d_in[25], *c3_nb2 = (const float*)d_in[26];
    const float *node_w1 = (const float*)d_in[27], *node_b1 = (const float*)d_in[28];
    const float *node_w2 = (const float*)d_in[29], *node_b2 = (const float*)d_in[30];
    const float *edge_w1 = (const float*)d_in[31], *edge_b1 = (const float*)d_in[32];
    const float *edge_w2 = (const float*)d_in[33], *edge_b2 = (const float*)d_in[34];

    // ws carve-up (64B-aligned chunks)
    char* w = (char*)d_ws;
    unsigned short* ebuf = (unsigned short*)w;            w += (size_t)NE * 16 * 2;   // 102.4 MB
    int* next = (int*)w;                                  w += (size_t)NE * 4;        // 12.8 MB
    int* head = (int*)w;                                  w += ((size_t)NN * 4 + 63) & ~63ull;
    unsigned short* Pa   = (unsigned short*)w;            w += (size_t)NN * 16 * 2;   // 3.2 MB
    unsigned short* Pc   = (unsigned short*)w;            w += (size_t)NN * 16 * 2;
    unsigned short* xnbf = (unsigned short*)w;            w += (size_t)NN * 16 * 2;

    float* out_n = (float*)d_out;                         // N*3
    float* out_e = out_n + (size_t)NN * 3;                // E*3
    float* agg   = out_e;                                 // N*16 f32 scratch inside edge-out region

    const int B = 256;
    const int gn = (NN + B - 1) / B;            // 391
    const int ge = (NE + B - 1) / B;            // 12500
    const int gq = (NN * 4 + B - 1) / B;        // 1563

    // --- adjacency build (list order = atomic completion order; only perturbs
    //     fp summation order, within tolerance) ---
    kinit_head<<<gn, B, 0, stream>>>(head);
    kbuild<<<ge, B, 0, stream>>>(ei, head, next);

    // --- conv1 ---
    prep1<<<gn, B, 0, stream>>>(x, c1_ew1, Pa, Pc);
    kagg3_list<<<gq, B, 0, stream>>>(head, next, ei, x, ea, agg);
    conv1_edge<<<ge, B, 0, stream>>>(ei, ea, Pa, Pc, c1_ew1, c1_eb1, c1_ew2, c1_eb2, ebuf);
    conv1_node<<<gn, B, 0, stream>>>(agg, x, c1_nw1, c1_nb1, c1_nw2, c1_nb2,
                                     c2_ew1, Pa, Pc, xnbf);

    // --- conv2 (agg reads old ebuf BEFORE edge kernel overwrites it) ---
    kagg16_list<<<gq, B, 0, stream>>>(head, next, ei, ebuf, xnbf, agg);
    conv_edge16<false><<<ge, B, 0, stream>>>(ei, ebuf, Pa, Pc,
                                             c2_ew1, c2_eb1, c2_ew2, c2_eb2, ebuf,
                                             nullptr, nullptr, nullptr, nullptr, nullptr);
    node_mid<<<gn, B, 0, stream>>>(agg, c2_nw1, c2_nb1, c2_nw2, c2_nb2,
                                   c3_ew1, Pa, Pc, xnbf);

    // --- conv3 (agg scratch in out_e region: node kernel consumes it, then the
    //     edge kernel overwrites the whole region with real outputs) ---
    kagg16_list<<<gq, B, 0, stream>>>(head, next, ei, ebuf, xnbf, agg);
    node_last<<<gn, B, 0, stream>>>(agg, xnbf, c3_nw1, c3_nb1, c3_nw2, c3_nb2,
                                    node_w1, node_b1, node_w2, node_b2, out_n);
    conv_edge16<true><<<ge, B, 0, stream>>>(ei, ebuf, Pa, Pc,
                                            c3_ew1, c3_eb1, c3_ew2, c3_eb2, nullptr,
                                            edge_w1, edge_b1, edge_w2, edge_b2, out_e);
}

// Round 4
// 999.421 us; speedup vs baseline: 5.7595x; 1.0141x over previous
//
#include <hip/hip_runtime.h>
#include <hip/hip_bf16.h>

// GINE 3-conv GNN. Two paths selected by ws_size:
//  SORTED (ws >= ~138MB): per-call dst-sorted edge layout (linked list -> deg ->
//    scan -> fill). All conv kernels stream ebuf sequentially in slot space;
//    dst recovered by binary search on start[]. Random access only in the
//    one-time build walk and conv3's out_e scatter.
//  FALLBACK (smaller ws): round-3 linked-list gather path (known-pass).
// N=100000, E=3200000, H=16. fp32 in/out; edge_index int32 rows [src | dst].

#define NN 100000
#define NE 3200000
#define SCAN_B 512
#define NB_SCAN ((NN + SCAN_B - 1) / SCAN_B)   // 196

__device__ __forceinline__ float bf2f(unsigned int h) {
    unsigned int u = h << 16;
    float f; __builtin_memcpy(&f, &u, 4); return f;
}
__device__ __forceinline__ unsigned short f2bf(float f) {
    unsigned int u; __builtin_memcpy(&u, &f, 4);
    u += 0x7fffu + ((u >> 16) & 1u);          // RNE
    return (unsigned short)(u >> 16);
}
__device__ __forceinline__ void ldbf16x16(const unsigned short* p, float* r) {
    const uint4* q = reinterpret_cast<const uint4*>(p);
    uint4 a = q[0], b = q[1];
    unsigned int w[8] = {a.x, a.y, a.z, a.w, b.x, b.y, b.z, b.w};
    #pragma unroll
    for (int k = 0; k < 8; ++k) {
        r[2*k]   = bf2f(w[k] & 0xffffu);
        r[2*k+1] = bf2f(w[k] >> 16);
    }
}
__device__ __forceinline__ void stbf16x16(unsigned short* p, const float* r) {
    unsigned int w[8];
    #pragma unroll
    for (int k = 0; k < 8; ++k)
        w[k] = (unsigned int)f2bf(r[2*k]) | ((unsigned int)f2bf(r[2*k+1]) << 16);
    uint4* q = reinterpret_cast<uint4*>(p);
    q[0] = make_uint4(w[0], w[1], w[2], w[3]);
    q[1] = make_uint4(w[4], w[5], w[6], w[7]);
}

// slot j -> dst node: largest n with start[n] <= j (start L2-resident, 17 iters)
__device__ __forceinline__ int slot2dst(const int* __restrict__ start, int j) {
    int lo = 0, hi = NN;
    while (hi - lo > 1) {
        int mid = (lo + hi) >> 1;
        if (start[mid] <= j) lo = mid; else hi = mid;
    }
    return lo;
}

// ---------------- adjacency build ----------------

__global__ void kinit_head(int* head) {
    int i = blockIdx.x * blockDim.x + threadIdx.x;
    if (i < NN) head[i] = -1;
}

__global__ void kbuild(const int* __restrict__ ei, int* head, int* __restrict__ next) {
    int e = blockIdx.x * blockDim.x + threadIdx.x;
    if (e >= NE) return;
    int d = ei[NE + e];
    int old = atomicExch(&head[d], e);
    next[e] = old;                      // sequential, coalesced
}

__global__ void kdeg(const int* __restrict__ head, const int* __restrict__ next,
                     int* __restrict__ deg) {
    int n = blockIdx.x * blockDim.x + threadIdx.x;
    if (n >= NN) return;
    int c = 0;
    int e = head[n];
    while (e >= 0) { ++c; e = next[e]; }
    deg[n] = c;
}

__global__ void kscan1(const int* __restrict__ deg, int* __restrict__ start, int* __restrict__ bsum) {
    int t = threadIdx.x, b = blockIdx.x;
    int i = b * SCAN_B + t;
    int v = (i < NN) ? deg[i] : 0;
    int lane = t & 63, wid = t >> 6;
    #pragma unroll
    for (int off = 1; off < 64; off <<= 1) {
        int u = __shfl_up(v, off);
        if (lane >= off) v += u;
    }
    __shared__ int wsum[8];
    if (lane == 63) wsum[wid] = v;
    __syncthreads();
    if (t < 8) {
        int w = wsum[t];
        #pragma unroll
        for (int off = 1; off < 8; off <<= 1) {
            int u = __shfl_up(w, off);
            if (t >= off) w += u;
        }
        wsum[t] = w;
    }
    __syncthreads();
    if (wid > 0) v += wsum[wid - 1];
    if (i < NN) start[i + 1] = v;
    if (t == SCAN_B - 1) bsum[b] = v;
}

__global__ void kscan2(int* bsum) {
    __shared__ int s[256];
    int t = threadIdx.x;
    s[t] = (t < NB_SCAN) ? bsum[t] : 0;
    __syncthreads();
    for (int off = 1; off < 256; off <<= 1) {
        int u = (t >= off) ? s[t - off] : 0;
        __syncthreads();
        s[t] += u;
        __syncthreads();
    }
    if (t < NB_SCAN) bsum[t] = s[t];
}

__global__ void kscan3(int* __restrict__ start, const int* __restrict__ bsum) {
    int i = blockIdx.x * blockDim.x + threadIdx.x;
    if (i >= NN) return;
    int b = i >> 9;                 // SCAN_B = 512
    int off = (b > 0) ? bsum[b - 1] : 0;
    start[i + 1] += off;
    if (i == 0) start[0] = 0;
}

// walk each node's list once: assign contiguous slots, materialize eid/srcs/ea_s,
// and fuse conv1's 3-dim aggregation (full-precision ea used for the sum).
__global__ void kfill(const int* __restrict__ head, const int* __restrict__ next,
                      const int* __restrict__ ei, const float* __restrict__ ea,
                      const float* __restrict__ x, const int* __restrict__ start,
                      int* __restrict__ eid, int* __restrict__ srcs,
                      unsigned short* __restrict__ ea_s, float* __restrict__ agg) {
    int n = blockIdx.x * blockDim.x + threadIdx.x;
    if (n >= NN) return;
    int j = start[n];
    float a0 = 0.f, a1 = 0.f, a2 = 0.f;
    int e = head[n];
    while (e >= 0) {
        int s = ei[e];
        float e0 = ea[(size_t)3*e], e1 = ea[(size_t)3*e+1], e2 = ea[(size_t)3*e+2];
        eid[j] = e;
        srcs[j] = s;
        unsigned int w0 = (unsigned int)f2bf(e0) | ((unsigned int)f2bf(e1) << 16);
        unsigned int w1 = (unsigned int)f2bf(e2);
        *reinterpret_cast<uint2*>(ea_s + (size_t)j*4) = make_uint2(w0, w1);
        a0 += fmaxf(x[3*s  ] + e0, 0.f);
        a1 += fmaxf(x[3*s+1] + e1, 0.f);
        a2 += fmaxf(x[3*s+2] + e2, 0.f);
        ++j;
        e = next[e];
    }
    float* p = agg + (size_t)n*16;
    p[0] = a0; p[1] = a1; p[2] = a2;
}

// ---------------- shared node-side kernels ----------------

// Pa1 = x3 @ ew1[0:3], Pc1 = x3 @ ew1[6:9]   (bf16 rows)
__global__ void prep1(const float* __restrict__ x, const float* __restrict__ ew1,
                      unsigned short* __restrict__ Pa, unsigned short* __restrict__ Pc) {
    int n = blockIdx.x * blockDim.x + threadIdx.x;
    if (n >= NN) return;
    float x0 = x[3*n], x1 = x[3*n+1], x2 = x[3*n+2];
    float pa[16], pc[16];
    #pragma unroll
    for (int j = 0; j < 16; ++j) {
        pa[j] = x0*ew1[0*16+j] + x1*ew1[1*16+j] + x2*ew1[2*16+j];
        pc[j] = x0*ew1[6*16+j] + x1*ew1[7*16+j] + x2*ew1[8*16+j];
    }
    stbf16x16(Pa + (size_t)n*16, pa);
    stbf16x16(Pc + (size_t)n*16, pc);
}

__global__ void conv1_node(const float* __restrict__ agg, const float* __restrict__ x,
                           const float* __restrict__ nw1, const float* __restrict__ nb1,
                           const float* __restrict__ nw2, const float* __restrict__ nb2,
                           const float* __restrict__ next_ew1,
                           unsigned short* __restrict__ Pa, unsigned short* __restrict__ Pc,
                           unsigned short* __restrict__ xnbf) {
    int n = blockIdx.x * blockDim.x + threadIdx.x;
    if (n >= NN) return;
    float o0 = agg[(size_t)n*16+0] + x[3*n];
    float o1 = agg[(size_t)n*16+1] + x[3*n+1];
    float o2 = agg[(size_t)n*16+2] + x[3*n+2];
    float h[16];
    #pragma unroll
    for (int j = 0; j < 16; ++j)
        h[j] = fmaxf(nb1[j] + o0*nw1[0*16+j] + o1*nw1[1*16+j] + o2*nw1[2*16+j], 0.f);
    float xn[16];
    #pragma unroll
    for (int j = 0; j < 16; ++j) {
        float a = nb2[j];
        #pragma unroll
        for (int i = 0; i < 16; ++i) a = fmaf(h[i], nw2[i*16+j], a);
        xn[j] = fmaxf(a, 0.f);
    }
    float pa[16], pc[16];
    #pragma unroll
    for (int j = 0; j < 16; ++j) {
        float sa = 0.f, sc = 0.f;
        #pragma unroll
        for (int i = 0; i < 16; ++i) {
            sa = fmaf(xn[i], next_ew1[i*16+j], sa);
            sc = fmaf(xn[i], next_ew1[(32+i)*16+j], sc);
        }
        pa[j] = sa; pc[j] = sc;
    }
    stbf16x16(xnbf + (size_t)n*16, xn);
    stbf16x16(Pa + (size_t)n*16, pa);
    stbf16x16(Pc + (size_t)n*16, pc);
}

__global__ void node_mid(const float* __restrict__ agg,
                         const float* __restrict__ nw1, const float* __restrict__ nb1,
                         const float* __restrict__ nw2, const float* __restrict__ nb2,
                         const float* __restrict__ next_ew1,
                         unsigned short* __restrict__ Pa, unsigned short* __restrict__ Pc,
                         unsigned short* xnbf) {
    int n = blockIdx.x * blockDim.x + threadIdx.x;
    if (n >= NN) return;
    float o[16];
    ldbf16x16(xnbf + (size_t)n*16, o);
    #pragma unroll
    for (int j = 0; j < 16; ++j) o[j] += agg[(size_t)n*16 + j];
    float h[16];
    #pragma unroll
    for (int j = 0; j < 16; ++j) {
        float a = nb1[j];
        #pragma unroll
        for (int i = 0; i < 16; ++i) a = fmaf(o[i], nw1[i*16+j], a);
        h[j] = fmaxf(a, 0.f);
    }
    float xn[16];
    #pragma unroll
    for (int j = 0; j < 16; ++j) {
        float a = nb2[j];
        #pragma unroll
        for (int i = 0; i < 16; ++i) a = fmaf(h[i], nw2[i*16+j], a);
        xn[j] = fmaxf(a, 0.f);
    }
    float pa[16], pc[16];
    #pragma unroll
    for (int j = 0; j < 16; ++j) {
        float sa = 0.f, sc = 0.f;
        #pragma unroll
        for (int i = 0; i < 16; ++i) {
            sa = fmaf(xn[i], next_ew1[i*16+j], sa);
            sc = fmaf(xn[i], next_ew1[(32+i)*16+j], sc);
        }
        pa[j] = sa; pc[j] = sc;
    }
    stbf16x16(xnbf + (size_t)n*16, xn);
    stbf16x16(Pa + (size_t)n*16, pa);
    stbf16x16(Pc + (size_t)n*16, pc);
}

__global__ void node_last(const float* __restrict__ agg, const unsigned short* __restrict__ xnbf,
                          const float* __restrict__ nw1, const float* __restrict__ nb1,
                          const float* __restrict__ nw2, const float* __restrict__ nb2,
                          const float* __restrict__ hw1, const float* __restrict__ hb1,
                          const float* __restrict__ hw2, const float* __restrict__ hb2,
                          float* __restrict__ out_n) {
    int n = blockIdx.x * blockDim.x + threadIdx.x;
    if (n >= NN) return;
    float o[16];
    ldbf16x16(xnbf + (size_t)n*16, o);
    #pragma unroll
    for (int j = 0; j < 16; ++j) o[j] += agg[(size_t)n*16 + j];
    float h[16];
    #pragma unroll
    for (int j = 0; j < 16; ++j) {
        float a = nb1[j];
        #pragma unroll
        for (int i = 0; i < 16; ++i) a = fmaf(o[i], nw1[i*16+j], a);
        h[j] = fmaxf(a, 0.f);
    }
    float xn[16];
    #pragma unroll
    for (int j = 0; j < 16; ++j) {
        float a = nb2[j];
        #pragma unroll
        for (int i = 0; i < 16; ++i) a = fmaf(h[i], nw2[i*16+j], a);
        xn[j] = fmaxf(a, 0.f);
    }
    float g[16];
    #pragma unroll
    for (int j = 0; j < 16; ++j) {
        float a = hb1[j];
        #pragma unroll
        for (int i = 0; i < 16; ++i) a = fmaf(xn[i], hw1[i*16+j], a);
        g[j] = fmaxf(a, 0.f);
    }
    #pragma unroll
    for (int k = 0; k < 3; ++k) {
        float a = hb2[k];
        #pragma unroll
        for (int i = 0; i < 16; ++i) a = fmaf(g[i], hw2[i*3+k], a);
        out_n[(size_t)n*3 + k] = a;
    }
}

// ---------------- SORTED-path conv kernels (slot space) ----------------

__global__ void conv1_edge_s(const int* __restrict__ start, const int* __restrict__ srcs,
                             const unsigned short* __restrict__ ea_s,
                             const unsigned short* __restrict__ Pa, const unsigned short* __restrict__ Pc,
                             const float* __restrict__ ew1, const float* __restrict__ eb1,
                             const float* __restrict__ ew2, const float* __restrict__ eb2,
                             unsigned short* __restrict__ ebuf) {
    int j = blockIdx.x * blockDim.x + threadIdx.x;
    if (j >= NE) return;
    int t = slot2dst(start, j);
    int s = srcs[j];
    uint2 wv = *reinterpret_cast<const uint2*>(ea_s + (size_t)j*4);
    float e0 = bf2f(wv.x & 0xffffu), e1 = bf2f(wv.x >> 16), e2 = bf2f(wv.y & 0xffffu);
    float h[16], pc[16];
    ldbf16x16(Pa + (size_t)s*16, h);
    ldbf16x16(Pc + (size_t)t*16, pc);
    #pragma unroll
    for (int jj = 0; jj < 16; ++jj) {
        float a = h[jj] + pc[jj] + eb1[jj]
                + e0*ew1[3*16+jj] + e1*ew1[4*16+jj] + e2*ew1[5*16+jj];
        h[jj] = fmaxf(a, 0.f);
    }
    float h2[16];
    #pragma unroll
    for (int jj = 0; jj < 16; ++jj) {
        float a = eb2[jj];
        #pragma unroll
        for (int i = 0; i < 16; ++i) a = fmaf(h[i], ew2[i*16+jj], a);
        h2[jj] = fmaxf(a, 0.f);
    }
    stbf16x16(ebuf + (size_t)j*16, h2);
}

template <bool LAST>
__global__ void conv_edge16_s(const int* __restrict__ start, const int* __restrict__ srcs,
                              unsigned short* ebuf,          // in-place per slot
                              const unsigned short* __restrict__ Pa, const unsigned short* __restrict__ Pc,
                              const float* __restrict__ ew1, const float* __restrict__ eb1,
                              const float* __restrict__ ew2, const float* __restrict__ eb2,
                              const int* __restrict__ eid,
                              const float* __restrict__ hw1, const float* __restrict__ hb1,
                              const float* __restrict__ hw2, const float* __restrict__ hb2,
                              float* __restrict__ out_e) {
    int j = blockIdx.x * blockDim.x + threadIdx.x;
    if (j >= NE) return;
    int t = slot2dst(start, j);
    int s = srcs[j];
    float ein[16], h[16], pc[16];
    ldbf16x16(ebuf + (size_t)j*16, ein);
    ldbf16x16(Pa + (size_t)s*16, h);
    ldbf16x16(Pc + (size_t)t*16, pc);
    #pragma unroll
    for (int jj = 0; jj < 16; ++jj) h[jj] = h[jj] + pc[jj] + eb1[jj];
    #pragma unroll
    for (int i = 0; i < 16; ++i) {
        #pragma unroll
        for (int jj = 0; jj < 16; ++jj) h[jj] = fmaf(ein[i], ew1[(16+i)*16+jj], h[jj]);
    }
    #pragma unroll
    for (int jj = 0; jj < 16; ++jj) h[jj] = fmaxf(h[jj], 0.f);
    float h2[16];
    #pragma unroll
    for (int jj = 0; jj < 16; ++jj) {
        float a = eb2[jj];
        #pragma unroll
        for (int i = 0; i < 16; ++i) a = fmaf(h[i], ew2[i*16+jj], a);
        h2[jj] = fmaxf(a, 0.f);
    }
    if (!LAST) {
        stbf16x16(ebuf + (size_t)j*16, h2);
    } else {
        float g[16];
        #pragma unroll
        for (int jj = 0; jj < 16; ++jj) {
            float a = hb1[jj];
            #pragma unroll
            for (int i = 0; i < 16; ++i) a = fmaf(h2[i], hw1[i*16+jj], a);
            g[jj] = fmaxf(a, 0.f);
        }
        int e = eid[j];
        #pragma unroll
        for (int k = 0; k < 3; ++k) {
            float a = hb2[k];
            #pragma unroll
            for (int i = 0; i < 16; ++i) a = fmaf(g[i], hw2[i*3+k], a);
            out_e[(size_t)e*3 + k] = a;
        }
    }
}

// 4 threads/node; streams the node's contiguous slot segment.
__global__ void kagg16_s(const int* __restrict__ start, const int* __restrict__ srcs,
                         const unsigned short* __restrict__ ebuf,
                         const unsigned short* __restrict__ xnbf, float* __restrict__ agg) {
    int tg = blockIdx.x * blockDim.x + threadIdx.x;
    int n = tg >> 2, q = tg & 3;
    if (n >= NN) return;
    int j0 = start[n], j1 = start[n+1];
    float a0 = 0.f, a1 = 0.f, a2 = 0.f, a3 = 0.f;
    for (int j = j0; j < j1; ++j) {
        int s = srcs[j];
        uint2 w  = *reinterpret_cast<const uint2*>(ebuf + (size_t)j*16 + q*4);
        uint2 xw = *reinterpret_cast<const uint2*>(xnbf + (size_t)s*16 + q*4);
        a0 += fmaxf(bf2f(xw.x & 0xffffu) + bf2f(w.x & 0xffffu), 0.f);
        a1 += fmaxf(bf2f(xw.x >> 16)     + bf2f(w.x >> 16),     0.f);
        a2 += fmaxf(bf2f(xw.y & 0xffffu) + bf2f(w.y & 0xffffu), 0.f);
        a3 += fmaxf(bf2f(xw.y >> 16)     + bf2f(w.y >> 16),     0.f);
    }
    *reinterpret_cast<float4*>(agg + (size_t)n*16 + q*4) = make_float4(a0, a1, a2, a3);
}

// ---------------- FALLBACK-path conv kernels (linked-list gather) ----------------

__global__ void kagg3_list(const int* __restrict__ head, const int* __restrict__ next,
                           const int* __restrict__ ei, const float* __restrict__ x,
                           const float* __restrict__ ea, float* __restrict__ agg) {
    int t = blockIdx.x * blockDim.x + threadIdx.x;
    int n = t >> 2, q = t & 3;
    if (n >= NN) return;
    float a = 0.f;
    int e = head[n];
    while (e >= 0) {
        int s = ei[e];
        if (q < 3) a += fmaxf(x[3*s + q] + ea[(size_t)3*e + q], 0.f);
        e = next[e];
    }
    if (q < 3) agg[(size_t)n*16 + q] = a;
}

__global__ void kagg16_list(const int* __restrict__ head, const int* __restrict__ next,
                            const int* __restrict__ ei, const unsigned short* __restrict__ ebuf,
                            const unsigned short* __restrict__ xnbf, float* __restrict__ agg) {
    int t = blockIdx.x * blockDim.x + threadIdx.x;
    int n = t >> 2, q = t & 3;
    if (n >= NN) return;
    float a0 = 0.f, a1 = 0.f, a2 = 0.f, a3 = 0.f;
    int e = head[n];
    while (e >= 0) {
        int s = ei[e];
        uint2 w  = *reinterpret_cast<const uint2*>(ebuf + (size_t)e*16 + q*4);
        uint2 xw = *reinterpret_cast<const uint2*>(xnbf + (size_t)s*16 + q*4);
        a0 += fmaxf(bf2f(xw.x & 0xffffu) + bf2f(w.x & 0xffffu), 0.f);
        a1 += fmaxf(bf2f(xw.x >> 16)     + bf2f(w.x >> 16),     0.f);
        a2 += fmaxf(bf2f(xw.y & 0xffffu) + bf2f(w.y & 0xffffu), 0.f);
        a3 += fmaxf(bf2f(xw.y >> 16)     + bf2f(w.y >> 16),     0.f);
        e = next[e];
    }
    *reinterpret_cast<float4*>(agg + (size_t)n*16 + q*4) = make_float4(a0, a1, a2, a3);
}

__global__ void conv1_edge_l(const int* __restrict__ ei, const float* __restrict__ ea,
                             const unsigned short* __restrict__ Pa, const unsigned short* __restrict__ Pc,
                             const float* __restrict__ ew1, const float* __restrict__ eb1,
                             const float* __restrict__ ew2, const float* __restrict__ eb2,
                             unsigned short* __restrict__ ebuf) {
    int e = blockIdx.x * blockDim.x + threadIdx.x;
    if (e >= NE) return;
    int s = ei[e], t = ei[NE + e];
    float e0 = ea[(size_t)3*e], e1 = ea[(size_t)3*e+1], e2 = ea[(size_t)3*e+2];
    float h[16], pc[16];
    ldbf16x16(Pa + (size_t)s*16, h);
    ldbf16x16(Pc + (size_t)t*16, pc);
    #pragma unroll
    for (int j = 0; j < 16; ++j) {
        float a = h[j] + pc[j] + eb1[j]
                + e0*ew1[3*16+j] + e1*ew1[4*16+j] + e2*ew1[5*16+j];
        h[j] = fmaxf(a, 0.f);
    }
    float h2[16];
    #pragma unroll
    for (int j = 0; j < 16; ++j) {
        float a = eb2[j];
        #pragma unroll
        for (int i = 0; i < 16; ++i) a = fmaf(h[i], ew2[i*16+j], a);
        h2[j] = fmaxf(a, 0.f);
    }
    stbf16x16(ebuf + (size_t)e*16, h2);
}

template <bool LAST>
__global__ void conv_edge16_l(const int* __restrict__ ei, const unsigned short* __restrict__ ebuf_in,
                              const unsigned short* __restrict__ Pa, const unsigned short* __restrict__ Pc,
                              const float* __restrict__ ew1, const float* __restrict__ eb1,
                              const float* __restrict__ ew2, const float* __restrict__ eb2,
                              unsigned short* ebuf_out,
                              const float* __restrict__ hw1, const float* __restrict__ hb1,
                              const float* __restrict__ hw2, const float* __restrict__ hb2,
                              float* __restrict__ out_e) {
    int e = blockIdx.x * blockDim.x + threadIdx.x;
    if (e >= NE) return;
    int s = ei[e], t = ei[NE + e];
    float ein[16], h[16], pc[16];
    ldbf16x16(ebuf_in + (size_t)e*16, ein);
    ldbf16x16(Pa + (size_t)s*16, h);
    ldbf16x16(Pc + (size_t)t*16, pc);
    #pragma unroll
    for (int j = 0; j < 16; ++j) h[j] = h[j] + pc[j] + eb1[j];
    #pragma unroll
    for (int i = 0; i < 16; ++i) {
        #pragma unroll
        for (int j = 0; j < 16; ++j) h[j] = fmaf(ein[i], ew1[(16+i)*16+j], h[j]);
    }
    #pragma unroll
    for (int j = 0; j < 16; ++j) h[j] = fmaxf(h[j], 0.f);
    float h2[16];
    #pragma unroll
    for (int j = 0; j < 16; ++j) {
        float a = eb2[j];
        #pragma unroll
        for (int i = 0; i < 16; ++i) a = fmaf(h[i], ew2[i*16+j], a);
        h2[j] = fmaxf(a, 0.f);
    }
    if (!LAST) {
        stbf16x16(ebuf_out + (size_t)e*16, h2);
    } else {
        float g[16];
        #pragma unroll
        for (int j = 0; j < 16; ++j) {
            float a = hb1[j];
            #pragma unroll
            for (int i = 0; i < 16; ++i) a = fmaf(h2[i], hw1[i*16+j], a);
            g[j] = fmaxf(a, 0.f);
        }
        #pragma unroll
        for (int k = 0; k < 3; ++k) {
            float a = hb2[k];
            #pragma unroll
            for (int i = 0; i < 16; ++i) a = fmaf(g[i], hw2[i*3+k], a);
            out_e[(size_t)e*3 + k] = a;
        }
    }
}

extern "C" void kernel_launch(void* const* d_in, const int* in_sizes, int n_in,
                              void* d_out, int out_size, void* d_ws, size_t ws_size,
                              hipStream_t stream) {
    const float* x  = (const float*)d_in[0];
    const float* ea = (const float*)d_in[1];
    const int*   ei = (const int*)d_in[2];
    const float *c1_ew1 = (const float*)d_in[3],  *c1_eb1 = (const float*)d_in[4];
    const float *c1_ew2 = (const float*)d_in[5],  *c1_eb2 = (const float*)d_in[6];
    const float *c1_nw1 = (const float*)d_in[7],  *c1_nb1 = (const float*)d_in[8];
    const float *c1_nw2 = (const float*)d_in[9],  *c1_nb2 = (const float*)d_in[10];
    const float *c2_ew1 = (const float*)d_in[11], *c2_eb1 = (const float*)d_in[12];
    const float *c2_ew2 = (const float*)d_in[13], *c2_eb2 = (const float*)d_in[14];
    const float *c2_nw1 = (const float*)d_in[15], *c2_nb1 = (const float*)d_in[16];
    const float *c2_nw2 = (const float*)d_in[17], *c2_nb2 = (const float*)d_in[18];
    const float *c3_ew1 = (const float*)d_in[19], *c3_eb1 = (const float*)d_in[20];
    const float *c3_ew2 = (const float*)d_in[21], *c3_eb2 = (const float*)d_in[22];
    const float *c3_nw1 = (const float*)d_in[23], *c3_nb1 = (const float*)d_in[24];
    const float *c3_nw2 = (const float*)d_in[25], *c3_nb2 = (const float*)d_in[26];
    const float *node_w1 = (const float*)d_in[27], *node_b1 = (const float*)d_in[28];
    const float *node_w2 = (const float*)d_in[29], *node_b2 = (const float*)d_in[30];
    const float *edge_w1 = (const float*)d_in[31], *edge_b1 = (const float*)d_in[32];
    const float *edge_w2 = (const float*)d_in[33], *edge_b2 = (const float*)d_in[34];

    float* out_n = (float*)d_out;                         // N*3
    float* out_e = out_n + (size_t)NN * 3;                // E*3

    const int B = 256;
    const int gn = (NN + B - 1) / B;            // 391
    const int ge = (NE + B - 1) / B;            // 12500
    const int gq = (NN * 4 + B - 1) / B;        // 1563

    // sorted path needs: ebuf(NE*32) + eid(NE*4) + srcs(NE*4) + start + Pa/Pc/xnbf
    const size_t NEED_SORTED = (size_t)NE*32 + (size_t)NE*4*2 + ((size_t)(NN+1)*4 + 64)
                             + (size_t)NN*32*3 + 256;

    if (ws_size >= NEED_SORTED) {
        // ---------------- SORTED PATH ----------------
        char* w = (char*)d_ws;
        unsigned short* ebuf = (unsigned short*)w;        // NE*32 B; build scratch aliases inside:
        int* next = (int*)w;                              //   NE*4
        int* head = next + NE;                            //   NN*4
        int* deg  = head + NN;                            //   NN*4
        int* bsum = deg + NN;                             //   1 KB   (all dead before conv1_edge_s)
        w += (size_t)NE * 32;
        int* eid  = (int*)w;  w += (size_t)NE * 4;
        int* srcs = (int*)w;  w += (size_t)NE * 4;
        int* start = (int*)w; w += ((size_t)(NN + 1) * 4 + 63) & ~63ull;
        unsigned short* Pa   = (unsigned short*)w;  w += (size_t)NN * 32;
        unsigned short* Pc   = (unsigned short*)w;  w += (size_t)NN * 32;
        unsigned short* xnbf = (unsigned short*)w;

        // scratch inside out_e region (dead before conv3's edge kernel writes out_e)
        unsigned short* ea_s = (unsigned short*)out_e;                 // NE*8 B bf16x4
        float* agg = (float*)((char*)out_e + (size_t)NE * 8);          // NN*16 f32

        // build
        kinit_head<<<gn, B, 0, stream>>>(head);
        kbuild<<<ge, B, 0, stream>>>(ei, head, next);
        kdeg<<<gn, B, 0, stream>>>(head, next, deg);
        kscan1<<<NB_SCAN, SCAN_B, 0, stream>>>(deg, start, bsum);
        kscan2<<<1, 256, 0, stream>>>(bsum);
        kscan3<<<gn, B, 0, stream>>>(start, bsum);
        prep1<<<gn, B, 0, stream>>>(x, c1_ew1, Pa, Pc);
        kfill<<<gn, B, 0, stream>>>(head, next, ei, ea, x, start, eid, srcs, ea_s, agg);

        // conv1 (kfill already produced agg3)
        conv1_edge_s<<<ge, B, 0, stream>>>(start, srcs, ea_s, Pa, Pc,
                                           c1_ew1, c1_eb1, c1_ew2, c1_eb2, ebuf);
        conv1_node<<<gn, B, 0, stream>>>(agg, x, c1_nw1, c1_nb1, c1_nw2, c1_nb2,
                                         c2_ew1, Pa, Pc, xnbf);
        // conv2
        kagg16_s<<<gq, B, 0, stream>>>(start, srcs, ebuf, xnbf, agg);
        conv_edge16_s<false><<<ge, B, 0, stream>>>(start, srcs, ebuf, Pa, Pc,
                                                   c2_ew1, c2_eb1, c2_ew2, c2_eb2,
                                                   nullptr, nullptr, nullptr, nullptr, nullptr, nullptr);
        node_mid<<<gn, B, 0, stream>>>(agg, c2_nw1, c2_nb1, c2_nw2, c2_nb2,
                                       c3_ew1, Pa, Pc, xnbf);
        // conv3 (node side first: consumes agg before edge kernel overwrites out_e)
        kagg16_s<<<gq, B, 0, stream>>>(start, srcs, ebuf, xnbf, agg);
        node_last<<<gn, B, 0, stream>>>(agg, xnbf, c3_nw1, c3_nb1, c3_nw2, c3_nb2,
                                        node_w1, node_b1, node_w2, node_b2, out_n);
        conv_edge16_s<true><<<ge, B, 0, stream>>>(start, srcs, ebuf, Pa, Pc,
                                                  c3_ew1, c3_eb1, c3_ew2, c3_eb2,
                                                  eid, edge_w1, edge_b1, edge_w2, edge_b2, out_e);
    } else {
        // ---------------- FALLBACK PATH (round-3 linked-list) ----------------
        char* w = (char*)d_ws;
        unsigned short* ebuf = (unsigned short*)w;            w += (size_t)NE * 16 * 2;
        int* next = (int*)w;                                  w += (size_t)NE * 4;
        int* head = (int*)w;                                  w += ((size_t)NN * 4 + 63) & ~63ull;
        unsigned short* Pa   = (unsigned short*)w;            w += (size_t)NN * 16 * 2;
        unsigned short* Pc   = (unsigned short*)w;            w += (size_t)NN * 16 * 2;
        unsigned short* xnbf = (unsigned short*)w;

        float* agg = out_e;   // N*16 f32 scratch inside edge-out region

        kinit_head<<<gn, B, 0, stream>>>(head);
        kbuild<<<ge, B, 0, stream>>>(ei, head, next);

        prep1<<<gn, B, 0, stream>>>(x, c1_ew1, Pa, Pc);
        kagg3_list<<<gq, B, 0, stream>>>(head, next, ei, x, ea, agg);
        conv1_edge_l<<<ge, B, 0, stream>>>(ei, ea, Pa, Pc, c1_ew1, c1_eb1, c1_ew2, c1_eb2, ebuf);
        conv1_node<<<gn, B, 0, stream>>>(agg, x, c1_nw1, c1_nb1, c1_nw2, c1_nb2,
                                         c2_ew1, Pa, Pc, xnbf);

        kagg16_list<<<gq, B, 0, stream>>>(head, next, ei, ebuf, xnbf, agg);
        conv_edge16_l<false><<<ge, B, 0, stream>>>(ei, ebuf, Pa, Pc,
                                                   c2_ew1, c2_eb1, c2_ew2, c2_eb2, ebuf,
                                                   nullptr, nullptr, nullptr, nullptr, nullptr);
        node_mid<<<gn, B, 0, stream>>>(agg, c2_nw1, c2_nb1, c2_nw2, c2_nb2,
                                       c3_ew1, Pa, Pc, xnbf);

        kagg16_list<<<gq, B, 0, stream>>>(head, next, ei, ebuf, xnbf, agg);
        node_last<<<gn, B, 0, stream>>>(agg, xnbf, c3_nw1, c3_nb1, c3_nw2, c3_nb2,
                                        node_w1, node_b1, node_w2, node_b2, out_n);
        conv_edge16_l<true><<<ge, B, 0, stream>>>(ei, ebuf, Pa, Pc,
                                                  c3_ew1, c3_eb1, c3_ew2, c3_eb2, nullptr,
                                                  edge_w1, edge_b1, edge_w2, edge_b2, out_e);
    }
}

// Round 5
// 996.525 us; speedup vs baseline: 5.7762x; 1.0029x over previous
//
#include <hip/hip_runtime.h>
#include <hip/hip_bf16.h>

// GINE 3-conv GNN, dst-sorted edge layout built per call.
// Build: 4 linked lists/node with packed 16B records -> scan -> parallel fill.
// Convs stream ebuf in slot space; dst via binary search on start[].
// N=100000, E=3200000, H=16. fp32 in/out; edge_index int32 rows [src | dst].

#define NN 100000
#define NE 3200000
#define SCAN_B 512
#define NB_SCAN ((NN + SCAN_B - 1) / SCAN_B)   // 196

__device__ __forceinline__ float bf2f(unsigned int h) {
    unsigned int u = h << 16;
    float f; __builtin_memcpy(&f, &u, 4); return f;
}
__device__ __forceinline__ unsigned short f2bf(float f) {
    unsigned int u; __builtin_memcpy(&u, &f, 4);
    u += 0x7fffu + ((u >> 16) & 1u);          // RNE
    return (unsigned short)(u >> 16);
}
__device__ __forceinline__ void ldbf16x16(const unsigned short* p, float* r) {
    const uint4* q = reinterpret_cast<const uint4*>(p);
    uint4 a = q[0], b = q[1];
    unsigned int w[8] = {a.x, a.y, a.z, a.w, b.x, b.y, b.z, b.w};
    #pragma unroll
    for (int k = 0; k < 8; ++k) {
        r[2*k]   = bf2f(w[k] & 0xffffu);
        r[2*k+1] = bf2f(w[k] >> 16);
    }
}
__device__ __forceinline__ void stbf16x16(unsigned short* p, const float* r) {
    unsigned int w[8];
    #pragma unroll
    for (int k = 0; k < 8; ++k)
        w[k] = (unsigned int)f2bf(r[2*k]) | ((unsigned int)f2bf(r[2*k+1]) << 16);
    uint4* q = reinterpret_cast<uint4*>(p);
    q[0] = make_uint4(w[0], w[1], w[2], w[3]);
    q[1] = make_uint4(w[4], w[5], w[6], w[7]);
}

// slot j -> dst node: largest n with start[n] <= j (start L2-resident)
__device__ __forceinline__ int slot2dst(const int* __restrict__ start, int j) {
    int lo = 0, hi = NN;
    while (hi - lo > 1) {
        int mid = (lo + hi) >> 1;
        if (start[mid] <= j) lo = mid; else hi = mid;
    }
    return lo;
}

// ---------------- build ----------------

__global__ void kinit4(int* head4, int* deg4) {
    int i = blockIdx.x * blockDim.x + threadIdx.x;
    if (i < 4 * NN) { head4[i] = -1; deg4[i] = 0; }
}

// e-order streaming: pack rec[e] = {next, src, bf16(ea0,ea1), bf16(ea2)}; count deg4.
__global__ void kbuild_pack(const int* __restrict__ ei, const float* __restrict__ ea,
                            int* head4, int* deg4, int4* __restrict__ rec) {
    int e = blockIdx.x * blockDim.x + threadIdx.x;
    if (e >= NE) return;
    int s = ei[e], d = ei[NE + e];
    float e0 = ea[(size_t)3*e], e1 = ea[(size_t)3*e+1], e2 = ea[(size_t)3*e+2];
    int q = e & 3;
    int old = atomicExch(&head4[q * NN + d], e);
    atomicAdd(&deg4[q * NN + d], 1);
    int4 r;
    r.x = old;
    r.y = s;
    r.z = (int)((unsigned int)f2bf(e0) | ((unsigned int)f2bf(e1) << 16));
    r.w = (int)(unsigned int)f2bf(e2);
    rec[e] = r;
}

// per-block inclusive scan of (sum_q deg4[q][i]) -> start[i+1]; block totals -> bsum
__global__ void kscan1_4(const int* __restrict__ deg4, int* __restrict__ start, int* __restrict__ bsum) {
    int t = threadIdx.x, b = blockIdx.x;
    int i = b * SCAN_B + t;
    int v = 0;
    if (i < NN)
        v = deg4[i] + deg4[NN + i] + deg4[2*NN + i] + deg4[3*NN + i];
    int lane = t & 63, wid = t >> 6;
    #pragma unroll
    for (int off = 1; off < 64; off <<= 1) {
        int u = __shfl_up(v, off);
        if (lane >= off) v += u;
    }
    __shared__ int wsum[8];
    if (lane == 63) wsum[wid] = v;
    __syncthreads();
    if (t < 8) {
        int w = wsum[t];
        #pragma unroll
        for (int off = 1; off < 8; off <<= 1) {
            int u = __shfl_up(w, off);
            if (t >= off) w += u;
        }
        wsum[t] = w;
    }
    __syncthreads();
    if (wid > 0) v += wsum[wid - 1];
    if (i < NN) start[i + 1] = v;
    if (t == SCAN_B - 1) bsum[b] = v;
}

__global__ void kscan2(int* bsum) {
    __shared__ int s[256];
    int t = threadIdx.x;
    s[t] = (t < NB_SCAN) ? bsum[t] : 0;
    __syncthreads();
    for (int off = 1; off < 256; off <<= 1) {
        int u = (t >= off) ? s[t - off] : 0;
        __syncthreads();
        s[t] += u;
        __syncthreads();
    }
    if (t < NB_SCAN) bsum[t] = s[t];
}

__global__ void kscan3(int* __restrict__ start, const int* __restrict__ bsum) {
    int i = blockIdx.x * blockDim.x + threadIdx.x;
    if (i >= NN) return;
    int b = i >> 9;                 // SCAN_B = 512
    int off = (b > 0) ? bsum[b - 1] : 0;
    start[i + 1] += off;
    if (i == 0) start[0] = 0;
}

// 4 threads/node, each walks its own sub-list (one 16B rec line per hop).
__global__ void kfill4(const int* __restrict__ head4, const int* __restrict__ deg4,
                       const int4* __restrict__ rec, const int* __restrict__ start,
                       int* __restrict__ eid, int* __restrict__ srcs,
                       unsigned short* __restrict__ ea_s) {
    int t = blockIdx.x * blockDim.x + threadIdx.x;
    int n = t >> 2, q = t & 3;
    if (n >= NN) return;
    int j = start[n];
    #pragma unroll
    for (int k = 0; k < 3; ++k)
        if (k < q) j += deg4[k * NN + n];
    int e = head4[q * NN + n];
    while (e >= 0) {
        int4 r = rec[e];
        eid[j] = e;
        srcs[j] = r.y;
        *reinterpret_cast<uint2*>(ea_s + (size_t)j*4) = make_uint2((unsigned int)r.z, (unsigned int)r.w);
        ++j;
        e = r.x;
    }
}

// conv1 aggregation, slot-space streaming: agg3[n] = sum relu(x[src]+ea).
// 4 consecutive lanes per node, interleaved j, shfl reduce.
__global__ void kagg3_s(const int* __restrict__ start, const int* __restrict__ srcs,
                        const unsigned short* __restrict__ ea_s,
                        const float* __restrict__ x, float* __restrict__ agg) {
    int t = blockIdx.x * blockDim.x + threadIdx.x;
    int n = t >> 2, q = t & 3;
    if (n >= NN) return;
    int j0 = start[n], j1 = start[n+1];
    float a0 = 0.f, a1 = 0.f, a2 = 0.f;
    for (int j = j0 + q; j < j1; j += 4) {
        uint2 w = *reinterpret_cast<const uint2*>(ea_s + (size_t)j*4);
        int s = srcs[j];
        a0 += fmaxf(x[3*s  ] + bf2f(w.x & 0xffffu), 0.f);
        a1 += fmaxf(x[3*s+1] + bf2f(w.x >> 16),     0.f);
        a2 += fmaxf(x[3*s+2] + bf2f(w.y & 0xffffu), 0.f);
    }
    a0 += __shfl_xor(a0, 1); a0 += __shfl_xor(a0, 2);
    a1 += __shfl_xor(a1, 1); a1 += __shfl_xor(a1, 2);
    a2 += __shfl_xor(a2, 1); a2 += __shfl_xor(a2, 2);
    if (q == 0) {
        float* p = agg + (size_t)n*16;
        p[0] = a0; p[1] = a1; p[2] = a2;
    }
}

// ---------------- node-side kernels ----------------

__global__ void prep1(const float* __restrict__ x, const float* __restrict__ ew1,
                      unsigned short* __restrict__ Pa, unsigned short* __restrict__ Pc) {
    int n = blockIdx.x * blockDim.x + threadIdx.x;
    if (n >= NN) return;
    float x0 = x[3*n], x1 = x[3*n+1], x2 = x[3*n+2];
    float pa[16], pc[16];
    #pragma unroll
    for (int j = 0; j < 16; ++j) {
        pa[j] = x0*ew1[0*16+j] + x1*ew1[1*16+j] + x2*ew1[2*16+j];
        pc[j] = x0*ew1[6*16+j] + x1*ew1[7*16+j] + x2*ew1[8*16+j];
    }
    stbf16x16(Pa + (size_t)n*16, pa);
    stbf16x16(Pc + (size_t)n*16, pc);
}

__global__ void conv1_node(const float* __restrict__ agg, const float* __restrict__ x,
                           const float* __restrict__ nw1, const float* __restrict__ nb1,
                           const float* __restrict__ nw2, const float* __restrict__ nb2,
                           const float* __restrict__ next_ew1,
                           unsigned short* __restrict__ Pa, unsigned short* __restrict__ Pc,
                           unsigned short* __restrict__ xnbf) {
    int n = blockIdx.x * blockDim.x + threadIdx.x;
    if (n >= NN) return;
    float o0 = agg[(size_t)n*16+0] + x[3*n];
    float o1 = agg[(size_t)n*16+1] + x[3*n+1];
    float o2 = agg[(size_t)n*16+2] + x[3*n+2];
    float h[16];
    #pragma unroll
    for (int j = 0; j < 16; ++j)
        h[j] = fmaxf(nb1[j] + o0*nw1[0*16+j] + o1*nw1[1*16+j] + o2*nw1[2*16+j], 0.f);
    float xn[16];
    #pragma unroll
    for (int j = 0; j < 16; ++j) {
        float a = nb2[j];
        #pragma unroll
        for (int i = 0; i < 16; ++i) a = fmaf(h[i], nw2[i*16+j], a);
        xn[j] = fmaxf(a, 0.f);
    }
    float pa[16], pc[16];
    #pragma unroll
    for (int j = 0; j < 16; ++j) {
        float sa = 0.f, sc = 0.f;
        #pragma unroll
        for (int i = 0; i < 16; ++i) {
            sa = fmaf(xn[i], next_ew1[i*16+j], sa);
            sc = fmaf(xn[i], next_ew1[(32+i)*16+j], sc);
        }
        pa[j] = sa; pc[j] = sc;
    }
    stbf16x16(xnbf + (size_t)n*16, xn);
    stbf16x16(Pa + (size_t)n*16, pa);
    stbf16x16(Pc + (size_t)n*16, pc);
}

__global__ void node_mid(const float* __restrict__ agg,
                         const float* __restrict__ nw1, const float* __restrict__ nb1,
                         const float* __restrict__ nw2, const float* __restrict__ nb2,
                         const float* __restrict__ next_ew1,
                         unsigned short* __restrict__ Pa, unsigned short* __restrict__ Pc,
                         unsigned short* xnbf) {
    int n = blockIdx.x * blockDim.x + threadIdx.x;
    if (n >= NN) return;
    float o[16];
    ldbf16x16(xnbf + (size_t)n*16, o);
    #pragma unroll
    for (int j = 0; j < 16; ++j) o[j] += agg[(size_t)n*16 + j];
    float h[16];
    #pragma unroll
    for (int j = 0; j < 16; ++j) {
        float a = nb1[j];
        #pragma unroll
        for (int i = 0; i < 16; ++i) a = fmaf(o[i], nw1[i*16+j], a);
        h[j] = fmaxf(a, 0.f);
    }
    float xn[16];
    #pragma unroll
    for (int j = 0; j < 16; ++j) {
        float a = nb2[j];
        #pragma unroll
        for (int i = 0; i < 16; ++i) a = fmaf(h[i], nw2[i*16+j], a);
        xn[j] = fmaxf(a, 0.f);
    }
    float pa[16], pc[16];
    #pragma unroll
    for (int j = 0; j < 16; ++j) {
        float sa = 0.f, sc = 0.f;
        #pragma unroll
        for (int i = 0; i < 16; ++i) {
            sa = fmaf(xn[i], next_ew1[i*16+j], sa);
            sc = fmaf(xn[i], next_ew1[(32+i)*16+j], sc);
        }
        pa[j] = sa; pc[j] = sc;
    }
    stbf16x16(xnbf + (size_t)n*16, xn);
    stbf16x16(Pa + (size_t)n*16, pa);
    stbf16x16(Pc + (size_t)n*16, pc);
}

__global__ void node_last(const float* __restrict__ agg, const unsigned short* __restrict__ xnbf,
                          const float* __restrict__ nw1, const float* __restrict__ nb1,
                          const float* __restrict__ nw2, const float* __restrict__ nb2,
                          const float* __restrict__ hw1, const float* __restrict__ hb1,
                          const float* __restrict__ hw2, const float* __restrict__ hb2,
                          float* __restrict__ out_n) {
    int n = blockIdx.x * blockDim.x + threadIdx.x;
    if (n >= NN) return;
    float o[16];
    ldbf16x16(xnbf + (size_t)n*16, o);
    #pragma unroll
    for (int j = 0; j < 16; ++j) o[j] += agg[(size_t)n*16 + j];
    float h[16];
    #pragma unroll
    for (int j = 0; j < 16; ++j) {
        float a = nb1[j];
        #pragma unroll
        for (int i = 0; i < 16; ++i) a = fmaf(o[i], nw1[i*16+j], a);
        h[j] = fmaxf(a, 0.f);
    }
    float xn[16];
    #pragma unroll
    for (int j = 0; j < 16; ++j) {
        float a = nb2[j];
        #pragma unroll
        for (int i = 0; i < 16; ++i) a = fmaf(h[i], nw2[i*16+j], a);
        xn[j] = fmaxf(a, 0.f);
    }
    float g[16];
    #pragma unroll
    for (int j = 0; j < 16; ++j) {
        float a = hb1[j];
        #pragma unroll
        for (int i = 0; i < 16; ++i) a = fmaf(xn[i], hw1[i*16+j], a);
        g[j] = fmaxf(a, 0.f);
    }
    #pragma unroll
    for (int k = 0; k < 3; ++k) {
        float a = hb2[k];
        #pragma unroll
        for (int i = 0; i < 16; ++i) a = fmaf(g[i], hw2[i*3+k], a);
        out_n[(size_t)n*3 + k] = a;
    }
}

// ---------------- edge kernels (slot space) ----------------

__global__ void conv1_edge_s(const int* __restrict__ start, const int* __restrict__ srcs,
                             const unsigned short* __restrict__ ea_s,
                             const unsigned short* __restrict__ Pa, const unsigned short* __restrict__ Pc,
                             const float* __restrict__ ew1, const float* __restrict__ eb1,
                             const float* __restrict__ ew2, const float* __restrict__ eb2,
                             unsigned short* __restrict__ ebuf) {
    int j = blockIdx.x * blockDim.x + threadIdx.x;
    if (j >= NE) return;
    int t = slot2dst(start, j);
    int s = srcs[j];
    uint2 wv = *reinterpret_cast<const uint2*>(ea_s + (size_t)j*4);
    float e0 = bf2f(wv.x & 0xffffu), e1 = bf2f(wv.x >> 16), e2 = bf2f(wv.y & 0xffffu);
    float h[16], pc[16];
    ldbf16x16(Pa + (size_t)s*16, h);
    ldbf16x16(Pc + (size_t)t*16, pc);
    #pragma unroll
    for (int jj = 0; jj < 16; ++jj) {
        float a = h[jj] + pc[jj] + eb1[jj]
                + e0*ew1[3*16+jj] + e1*ew1[4*16+jj] + e2*ew1[5*16+jj];
        h[jj] = fmaxf(a, 0.f);
    }
    float h2[16];
    #pragma unroll
    for (int jj = 0; jj < 16; ++jj) {
        float a = eb2[jj];
        #pragma unroll
        for (int i = 0; i < 16; ++i) a = fmaf(h[i], ew2[i*16+jj], a);
        h2[jj] = fmaxf(a, 0.f);
    }
    stbf16x16(ebuf + (size_t)j*16, h2);
}

template <bool LAST>
__global__ void conv_edge16_s(const int* __restrict__ start, const int* __restrict__ srcs,
                              unsigned short* ebuf,          // in-place per slot
                              const unsigned short* __restrict__ Pa, const unsigned short* __restrict__ Pc,
                              const float* __restrict__ ew1, const float* __restrict__ eb1,
                              const float* __restrict__ ew2, const float* __restrict__ eb2,
                              const int* __restrict__ eid,
                              const float* __restrict__ hw1, const float* __restrict__ hb1,
                              const float* __restrict__ hw2, const float* __restrict__ hb2,
                              float* __restrict__ out_e) {
    int j = blockIdx.x * blockDim.x + threadIdx.x;
    if (j >= NE) return;
    int t = slot2dst(start, j);
    int s = srcs[j];
    float ein[16], h[16], pc[16];
    ldbf16x16(ebuf + (size_t)j*16, ein);
    ldbf16x16(Pa + (size_t)s*16, h);
    ldbf16x16(Pc + (size_t)t*16, pc);
    #pragma unroll
    for (int jj = 0; jj < 16; ++jj) h[jj] = h[jj] + pc[jj] + eb1[jj];
    #pragma unroll
    for (int i = 0; i < 16; ++i) {
        #pragma unroll
        for (int jj = 0; jj < 16; ++jj) h[jj] = fmaf(ein[i], ew1[(16+i)*16+jj], h[jj]);
    }
    #pragma unroll
    for (int jj = 0; jj < 16; ++jj) h[jj] = fmaxf(h[jj], 0.f);
    float h2[16];
    #pragma unroll
    for (int jj = 0; jj < 16; ++jj) {
        float a = eb2[jj];
        #pragma unroll
        for (int i = 0; i < 16; ++i) a = fmaf(h[i], ew2[i*16+jj], a);
        h2[jj] = fmaxf(a, 0.f);
    }
    if (!LAST) {
        stbf16x16(ebuf + (size_t)j*16, h2);
    } else {
        float g[16];
        #pragma unroll
        for (int jj = 0; jj < 16; ++jj) {
            float a = hb1[jj];
            #pragma unroll
            for (int i = 0; i < 16; ++i) a = fmaf(h2[i], hw1[i*16+jj], a);
            g[jj] = fmaxf(a, 0.f);
        }
        int e = eid[j];
        #pragma unroll
        for (int k = 0; k < 3; ++k) {
            float a = hb2[k];
            #pragma unroll
            for (int i = 0; i < 16; ++i) a = fmaf(g[i], hw2[i*3+k], a);
            out_e[(size_t)e*3 + k] = a;
        }
    }
}

// 4 threads/node; streams the node's contiguous slot segment.
__global__ void kagg16_s(const int* __restrict__ start, const int* __restrict__ srcs,
                         const unsigned short* __restrict__ ebuf,
                         const unsigned short* __restrict__ xnbf, float* __restrict__ agg) {
    int tg = blockIdx.x * blockDim.x + threadIdx.x;
    int n = tg >> 2, q = tg & 3;
    if (n >= NN) return;
    int j0 = start[n], j1 = start[n+1];
    float a0 = 0.f, a1 = 0.f, a2 = 0.f, a3 = 0.f;
    for (int j = j0; j < j1; ++j) {
        int s = srcs[j];
        uint2 w  = *reinterpret_cast<const uint2*>(ebuf + (size_t)j*16 + q*4);
        uint2 xw = *reinterpret_cast<const uint2*>(xnbf + (size_t)s*16 + q*4);
        a0 += fmaxf(bf2f(xw.x & 0xffffu) + bf2f(w.x & 0xffffu), 0.f);
        a1 += fmaxf(bf2f(xw.x >> 16)     + bf2f(w.x >> 16),     0.f);
        a2 += fmaxf(bf2f(xw.y & 0xffffu) + bf2f(w.y & 0xffffu), 0.f);
        a3 += fmaxf(bf2f(xw.y >> 16)     + bf2f(w.y >> 16),     0.f);
    }
    *reinterpret_cast<float4*>(agg + (size_t)n*16 + q*4) = make_float4(a0, a1, a2, a3);
}

// ---------------- FALLBACK path (round-3 linked-list, known-pass) ----------------

__global__ void kinit_head(int* head) {
    int i = blockIdx.x * blockDim.x + threadIdx.x;
    if (i < NN) head[i] = -1;
}
__global__ void kbuild(const int* __restrict__ ei, int* head, int* __restrict__ next) {
    int e = blockIdx.x * blockDim.x + threadIdx.x;
    if (e >= NE) return;
    int d = ei[NE + e];
    int old = atomicExch(&head[d], e);
    next[e] = old;
}
__global__ void kagg3_list(const int* __restrict__ head, const int* __restrict__ next,
                           const int* __restrict__ ei, const float* __restrict__ x,
                           const float* __restrict__ ea, float* __restrict__ agg) {
    int t = blockIdx.x * blockDim.x + threadIdx.x;
    int n = t >> 2, q = t & 3;
    if (n >= NN) return;
    float a = 0.f;
    int e = head[n];
    while (e >= 0) {
        int s = ei[e];
        if (q < 3) a += fmaxf(x[3*s + q] + ea[(size_t)3*e + q], 0.f);
        e = next[e];
    }
    if (q < 3) agg[(size_t)n*16 + q] = a;
}
__global__ void kagg16_list(const int* __restrict__ head, const int* __restrict__ next,
                            const int* __restrict__ ei, const unsigned short* __restrict__ ebuf,
                            const unsigned short* __restrict__ xnbf, float* __restrict__ agg) {
    int t = blockIdx.x * blockDim.x + threadIdx.x;
    int n = t >> 2, q = t & 3;
    if (n >= NN) return;
    float a0 = 0.f, a1 = 0.f, a2 = 0.f, a3 = 0.f;
    int e = head[n];
    while (e >= 0) {
        int s = ei[e];
        uint2 w  = *reinterpret_cast<const uint2*>(ebuf + (size_t)e*16 + q*4);
        uint2 xw = *reinterpret_cast<const uint2*>(xnbf + (size_t)s*16 + q*4);
        a0 += fmaxf(bf2f(xw.x & 0xffffu) + bf2f(w.x & 0xffffu), 0.f);
        a1 += fmaxf(bf2f(xw.x >> 16)     + bf2f(w.x >> 16),     0.f);
        a2 += fmaxf(bf2f(xw.y & 0xffffu) + bf2f(w.y & 0xffffu), 0.f);
        a3 += fmaxf(bf2f(xw.y >> 16)     + bf2f(w.y >> 16),     0.f);
        e = next[e];
    }
    *reinterpret_cast<float4*>(agg + (size_t)n*16 + q*4) = make_float4(a0, a1, a2, a3);
}
__global__ void conv1_edge_l(const int* __restrict__ ei, const float* __restrict__ ea,
                             const unsigned short* __restrict__ Pa, const unsigned short* __restrict__ Pc,
                             const float* __restrict__ ew1, const float* __restrict__ eb1,
                             const float* __restrict__ ew2, const float* __restrict__ eb2,
                             unsigned short* __restrict__ ebuf) {
    int e = blockIdx.x * blockDim.x + threadIdx.x;
    if (e >= NE) return;
    int s = ei[e], t = ei[NE + e];
    float e0 = ea[(size_t)3*e], e1 = ea[(size_t)3*e+1], e2 = ea[(size_t)3*e+2];
    float h[16], pc[16];
    ldbf16x16(Pa + (size_t)s*16, h);
    ldbf16x16(Pc + (size_t)t*16, pc);
    #pragma unroll
    for (int j = 0; j < 16; ++j) {
        float a = h[j] + pc[j] + eb1[j]
                + e0*ew1[3*16+j] + e1*ew1[4*16+j] + e2*ew1[5*16+j];
        h[j] = fmaxf(a, 0.f);
    }
    float h2[16];
    #pragma unroll
    for (int j = 0; j < 16; ++j) {
        float a = eb2[j];
        #pragma unroll
        for (int i = 0; i < 16; ++i) a = fmaf(h[i], ew2[i*16+j], a);
        h2[j] = fmaxf(a, 0.f);
    }
    stbf16x16(ebuf + (size_t)e*16, h2);
}
template <bool LAST>
__global__ void conv_edge16_l(const int* __restrict__ ei, const unsigned short* __restrict__ ebuf_in,
                              const unsigned short* __restrict__ Pa, const unsigned short* __restrict__ Pc,
                              const float* __restrict__ ew1, const float* __restrict__ eb1,
                              const float* __restrict__ ew2, const float* __restrict__ eb2,
                              unsigned short* ebuf_out,
                              const float* __restrict__ hw1, const float* __restrict__ hb1,
                              const float* __restrict__ hw2, const float* __restrict__ hb2,
                              float* __restrict__ out_e) {
    int e = blockIdx.x * blockDim.x + threadIdx.x;
    if (e >= NE) return;
    int s = ei[e], t = ei[NE + e];
    float ein[16], h[16], pc[16];
    ldbf16x16(ebuf_in + (size_t)e*16, ein);
    ldbf16x16(Pa + (size_t)s*16, h);
    ldbf16x16(Pc + (size_t)t*16, pc);
    #pragma unroll
    for (int j = 0; j < 16; ++j) h[j] = h[j] + pc[j] + eb1[j];
    #pragma unroll
    for (int i = 0; i < 16; ++i) {
        #pragma unroll
        for (int j = 0; j < 16; ++j) h[j] = fmaf(ein[i], ew1[(16+i)*16+j], h[j]);
    }
    #pragma unroll
    for (int j = 0; j < 16; ++j) h[j] = fmaxf(h[j], 0.f);
    float h2[16];
    #pragma unroll
    for (int j = 0; j < 16; ++j) {
        float a = eb2[j];
        #pragma unroll
        for (int i = 0; i < 16; ++i) a = fmaf(h[i], ew2[i*16+j], a);
        h2[j] = fmaxf(a, 0.f);
    }
    if (!LAST) {
        stbf16x16(ebuf_out + (size_t)e*16, h2);
    } else {
        float g[16];
        #pragma unroll
        for (int j = 0; j < 16; ++j) {
            float a = hb1[j];
            #pragma unroll
            for (int i = 0; i < 16; ++i) a = fmaf(h2[i], hw1[i*16+j], a);
            g[j] = fmaxf(a, 0.f);
        }
        #pragma unroll
        for (int k = 0; k < 3; ++k) {
            float a = hb2[k];
            #pragma unroll
            for (int i = 0; i < 16; ++i) a = fmaf(g[i], hw2[i*3+k], a);
            out_e[(size_t)e*3 + k] = a;
        }
    }
}

extern "C" void kernel_launch(void* const* d_in, const int* in_sizes, int n_in,
                              void* d_out, int out_size, void* d_ws, size_t ws_size,
                              hipStream_t stream) {
    const float* x  = (const float*)d_in[0];
    const float* ea = (const float*)d_in[1];
    const int*   ei = (const int*)d_in[2];
    const float *c1_ew1 = (const float*)d_in[3],  *c1_eb1 = (const float*)d_in[4];
    const float *c1_ew2 = (const float*)d_in[5],  *c1_eb2 = (const float*)d_in[6];
    const float *c1_nw1 = (const float*)d_in[7],  *c1_nb1 = (const float*)d_in[8];
    const float *c1_nw2 = (const float*)d_in[9],  *c1_nb2 = (const float*)d_in[10];
    const float *c2_ew1 = (const float*)d_in[11], *c2_eb1 = (const float*)d_in[12];
    const float *c2_ew2 = (const float*)d_in[13], *c2_eb2 = (const float*)d_in[14];
    const float *c2_nw1 = (const float*)d_in[15], *c2_nb1 = (const float*)d_in[16];
    const float *c2_nw2 = (const float*)d_in[17], *c2_nb2 = (const float*)d_in[18];
    const float *c3_ew1 = (const float*)d_in[19], *c3_eb1 = (const float*)d_in[20];
    const float *c3_ew2 = (const float*)d_in[21], *c3_eb2 = (const float*)d_in[22];
    const float *c3_nw1 = (const float*)d_in[23], *c3_nb1 = (const float*)d_in[24];
    const float *c3_nw2 = (const float*)d_in[25], *c3_nb2 = (const float*)d_in[26];
    const float *node_w1 = (const float*)d_in[27], *node_b1 = (const float*)d_in[28];
    const float *node_w2 = (const float*)d_in[29], *node_b2 = (const float*)d_in[30];
    const float *edge_w1 = (const float*)d_in[31], *edge_b1 = (const float*)d_in[32];
    const float *edge_w2 = (const float*)d_in[33], *edge_b2 = (const float*)d_in[34];

    float* out_n = (float*)d_out;                         // N*3
    float* out_e = out_n + (size_t)NN * 3;                // E*3

    const int B = 256;
    const int gn  = (NN + B - 1) / B;            // 391
    const int ge  = (NE + B - 1) / B;            // 12500
    const int gq  = (NN * 4 + B - 1) / B;        // 1563

    // same footprint as round-4's proven NEED_SORTED
    const size_t NEED_SORTED = (size_t)NE*32 + (size_t)NE*4*2 + ((size_t)(NN+1)*4 + 64)
                             + (size_t)NN*32*3 + 256;

    if (ws_size >= NEED_SORTED) {
        // ---------------- SORTED PATH ----------------
        char* w = (char*)d_ws;
        unsigned short* ebuf = (unsigned short*)w;        // NE*32 B; build scratch aliases inside:
        int4* rec  = (int4*)w;                            //   NE*16 = 51.2 MB
        int* head4 = (int*)(w + (size_t)NE*16);           //   4*NN*4 = 1.6 MB
        int* deg4  = head4 + 4*NN;                        //   1.6 MB
        int* bsum  = deg4 + 4*NN;                         //   1 KB  (all dead before conv1_edge_s)
        w += (size_t)NE * 32;
        int* eid  = (int*)w;  w += (size_t)NE * 4;
        int* srcs = (int*)w;  w += (size_t)NE * 4;
        int* start = (int*)w; w += ((size_t)(NN + 1) * 4 + 63) & ~63ull;
        unsigned short* Pa   = (unsigned short*)w;  w += (size_t)NN * 32;
        unsigned short* Pc   = (unsigned short*)w;  w += (size_t)NN * 32;
        unsigned short* xnbf = (unsigned short*)w;

        // scratch inside out_e region (dead before conv3's edge kernel writes out_e)
        unsigned short* ea_s = (unsigned short*)out_e;                 // NE*8 B bf16x4
        float* agg = (float*)((char*)out_e + (size_t)NE * 8);          // NN*16 f32

        // build
        kinit4<<<gq, B, 0, stream>>>(head4, deg4);
        kbuild_pack<<<ge, B, 0, stream>>>(ei, ea, head4, deg4, rec);
        kscan1_4<<<NB_SCAN, SCAN_B, 0, stream>>>(deg4, start, bsum);
        kscan2<<<1, 256, 0, stream>>>(bsum);
        kscan3<<<gn, B, 0, stream>>>(start, bsum);
        kfill4<<<gq, B, 0, stream>>>(head4, deg4, rec, start, eid, srcs, ea_s);

        // conv1
        prep1<<<gn, B, 0, stream>>>(x, c1_ew1, Pa, Pc);
        kagg3_s<<<gq, B, 0, stream>>>(start, srcs, ea_s, x, agg);
        conv1_edge_s<<<ge, B, 0, stream>>>(start, srcs, ea_s, Pa, Pc,
                                           c1_ew1, c1_eb1, c1_ew2, c1_eb2, ebuf);
        conv1_node<<<gn, B, 0, stream>>>(agg, x, c1_nw1, c1_nb1, c1_nw2, c1_nb2,
                                         c2_ew1, Pa, Pc, xnbf);
        // conv2
        kagg16_s<<<gq, B, 0, stream>>>(start, srcs, ebuf, xnbf, agg);
        conv_edge16_s<false><<<ge, B, 0, stream>>>(start, srcs, ebuf, Pa, Pc,
                                                   c2_ew1, c2_eb1, c2_ew2, c2_eb2,
                                                   nullptr, nullptr, nullptr, nullptr, nullptr, nullptr);
        node_mid<<<gn, B, 0, stream>>>(agg, c2_nw1, c2_nb1, c2_nw2, c2_nb2,
                                       c3_ew1, Pa, Pc, xnbf);
        // conv3 (node side first: consumes agg before edge kernel overwrites out_e)
        kagg16_s<<<gq, B, 0, stream>>>(start, srcs, ebuf, xnbf, agg);
        node_last<<<gn, B, 0, stream>>>(agg, xnbf, c3_nw1, c3_nb1, c3_nw2, c3_nb2,
                                        node_w1, node_b1, node_w2, node_b2, out_n);
        conv_edge16_s<true><<<ge, B, 0, stream>>>(start, srcs, ebuf, Pa, Pc,
                                                  c3_ew1, c3_eb1, c3_ew2, c3_eb2,
                                                  eid, edge_w1, edge_b1, edge_w2, edge_b2, out_e);
    } else {
        // ---------------- FALLBACK PATH ----------------
        char* w = (char*)d_ws;
        unsigned short* ebuf = (unsigned short*)w;            w += (size_t)NE * 16 * 2;
        int* next = (int*)w;                                  w += (size_t)NE * 4;
        int* head = (int*)w;                                  w += ((size_t)NN * 4 + 63) & ~63ull;
        unsigned short* Pa   = (unsigned short*)w;            w += (size_t)NN * 16 * 2;
        unsigned short* Pc   = (unsigned short*)w;            w += (size_t)NN * 16 * 2;
        unsigned short* xnbf = (unsigned short*)w;

        float* agg = out_e;

        kinit_head<<<gn, B, 0, stream>>>(head);
        kbuild<<<ge, B, 0, stream>>>(ei, head, next);
        prep1<<<gn, B, 0, stream>>>(x, c1_ew1, Pa, Pc);
        kagg3_list<<<gq, B, 0, stream>>>(head, next, ei, x, ea, agg);
        conv1_edge_l<<<ge, B, 0, stream>>>(ei, ea, Pa, Pc, c1_ew1, c1_eb1, c1_ew2, c1_eb2, ebuf);
        conv1_node<<<gn, B, 0, stream>>>(agg, x, c1_nw1, c1_nb1, c1_nw2, c1_nb2,
                                         c2_ew1, Pa, Pc, xnbf);
        kagg16_list<<<gq, B, 0, stream>>>(head, next, ei, ebuf, xnbf, agg);
        conv_edge16_l<false><<<ge, B, 0, stream>>>(ei, ebuf, Pa, Pc,
                                                   c2_ew1, c2_eb1, c2_ew2, c2_eb2, ebuf,
                                                   nullptr, nullptr, nullptr, nullptr, nullptr);
        node_mid<<<gn, B, 0, stream>>>(agg, c2_nw1, c2_nb1, c2_nw2, c2_nb2,
                                       c3_ew1, Pa, Pc, xnbf);
        kagg16_list<<<gq, B, 0, stream>>>(head, next, ei, ebuf, xnbf, agg);
        node_last<<<gn, B, 0, stream>>>(agg, xnbf, c3_nw1, c3_nb1, c3_nw2, c3_nb2,
                                        node_w1, node_b1, node_w2, node_b2, out_n);
        conv_edge16_l<true><<<ge, B, 0, stream>>>(ei, ebuf, Pa, Pc,
                                                  c3_ew1, c3_eb1, c3_ew2, c3_eb2, nullptr,
                                                  edge_w1, edge_b1, edge_w2, edge_b2, out_e);
    }
}

// Round 6
// 916.353 us; speedup vs baseline: 6.2816x; 1.0875x over previous
//
#include <hip/hip_runtime.h>
#include <hip/hip_bf16.h>

// GINE 3-conv GNN. Dst-grouped slot layout built per call with MINIMAL atomics:
//   kbuild2: 2 linked lists/node via atomicExch (3.2M atomics) + packed 16B recs
//   kwalk2 : per-chain len walk + ONE atomicAdd(gctr, len) per chain (200k atomics)
//            -> contiguous slot runs; writes sorted srec {src,dst,eid} u64 + bf16 ea
// Convs stream slots sequentially; per-slot dst read directly (no binary search).
// N=100000, E=3200000, H=16. fp32 in/out; edge_index int32 rows [src | dst].
//
// ws (137.6 MB <= proven 138.0 MB):
//   ebuf [E][16] bf16 (102.4M)   conv edge features; build aliases inside:
//       rec [E] int4 (51.2M) {next, src, bf16 ea01, bf16 ea2}, head2 [2N] int
//   srec [E] u64 (25.6M)         packed {src:17, dst:17, eid:22} per slot
//   Pa, Pc, xnbf [N][16] bf16 (9.6M),  gctr u32
// out_n region (1.2M): runpos [2N] u32 + runlen [2N] u16 (dead before node_last)
// out_e region (38.4M): ea_s [E] 8B bf16x4 (25.6M) + agg [N][16] f32 (6.4M)
//   (dead before conv3's edge kernel writes out_e)

#define NN 100000
#define NE 3200000

__device__ __forceinline__ float bf2f(unsigned int h) {
    unsigned int u = h << 16;
    float f; __builtin_memcpy(&f, &u, 4); return f;
}
__device__ __forceinline__ unsigned short f2bf(float f) {
    unsigned int u; __builtin_memcpy(&u, &f, 4);
    u += 0x7fffu + ((u >> 16) & 1u);          // RNE
    return (unsigned short)(u >> 16);
}
__device__ __forceinline__ void ldbf16x16(const unsigned short* p, float* r) {
    const uint4* q = reinterpret_cast<const uint4*>(p);
    uint4 a = q[0], b = q[1];
    unsigned int w[8] = {a.x, a.y, a.z, a.w, b.x, b.y, b.z, b.w};
    #pragma unroll
    for (int k = 0; k < 8; ++k) {
        r[2*k]   = bf2f(w[k] & 0xffffu);
        r[2*k+1] = bf2f(w[k] >> 16);
    }
}
__device__ __forceinline__ void stbf16x16(unsigned short* p, const float* r) {
    unsigned int w[8];
    #pragma unroll
    for (int k = 0; k < 8; ++k)
        w[k] = (unsigned int)f2bf(r[2*k]) | ((unsigned int)f2bf(r[2*k+1]) << 16);
    uint4* q = reinterpret_cast<uint4*>(p);
    q[0] = make_uint4(w[0], w[1], w[2], w[3]);
    q[1] = make_uint4(w[4], w[5], w[6], w[7]);
}

// ---------------- build ----------------

__global__ void kinit2(int* head2, unsigned int* gctr) {
    int i = blockIdx.x * blockDim.x + threadIdx.x;
    if (i < 2 * NN) head2[i] = -1;
    if (i == 2 * NN) *gctr = 0u;
}

// e-order streaming: single atomicExch per edge; rec[e]={next, src, bf16 ea}.
__global__ void kbuild2(const int* __restrict__ ei, const float* __restrict__ ea,
                        int* head2, int4* __restrict__ rec) {
    int e = blockIdx.x * blockDim.x + threadIdx.x;
    if (e >= NE) return;
    int s = ei[e], d = ei[NE + e];
    float e0 = ea[(size_t)3*e], e1 = ea[(size_t)3*e+1], e2 = ea[(size_t)3*e+2];
    int q = e & 1;
    int old = atomicExch(&head2[q * NN + d], e);
    int4 r;
    r.x = old;
    r.y = s;
    r.z = (int)((unsigned int)f2bf(e0) | ((unsigned int)f2bf(e1) << 16));
    r.w = (int)(unsigned int)f2bf(e2);
    rec[e] = r;
}

// One thread per chain (2 per node): count len, grab a contiguous run via one
// global fetch-add, then fill sorted srec/ea_s. Order within/between runs is
// atomic-completion order -> only perturbs fp summation order (in tolerance).
__global__ void kwalk2(const int* __restrict__ head2, const int4* __restrict__ rec,
                       unsigned long long* __restrict__ srec, unsigned int* __restrict__ ea_s,
                       unsigned int* __restrict__ runpos, unsigned short* __restrict__ runlen,
                       unsigned int* gctr) {
    int t = blockIdx.x * blockDim.x + threadIdx.x;
    if (t >= 2 * NN) return;
    int e0 = head2[t];
    int len = 0;
    for (int x = e0; x >= 0; ) { x = rec[x].x; ++len; }
    unsigned int pos = atomicAdd(gctr, (unsigned int)len);
    runpos[t] = pos;
    runlen[t] = (unsigned short)len;
    unsigned long long n = (unsigned long long)((t >= NN) ? t - NN : t);
    unsigned int j = pos;
    for (int x = e0; x >= 0; ++j) {
        int4 r = rec[x];
        srec[j] = (unsigned long long)(unsigned int)r.y
                | (n << 17)
                | ((unsigned long long)(unsigned int)x << 34);
        *reinterpret_cast<uint2*>(&ea_s[(size_t)2*j]) =
            make_uint2((unsigned int)r.z, (unsigned int)r.w);
        x = r.x;
    }
}

// conv1 aggregation: 2 threads/node (one per run); agg3[n] = sum relu(x[src]+ea).
__global__ void kagg3_s2(const unsigned int* __restrict__ runpos, const unsigned short* __restrict__ runlen,
                         const unsigned long long* __restrict__ srec, const unsigned int* __restrict__ ea_s,
                         const float* __restrict__ x, float* __restrict__ agg) {
    int t = blockIdx.x * blockDim.x + threadIdx.x;
    int n = t >> 1, q = t & 1;
    if (n >= NN) return;
    int h = q * NN + n;
    unsigned int j0 = runpos[h];
    int L = runlen[h];
    float a0 = 0.f, a1 = 0.f, a2 = 0.f;
    for (int i = 0; i < L; ++i) {
        unsigned int j = j0 + i;
        unsigned long long sr = srec[j];
        int s = (int)(sr & 0x1FFFFu);
        uint2 w = *reinterpret_cast<const uint2*>(&ea_s[(size_t)2*j]);
        a0 += fmaxf(x[3*s  ] + bf2f(w.x & 0xffffu), 0.f);
        a1 += fmaxf(x[3*s+1] + bf2f(w.x >> 16),     0.f);
        a2 += fmaxf(x[3*s+2] + bf2f(w.y & 0xffffu), 0.f);
    }
    a0 += __shfl_xor(a0, 1);
    a1 += __shfl_xor(a1, 1);
    a2 += __shfl_xor(a2, 1);
    if (q == 0) {
        float* p = agg + (size_t)n*16;
        p[0] = a0; p[1] = a1; p[2] = a2;
    }
}

// ---------------- node-side kernels ----------------

__global__ void prep1(const float* __restrict__ x, const float* __restrict__ ew1,
                      unsigned short* __restrict__ Pa, unsigned short* __restrict__ Pc) {
    int n = blockIdx.x * blockDim.x + threadIdx.x;
    if (n >= NN) return;
    float x0 = x[3*n], x1 = x[3*n+1], x2 = x[3*n+2];
    float pa[16], pc[16];
    #pragma unroll
    for (int j = 0; j < 16; ++j) {
        pa[j] = x0*ew1[0*16+j] + x1*ew1[1*16+j] + x2*ew1[2*16+j];
        pc[j] = x0*ew1[6*16+j] + x1*ew1[7*16+j] + x2*ew1[8*16+j];
    }
    stbf16x16(Pa + (size_t)n*16, pa);
    stbf16x16(Pc + (size_t)n*16, pc);
}

__global__ void conv1_node(const float* __restrict__ agg, const float* __restrict__ x,
                           const float* __restrict__ nw1, const float* __restrict__ nb1,
                           const float* __restrict__ nw2, const float* __restrict__ nb2,
                           const float* __restrict__ next_ew1,
                           unsigned short* __restrict__ Pa, unsigned short* __restrict__ Pc,
                           unsigned short* __restrict__ xnbf) {
    int n = blockIdx.x * blockDim.x + threadIdx.x;
    if (n >= NN) return;
    float o0 = agg[(size_t)n*16+0] + x[3*n];
    float o1 = agg[(size_t)n*16+1] + x[3*n+1];
    float o2 = agg[(size_t)n*16+2] + x[3*n+2];
    float h[16];
    #pragma unroll
    for (int j = 0; j < 16; ++j)
        h[j] = fmaxf(nb1[j] + o0*nw1[0*16+j] + o1*nw1[1*16+j] + o2*nw1[2*16+j], 0.f);
    float xn[16];
    #pragma unroll
    for (int j = 0; j < 16; ++j) {
        float a = nb2[j];
        #pragma unroll
        for (int i = 0; i < 16; ++i) a = fmaf(h[i], nw2[i*16+j], a);
        xn[j] = fmaxf(a, 0.f);
    }
    float pa[16], pc[16];
    #pragma unroll
    for (int j = 0; j < 16; ++j) {
        float sa = 0.f, sc = 0.f;
        #pragma unroll
        for (int i = 0; i < 16; ++i) {
            sa = fmaf(xn[i], next_ew1[i*16+j], sa);
            sc = fmaf(xn[i], next_ew1[(32+i)*16+j], sc);
        }
        pa[j] = sa; pc[j] = sc;
    }
    stbf16x16(xnbf + (size_t)n*16, xn);
    stbf16x16(Pa + (size_t)n*16, pa);
    stbf16x16(Pc + (size_t)n*16, pc);
}

__global__ void node_mid(const float* __restrict__ agg,
                         const float* __restrict__ nw1, const float* __restrict__ nb1,
                         const float* __restrict__ nw2, const float* __restrict__ nb2,
                         const float* __restrict__ next_ew1,
                         unsigned short* __restrict__ Pa, unsigned short* __restrict__ Pc,
                         unsigned short* xnbf) {
    int n = blockIdx.x * blockDim.x + threadIdx.x;
    if (n >= NN) return;
    float o[16];
    ldbf16x16(xnbf + (size_t)n*16, o);
    #pragma unroll
    for (int j = 0; j < 16; ++j) o[j] += agg[(size_t)n*16 + j];
    float h[16];
    #pragma unroll
    for (int j = 0; j < 16; ++j) {
        float a = nb1[j];
        #pragma unroll
        for (int i = 0; i < 16; ++i) a = fmaf(o[i], nw1[i*16+j], a);
        h[j] = fmaxf(a, 0.f);
    }
    float xn[16];
    #pragma unroll
    for (int j = 0; j < 16; ++j) {
        float a = nb2[j];
        #pragma unroll
        for (int i = 0; i < 16; ++i) a = fmaf(h[i], nw2[i*16+j], a);
        xn[j] = fmaxf(a, 0.f);
    }
    float pa[16], pc[16];
    #pragma unroll
    for (int j = 0; j < 16; ++j) {
        float sa = 0.f, sc = 0.f;
        #pragma unroll
        for (int i = 0; i < 16; ++i) {
            sa = fmaf(xn[i], next_ew1[i*16+j], sa);
            sc = fmaf(xn[i], next_ew1[(32+i)*16+j], sc);
        }
        pa[j] = sa; pc[j] = sc;
    }
    stbf16x16(xnbf + (size_t)n*16, xn);
    stbf16x16(Pa + (size_t)n*16, pa);
    stbf16x16(Pc + (size_t)n*16, pc);
}

__global__ void node_last(const float* __restrict__ agg, const unsigned short* __restrict__ xnbf,
                          const float* __restrict__ nw1, const float* __restrict__ nb1,
                          const float* __restrict__ nw2, const float* __restrict__ nb2,
                          const float* __restrict__ hw1, const float* __restrict__ hb1,
                          const float* __restrict__ hw2, const float* __restrict__ hb2,
                          float* __restrict__ out_n) {
    int n = blockIdx.x * blockDim.x + threadIdx.x;
    if (n >= NN) return;
    float o[16];
    ldbf16x16(xnbf + (size_t)n*16, o);
    #pragma unroll
    for (int j = 0; j < 16; ++j) o[j] += agg[(size_t)n*16 + j];
    float h[16];
    #pragma unroll
    for (int j = 0; j < 16; ++j) {
        float a = nb1[j];
        #pragma unroll
        for (int i = 0; i < 16; ++i) a = fmaf(o[i], nw1[i*16+j], a);
        h[j] = fmaxf(a, 0.f);
    }
    float xn[16];
    #pragma unroll
    for (int j = 0; j < 16; ++j) {
        float a = nb2[j];
        #pragma unroll
        for (int i = 0; i < 16; ++i) a = fmaf(h[i], nw2[i*16+j], a);
        xn[j] = fmaxf(a, 0.f);
    }
    float g[16];
    #pragma unroll
    for (int j = 0; j < 16; ++j) {
        float a = hb1[j];
        #pragma unroll
        for (int i = 0; i < 16; ++i) a = fmaf(xn[i], hw1[i*16+j], a);
        g[j] = fmaxf(a, 0.f);
    }
    #pragma unroll
    for (int k = 0; k < 3; ++k) {
        float a = hb2[k];
        #pragma unroll
        for (int i = 0; i < 16; ++i) a = fmaf(g[i], hw2[i*3+k], a);
        out_n[(size_t)n*3 + k] = a;
    }
}

// ---------------- edge kernels (slot space, dst direct from srec) ----------------

__global__ void conv1_edge_s2(const unsigned long long* __restrict__ srec,
                              const unsigned int* __restrict__ ea_s,
                              const unsigned short* __restrict__ Pa, const unsigned short* __restrict__ Pc,
                              const float* __restrict__ ew1, const float* __restrict__ eb1,
                              const float* __restrict__ ew2, const float* __restrict__ eb2,
                              unsigned short* __restrict__ ebuf) {
    int j = blockIdx.x * blockDim.x + threadIdx.x;
    if (j >= NE) return;
    unsigned long long sr = srec[j];
    int s = (int)(sr & 0x1FFFFu);
    int t = (int)((sr >> 17) & 0x1FFFFu);
    uint2 wv = *reinterpret_cast<const uint2*>(&ea_s[(size_t)2*j]);
    float e0 = bf2f(wv.x & 0xffffu), e1 = bf2f(wv.x >> 16), e2 = bf2f(wv.y & 0xffffu);
    float h[16], pc[16];
    ldbf16x16(Pa + (size_t)s*16, h);
    ldbf16x16(Pc + (size_t)t*16, pc);
    #pragma unroll
    for (int jj = 0; jj < 16; ++jj) {
        float a = h[jj] + pc[jj] + eb1[jj]
                + e0*ew1[3*16+jj] + e1*ew1[4*16+jj] + e2*ew1[5*16+jj];
        h[jj] = fmaxf(a, 0.f);
    }
    float h2[16];
    #pragma unroll
    for (int jj = 0; jj < 16; ++jj) {
        float a = eb2[jj];
        #pragma unroll
        for (int i = 0; i < 16; ++i) a = fmaf(h[i], ew2[i*16+jj], a);
        h2[jj] = fmaxf(a, 0.f);
    }
    stbf16x16(ebuf + (size_t)j*16, h2);
}

template <bool LAST>
__global__ void conv_edge2(const unsigned long long* __restrict__ srec,
                           unsigned short* ebuf,          // in-place per slot
                           const unsigned short* __restrict__ Pa, const unsigned short* __restrict__ Pc,
                           const float* __restrict__ ew1, const float* __restrict__ eb1,
                           const float* __restrict__ ew2, const float* __restrict__ eb2,
                           const float* __restrict__ hw1, const float* __restrict__ hb1,
                           const float* __restrict__ hw2, const float* __restrict__ hb2,
                           float* __restrict__ out_e) {
    int j = blockIdx.x * blockDim.x + threadIdx.x;
    if (j >= NE) return;
    unsigned long long sr = srec[j];
    int s = (int)(sr & 0x1FFFFu);
    int t = (int)((sr >> 17) & 0x1FFFFu);
    float ein[16], h[16], pc[16];
    ldbf16x16(ebuf + (size_t)j*16, ein);
    ldbf16x16(Pa + (size_t)s*16, h);
    ldbf16x16(Pc + (size_t)t*16, pc);
    #pragma unroll
    for (int jj = 0; jj < 16; ++jj) h[jj] = h[jj] + pc[jj] + eb1[jj];
    #pragma unroll
    for (int i = 0; i < 16; ++i) {
        #pragma unroll
        for (int jj = 0; jj < 16; ++jj) h[jj] = fmaf(ein[i], ew1[(16+i)*16+jj], h[jj]);
    }
    #pragma unroll
    for (int jj = 0; jj < 16; ++jj) h[jj] = fmaxf(h[jj], 0.f);
    float h2[16];
    #pragma unroll
    for (int jj = 0; jj < 16; ++jj) {
        float a = eb2[jj];
        #pragma unroll
        for (int i = 0; i < 16; ++i) a = fmaf(h[i], ew2[i*16+jj], a);
        h2[jj] = fmaxf(a, 0.f);
    }
    if (!LAST) {
        stbf16x16(ebuf + (size_t)j*16, h2);
    } else {
        float g[16];
        #pragma unroll
        for (int jj = 0; jj < 16; ++jj) {
            float a = hb1[jj];
            #pragma unroll
            for (int i = 0; i < 16; ++i) a = fmaf(h2[i], hw1[i*16+jj], a);
            g[jj] = fmaxf(a, 0.f);
        }
        int e = (int)(sr >> 34);
        #pragma unroll
        for (int k = 0; k < 3; ++k) {
            float a = hb2[k];
            #pragma unroll
            for (int i = 0; i < 16; ++i) a = fmaf(g[i], hw2[i*3+k], a);
            out_e[(size_t)e*3 + k] = a;
        }
    }
}

// conv2/3 aggregation: 4 threads/node (4 dims each), streaming both runs.
__global__ void kagg16_s2(const unsigned int* __restrict__ runpos, const unsigned short* __restrict__ runlen,
                          const unsigned long long* __restrict__ srec,
                          const unsigned short* __restrict__ ebuf,
                          const unsigned short* __restrict__ xnbf, float* __restrict__ agg) {
    int tg = blockIdx.x * blockDim.x + threadIdx.x;
    int n = tg >> 2, q = tg & 3;
    if (n >= NN) return;
    float a0 = 0.f, a1 = 0.f, a2 = 0.f, a3 = 0.f;
    #pragma unroll
    for (int r = 0; r < 2; ++r) {
        int h = r * NN + n;
        unsigned int j0 = runpos[h];
        int L = runlen[h];
        for (int i = 0; i < L; ++i) {
            unsigned int j = j0 + i;
            int s = (int)(srec[j] & 0x1FFFFu);
            uint2 w  = *reinterpret_cast<const uint2*>(ebuf + (size_t)j*16 + q*4);
            uint2 xw = *reinterpret_cast<const uint2*>(xnbf + (size_t)s*16 + q*4);
            a0 += fmaxf(bf2f(xw.x & 0xffffu) + bf2f(w.x & 0xffffu), 0.f);
            a1 += fmaxf(bf2f(xw.x >> 16)     + bf2f(w.x >> 16),     0.f);
            a2 += fmaxf(bf2f(xw.y & 0xffffu) + bf2f(w.y & 0xffffu), 0.f);
            a3 += fmaxf(bf2f(xw.y >> 16)     + bf2f(w.y >> 16),     0.f);
        }
    }
    *reinterpret_cast<float4*>(agg + (size_t)n*16 + q*4) = make_float4(a0, a1, a2, a3);
}

extern "C" void kernel_launch(void* const* d_in, const int* in_sizes, int n_in,
                              void* d_out, int out_size, void* d_ws, size_t ws_size,
                              hipStream_t stream) {
    const float* x  = (const float*)d_in[0];
    const float* ea = (const float*)d_in[1];
    const int*   ei = (const int*)d_in[2];
    const float *c1_ew1 = (const float*)d_in[3],  *c1_eb1 = (const float*)d_in[4];
    const float *c1_ew2 = (const float*)d_in[5],  *c1_eb2 = (const float*)d_in[6];
    const float *c1_nw1 = (const float*)d_in[7],  *c1_nb1 = (const float*)d_in[8];
    const float *c1_nw2 = (const float*)d_in[9],  *c1_nb2 = (const float*)d_in[10];
    const float *c2_ew1 = (const float*)d_in[11], *c2_eb1 = (const float*)d_in[12];
    const float *c2_ew2 = (const float*)d_in[13], *c2_eb2 = (const float*)d_in[14];
    const float *c2_nw1 = (const float*)d_in[15], *c2_nb1 = (const float*)d_in[16];
    const float *c2_nw2 = (const float*)d_in[17], *c2_nb2 = (const float*)d_in[18];
    const float *c3_ew1 = (const float*)d_in[19], *c3_eb1 = (const float*)d_in[20];
    const float *c3_ew2 = (const float*)d_in[21], *c3_eb2 = (const float*)d_in[22];
    const float *c3_nw1 = (const float*)d_in[23], *c3_nb1 = (const float*)d_in[24];
    const float *c3_nw2 = (const float*)d_in[25], *c3_nb2 = (const float*)d_in[26];
    const float *node_w1 = (const float*)d_in[27], *node_b1 = (const float*)d_in[28];
    const float *node_w2 = (const float*)d_in[29], *node_b2 = (const float*)d_in[30];
    const float *edge_w1 = (const float*)d_in[31], *edge_b1 = (const float*)d_in[32];
    const float *edge_w2 = (const float*)d_in[33], *edge_b2 = (const float*)d_in[34];

    // ---- ws carve-up (137.6 MB) ----
    char* w = (char*)d_ws;
    unsigned short* ebuf = (unsigned short*)w;         // NE*32; build scratch aliases inside:
    int4* rec  = (int4*)w;                             //   NE*16 = 51.2 MB
    int* head2 = (int*)(w + (size_t)NE * 16);          //   2*NN*4 = 0.8 MB
    w += (size_t)NE * 32;
    unsigned long long* srec = (unsigned long long*)w; w += (size_t)NE * 8;   // 25.6 MB
    unsigned short* Pa   = (unsigned short*)w;         w += (size_t)NN * 32;
    unsigned short* Pc   = (unsigned short*)w;         w += (size_t)NN * 32;
    unsigned short* xnbf = (unsigned short*)w;         w += (size_t)NN * 32;
    unsigned int* gctr = (unsigned int*)w;

    // ---- d_out overlays ----
    float* out_n = (float*)d_out;                      // N*3 floats (1.2 MB)
    float* out_e = out_n + (size_t)NN * 3;             // E*3 floats (38.4 MB)
    unsigned int*   runpos = (unsigned int*)out_n;                     // 2N*4 = 0.8 MB
    unsigned short* runlen = (unsigned short*)((char*)out_n + (size_t)2*NN*4); // 2N*2 = 0.4 MB
    unsigned int* ea_s = (unsigned int*)out_e;                         // NE*8 = 25.6 MB
    float* agg = (float*)((char*)out_e + (size_t)NE * 8);              // N*16 f32 = 6.4 MB

    const int B = 256;
    const int gn = (NN + B - 1) / B;                 // 391
    const int ge = (NE + B - 1) / B;                 // 12500
    const int gq = (NN * 4 + B - 1) / B;             // 1563
    const int g2 = (2 * NN + 1 + B - 1) / B;         // 782

    // ---- build ----
    kinit2<<<g2, B, 0, stream>>>(head2, gctr);
    kbuild2<<<ge, B, 0, stream>>>(ei, ea, head2, rec);
    kwalk2<<<g2, B, 0, stream>>>(head2, rec, srec, ea_s, runpos, runlen, gctr);

    // ---- conv1 ----
    prep1<<<gn, B, 0, stream>>>(x, c1_ew1, Pa, Pc);
    kagg3_s2<<<g2, B, 0, stream>>>(runpos, runlen, srec, ea_s, x, agg);
    conv1_edge_s2<<<ge, B, 0, stream>>>(srec, ea_s, Pa, Pc,
                                        c1_ew1, c1_eb1, c1_ew2, c1_eb2, ebuf);
    conv1_node<<<gn, B, 0, stream>>>(agg, x, c1_nw1, c1_nb1, c1_nw2, c1_nb2,
                                     c2_ew1, Pa, Pc, xnbf);
    // ---- conv2 ----
    kagg16_s2<<<gq, B, 0, stream>>>(runpos, runlen, srec, ebuf, xnbf, agg);
    conv_edge2<false><<<ge, B, 0, stream>>>(srec, ebuf, Pa, Pc,
                                            c2_ew1, c2_eb1, c2_ew2, c2_eb2,
                                            nullptr, nullptr, nullptr, nullptr, nullptr);
    node_mid<<<gn, B, 0, stream>>>(agg, c2_nw1, c2_nb1, c2_nw2, c2_nb2,
                                   c3_ew1, Pa, Pc, xnbf);
    // ---- conv3 (agg consumed by node_last; runpos/runlen dead before node_last
    //      writes out_n; ea_s/agg dead before conv_edge2<true> writes out_e) ----
    kagg16_s2<<<gq, B, 0, stream>>>(runpos, runlen, srec, ebuf, xnbf, agg);
    node_last<<<gn, B, 0, stream>>>(agg, xnbf, c3_nw1, c3_nb1, c3_nw2, c3_nb2,
                                    node_w1, node_b1, node_w2, node_b2, out_n);
    conv_edge2<true><<<ge, B, 0, stream>>>(srec, ebuf, Pa, Pc,
                                           c3_ew1, c3_eb1, c3_ew2, c3_eb2,
                                           edge_w1, edge_b1, edge_w2, edge_b2, out_e);
}

// Round 7
// 653.525 us; speedup vs baseline: 8.8078x; 1.4022x over previous
//
#include <hip/hip_runtime.h>
#include <hip/hip_bf16.h>

// GINE 3-conv GNN. Dst-grouped slot layout via ZERO-global-atomic two-level
// counting sort: coarse bucket (dst>>8, 391 buckets) with per-block LDS
// histograms + deterministic scans, then per-bucket LDS count/scan/scatter to
// full dst grouping + CSR start[]. Convs stream slots sequentially.
// N=100000, E=3200000, H=16. fp32 in/out; edge_index int32 rows [src | dst].
//
// ws (137.6 MB):
//   ebuf [E][16] bf16 (102.4M); build scratch aliases inside (dead before conv1):
//       brec [E] u64 (25.6M) {src:17,dst:17,eid:22}, bea [E] 8B bf16x3,
//       hist [391][512] int (0.8M), binsum[391], binbase[392]
//   srec [E] u64 (25.6M)  final dst-grouped records
//   Pa, Pc, xnbf [N][16] bf16 (9.6M)
// out_n region: start[N+1] int (0.4M, dead before node_last writes out_n)
// out_e region: ea_s [E] 8B (25.6M) + agg [N][16] f32 (6.4M)
//   (dead before conv3's edge kernel writes out_e)

#define NN 100000
#define NE 3200000
#define NBKT 391          // ceil(NN/256)
#define NBLK1 512         // pass-1 blocks
#define EPB1 6250         // NE / NBLK1 (exact)

__device__ __forceinline__ float bf2f(unsigned int h) {
    unsigned int u = h << 16;
    float f; __builtin_memcpy(&f, &u, 4); return f;
}
__device__ __forceinline__ unsigned short f2bf(float f) {
    unsigned int u; __builtin_memcpy(&u, &f, 4);
    u += 0x7fffu + ((u >> 16) & 1u);          // RNE
    return (unsigned short)(u >> 16);
}
__device__ __forceinline__ void ldbf16x16(const unsigned short* p, float* r) {
    const uint4* q = reinterpret_cast<const uint4*>(p);
    uint4 a = q[0], b = q[1];
    unsigned int w[8] = {a.x, a.y, a.z, a.w, b.x, b.y, b.z, b.w};
    #pragma unroll
    for (int k = 0; k < 8; ++k) {
        r[2*k]   = bf2f(w[k] & 0xffffu);
        r[2*k+1] = bf2f(w[k] >> 16);
    }
}
__device__ __forceinline__ void stbf16x16(unsigned short* p, const float* r) {
    unsigned int w[8];
    #pragma unroll
    for (int k = 0; k < 8; ++k)
        w[k] = (unsigned int)f2bf(r[2*k]) | ((unsigned int)f2bf(r[2*k+1]) << 16);
    uint4* q = reinterpret_cast<uint4*>(p);
    q[0] = make_uint4(w[0], w[1], w[2], w[3]);
    q[1] = make_uint4(w[4], w[5], w[6], w[7]);
}

// ---------------- build: two-level counting sort (no global atomics) ----------------

// pass-1 histogram: hist[bin][blk] = # edges of block blk with dst>>8 == bin
__global__ void khist1(const int* __restrict__ ei, int* __restrict__ hist) {
    __shared__ int h[NBKT];
    int blk = blockIdx.x, tid = threadIdx.x;
    for (int b = tid; b < NBKT; b += 256) h[b] = 0;
    __syncthreads();
    int e0 = blk * EPB1;
    for (int e = e0 + tid; e < e0 + EPB1; e += 256)
        atomicAdd(&h[ei[NE + e] >> 8], 1);          // LDS atomic
    __syncthreads();
    for (int b = tid; b < NBKT; b += 256) hist[b * NBLK1 + blk] = h[b];
}

// per-bin exclusive scan over blocks; binsum[bin] = total
__global__ void kscan_a(int* __restrict__ hist, int* __restrict__ binsum) {
    __shared__ int s[NBLK1];
    int b = blockIdx.x, t = threadIdx.x;
    int v = hist[b * NBLK1 + t];
    s[t] = v; __syncthreads();
    for (int off = 1; off < NBLK1; off <<= 1) {
        int u = (t >= off) ? s[t - off] : 0;
        __syncthreads();
        s[t] += u;
        __syncthreads();
    }
    hist[b * NBLK1 + t] = s[t] - v;                 // exclusive within bin
    if (t == NBLK1 - 1) binsum[b] = s[t];
}

// exclusive scan over bins -> binbase[0..NBKT]; also start[NN] = NE
__global__ void kscan_b(const int* __restrict__ binsum, int* __restrict__ binbase,
                        int* __restrict__ start) {
    __shared__ int s[512];
    int t = threadIdx.x;
    int v = (t < NBKT) ? binsum[t] : 0;
    s[t] = v; __syncthreads();
    for (int off = 1; off < 512; off <<= 1) {
        int u = (t >= off) ? s[t - off] : 0;
        __syncthreads();
        s[t] += u;
        __syncthreads();
    }
    if (t < NBKT) binbase[t] = s[t] - v;
    if (t == NBKT - 1) binbase[NBKT] = s[t];        // == NE
    if (t == 0) start[NN] = NE;
}

// pass-1 scatter into coarse buckets. Each block owns a reserved contiguous
// range per bucket (binbase + scanned hist) -> LDS cursors, no global atomics.
__global__ void kscatter1(const int* __restrict__ ei, const float* __restrict__ ea,
                          const int* __restrict__ hist, const int* __restrict__ binbase,
                          unsigned long long* __restrict__ brec, unsigned int* __restrict__ bea) {
    __shared__ int cur[NBKT];
    int blk = blockIdx.x, tid = threadIdx.x;
    for (int b = tid; b < NBKT; b += 256)
        cur[b] = binbase[b] + hist[b * NBLK1 + blk];
    __syncthreads();
    int e0 = blk * EPB1;
    for (int e = e0 + tid; e < e0 + EPB1; e += 256) {
        int s = ei[e], d = ei[NE + e];
        float f0 = ea[(size_t)3*e], f1 = ea[(size_t)3*e+1], f2 = ea[(size_t)3*e+2];
        int pos = atomicAdd(&cur[d >> 8], 1);       // LDS atomic
        brec[pos] = (unsigned long long)(unsigned int)s
                  | ((unsigned long long)(unsigned int)d << 17)
                  | ((unsigned long long)(unsigned int)e << 34);
        *reinterpret_cast<uint2*>(&bea[(size_t)2*pos]) = make_uint2(
            (unsigned int)f2bf(f0) | ((unsigned int)f2bf(f1) << 16),
            (unsigned int)f2bf(f2));
    }
}

// pass-2: one block per bucket; count 256 local nodes, scan, scatter to final
// dst-grouped srec/ea_s; emit CSR start[].
__global__ void kbucket(const unsigned long long* __restrict__ brec,
                        const unsigned int* __restrict__ bea,
                        const int* __restrict__ binbase,
                        unsigned long long* __restrict__ srec, unsigned int* __restrict__ ea_s,
                        int* __restrict__ start) {
    __shared__ int cnt[256];
    __shared__ int off[256];
    __shared__ int cur[256];
    int bkt = blockIdx.x, t = threadIdx.x;
    int base = binbase[bkt], end = binbase[bkt + 1];
    cnt[t] = 0;
    __syncthreads();
    for (int j = base + t; j < end; j += 256)
        atomicAdd(&cnt[(int)((brec[j] >> 17) & 0xFFu)], 1);
    __syncthreads();
    int v = cnt[t];
    off[t] = v; __syncthreads();
    for (int o = 1; o < 256; o <<= 1) {
        int u = (t >= o) ? off[t - o] : 0;
        __syncthreads();
        off[t] += u;
        __syncthreads();
    }
    int excl = off[t] - v;
    int node = bkt * 256 + t;
    if (node < NN) start[node] = base + excl;
    cur[t] = base + excl;
    __syncthreads();
    for (int j = base + t; j < end; j += 256) {
        unsigned long long r = brec[j];
        int p = atomicAdd(&cur[(int)((r >> 17) & 0xFFu)], 1);
        srec[p] = r;
        uint2 w = *reinterpret_cast<const uint2*>(&bea[(size_t)2*j]);
        *reinterpret_cast<uint2*>(&ea_s[(size_t)2*p]) = w;
    }
}

// ---------------- aggregations (CSR streaming) ----------------

// conv1: agg3[n] = sum relu(x[src]+ea); 4 threads/node interleaved + shfl reduce
__global__ void kagg3_s(const int* __restrict__ start, const unsigned long long* __restrict__ srec,
                        const unsigned int* __restrict__ ea_s,
                        const float* __restrict__ x, float* __restrict__ agg) {
    int t = blockIdx.x * blockDim.x + threadIdx.x;
    int n = t >> 2, q = t & 3;
    if (n >= NN) return;
    int j0 = start[n], j1 = start[n + 1];
    float a0 = 0.f, a1 = 0.f, a2 = 0.f;
    for (int j = j0 + q; j < j1; j += 4) {
        int s = (int)(srec[j] & 0x1FFFFu);
        uint2 w = *reinterpret_cast<const uint2*>(&ea_s[(size_t)2*j]);
        a0 += fmaxf(x[3*s  ] + bf2f(w.x & 0xffffu), 0.f);
        a1 += fmaxf(x[3*s+1] + bf2f(w.x >> 16),     0.f);
        a2 += fmaxf(x[3*s+2] + bf2f(w.y & 0xffffu), 0.f);
    }
    a0 += __shfl_xor(a0, 1); a0 += __shfl_xor(a0, 2);
    a1 += __shfl_xor(a1, 1); a1 += __shfl_xor(a1, 2);
    a2 += __shfl_xor(a2, 1); a2 += __shfl_xor(a2, 2);
    if (q == 0) {
        float* p = agg + (size_t)n*16;
        p[0] = a0; p[1] = a1; p[2] = a2;
    }
}

// conv2/3: 4 threads/node, 4 dims each, contiguous segment stream
__global__ void kagg16_s(const int* __restrict__ start, const unsigned long long* __restrict__ srec,
                         const unsigned short* __restrict__ ebuf,
                         const unsigned short* __restrict__ xnbf, float* __restrict__ agg) {
    int tg = blockIdx.x * blockDim.x + threadIdx.x;
    int n = tg >> 2, q = tg & 3;
    if (n >= NN) return;
    int j0 = start[n], j1 = start[n + 1];
    float a0 = 0.f, a1 = 0.f, a2 = 0.f, a3 = 0.f;
    for (int j = j0; j < j1; ++j) {
        int s = (int)(srec[j] & 0x1FFFFu);
        uint2 w  = *reinterpret_cast<const uint2*>(ebuf + (size_t)j*16 + q*4);
        uint2 xw = *reinterpret_cast<const uint2*>(xnbf + (size_t)s*16 + q*4);
        a0 += fmaxf(bf2f(xw.x & 0xffffu) + bf2f(w.x & 0xffffu), 0.f);
        a1 += fmaxf(bf2f(xw.x >> 16)     + bf2f(w.x >> 16),     0.f);
        a2 += fmaxf(bf2f(xw.y & 0xffffu) + bf2f(w.y & 0xffffu), 0.f);
        a3 += fmaxf(bf2f(xw.y >> 16)     + bf2f(w.y >> 16),     0.f);
    }
    *reinterpret_cast<float4*>(agg + (size_t)n*16 + q*4) = make_float4(a0, a1, a2, a3);
}

// ---------------- node-side kernels ----------------

__global__ void prep1(const float* __restrict__ x, const float* __restrict__ ew1,
                      unsigned short* __restrict__ Pa, unsigned short* __restrict__ Pc) {
    int n = blockIdx.x * blockDim.x + threadIdx.x;
    if (n >= NN) return;
    float x0 = x[3*n], x1 = x[3*n+1], x2 = x[3*n+2];
    float pa[16], pc[16];
    #pragma unroll
    for (int j = 0; j < 16; ++j) {
        pa[j] = x0*ew1[0*16+j] + x1*ew1[1*16+j] + x2*ew1[2*16+j];
        pc[j] = x0*ew1[6*16+j] + x1*ew1[7*16+j] + x2*ew1[8*16+j];
    }
    stbf16x16(Pa + (size_t)n*16, pa);
    stbf16x16(Pc + (size_t)n*16, pc);
}

__global__ void conv1_node(const float* __restrict__ agg, const float* __restrict__ x,
                           const float* __restrict__ nw1, const float* __restrict__ nb1,
                           const float* __restrict__ nw2, const float* __restrict__ nb2,
                           const float* __restrict__ next_ew1,
                           unsigned short* __restrict__ Pa, unsigned short* __restrict__ Pc,
                           unsigned short* __restrict__ xnbf) {
    int n = blockIdx.x * blockDim.x + threadIdx.x;
    if (n >= NN) return;
    float o0 = agg[(size_t)n*16+0] + x[3*n];
    float o1 = agg[(size_t)n*16+1] + x[3*n+1];
    float o2 = agg[(size_t)n*16+2] + x[3*n+2];
    float h[16];
    #pragma unroll
    for (int j = 0; j < 16; ++j)
        h[j] = fmaxf(nb1[j] + o0*nw1[0*16+j] + o1*nw1[1*16+j] + o2*nw1[2*16+j], 0.f);
    float xn[16];
    #pragma unroll
    for (int j = 0; j < 16; ++j) {
        float a = nb2[j];
        #pragma unroll
        for (int i = 0; i < 16; ++i) a = fmaf(h[i], nw2[i*16+j], a);
        xn[j] = fmaxf(a, 0.f);
    }
    float pa[16], pc[16];
    #pragma unroll
    for (int j = 0; j < 16; ++j) {
        float sa = 0.f, sc = 0.f;
        #pragma unroll
        for (int i = 0; i < 16; ++i) {
            sa = fmaf(xn[i], next_ew1[i*16+j], sa);
            sc = fmaf(xn[i], next_ew1[(32+i)*16+j], sc);
        }
        pa[j] = sa; pc[j] = sc;
    }
    stbf16x16(xnbf + (size_t)n*16, xn);
    stbf16x16(Pa + (size_t)n*16, pa);
    stbf16x16(Pc + (size_t)n*16, pc);
}

__global__ void node_mid(const float* __restrict__ agg,
                         const float* __restrict__ nw1, const float* __restrict__ nb1,
                         const float* __restrict__ nw2, const float* __restrict__ nb2,
                         const float* __restrict__ next_ew1,
                         unsigned short* __restrict__ Pa, unsigned short* __restrict__ Pc,
                         unsigned short* xnbf) {
    int n = blockIdx.x * blockDim.x + threadIdx.x;
    if (n >= NN) return;
    float o[16];
    ldbf16x16(xnbf + (size_t)n*16, o);
    #pragma unroll
    for (int j = 0; j < 16; ++j) o[j] += agg[(size_t)n*16 + j];
    float h[16];
    #pragma unroll
    for (int j = 0; j < 16; ++j) {
        float a = nb1[j];
        #pragma unroll
        for (int i = 0; i < 16; ++i) a = fmaf(o[i], nw1[i*16+j], a);
        h[j] = fmaxf(a, 0.f);
    }
    float xn[16];
    #pragma unroll
    for (int j = 0; j < 16; ++j) {
        float a = nb2[j];
        #pragma unroll
        for (int i = 0; i < 16; ++i) a = fmaf(h[i], nw2[i*16+j], a);
        xn[j] = fmaxf(a, 0.f);
    }
    float pa[16], pc[16];
    #pragma unroll
    for (int j = 0; j < 16; ++j) {
        float sa = 0.f, sc = 0.f;
        #pragma unroll
        for (int i = 0; i < 16; ++i) {
            sa = fmaf(xn[i], next_ew1[i*16+j], sa);
            sc = fmaf(xn[i], next_ew1[(32+i)*16+j], sc);
        }
        pa[j] = sa; pc[j] = sc;
    }
    stbf16x16(xnbf + (size_t)n*16, xn);
    stbf16x16(Pa + (size_t)n*16, pa);
    stbf16x16(Pc + (size_t)n*16, pc);
}

__global__ void node_last(const float* __restrict__ agg, const unsigned short* __restrict__ xnbf,
                          const float* __restrict__ nw1, const float* __restrict__ nb1,
                          const float* __restrict__ nw2, const float* __restrict__ nb2,
                          const float* __restrict__ hw1, const float* __restrict__ hb1,
                          const float* __restrict__ hw2, const float* __restrict__ hb2,
                          float* __restrict__ out_n) {
    int n = blockIdx.x * blockDim.x + threadIdx.x;
    if (n >= NN) return;
    float o[16];
    ldbf16x16(xnbf + (size_t)n*16, o);
    #pragma unroll
    for (int j = 0; j < 16; ++j) o[j] += agg[(size_t)n*16 + j];
    float h[16];
    #pragma unroll
    for (int j = 0; j < 16; ++j) {
        float a = nb1[j];
        #pragma unroll
        for (int i = 0; i < 16; ++i) a = fmaf(o[i], nw1[i*16+j], a);
        h[j] = fmaxf(a, 0.f);
    }
    float xn[16];
    #pragma unroll
    for (int j = 0; j < 16; ++j) {
        float a = nb2[j];
        #pragma unroll
        for (int i = 0; i < 16; ++i) a = fmaf(h[i], nw2[i*16+j], a);
        xn[j] = fmaxf(a, 0.f);
    }
    float g[16];
    #pragma unroll
    for (int j = 0; j < 16; ++j) {
        float a = hb1[j];
        #pragma unroll
        for (int i = 0; i < 16; ++i) a = fmaf(xn[i], hw1[i*16+j], a);
        g[j] = fmaxf(a, 0.f);
    }
    #pragma unroll
    for (int k = 0; k < 3; ++k) {
        float a = hb2[k];
        #pragma unroll
        for (int i = 0; i < 16; ++i) a = fmaf(g[i], hw2[i*3+k], a);
        out_n[(size_t)n*3 + k] = a;
    }
}

// ---------------- edge kernels (slot space, dst direct from srec) ----------------

__global__ void conv1_edge_s2(const unsigned long long* __restrict__ srec,
                              const unsigned int* __restrict__ ea_s,
                              const unsigned short* __restrict__ Pa, const unsigned short* __restrict__ Pc,
                              const float* __restrict__ ew1, const float* __restrict__ eb1,
                              const float* __restrict__ ew2, const float* __restrict__ eb2,
                              unsigned short* __restrict__ ebuf) {
    int j = blockIdx.x * blockDim.x + threadIdx.x;
    if (j >= NE) return;
    unsigned long long sr = srec[j];
    int s = (int)(sr & 0x1FFFFu);
    int t = (int)((sr >> 17) & 0x1FFFFu);
    uint2 wv = *reinterpret_cast<const uint2*>(&ea_s[(size_t)2*j]);
    float e0 = bf2f(wv.x & 0xffffu), e1 = bf2f(wv.x >> 16), e2 = bf2f(wv.y & 0xffffu);
    float h[16], pc[16];
    ldbf16x16(Pa + (size_t)s*16, h);
    ldbf16x16(Pc + (size_t)t*16, pc);
    #pragma unroll
    for (int jj = 0; jj < 16; ++jj) {
        float a = h[jj] + pc[jj] + eb1[jj]
                + e0*ew1[3*16+jj] + e1*ew1[4*16+jj] + e2*ew1[5*16+jj];
        h[jj] = fmaxf(a, 0.f);
    }
    float h2[16];
    #pragma unroll
    for (int jj = 0; jj < 16; ++jj) {
        float a = eb2[jj];
        #pragma unroll
        for (int i = 0; i < 16; ++i) a = fmaf(h[i], ew2[i*16+jj], a);
        h2[jj] = fmaxf(a, 0.f);
    }
    stbf16x16(ebuf + (size_t)j*16, h2);
}

template <bool LAST>
__global__ void conv_edge2(const unsigned long long* __restrict__ srec,
                           unsigned short* ebuf,          // in-place per slot
                           const unsigned short* __restrict__ Pa, const unsigned short* __restrict__ Pc,
                           const float* __restrict__ ew1, const float* __restrict__ eb1,
                           const float* __restrict__ ew2, const float* __restrict__ eb2,
                           const float* __restrict__ hw1, const float* __restrict__ hb1,
                           const float* __restrict__ hw2, const float* __restrict__ hb2,
                           float* __restrict__ out_e) {
    int j = blockIdx.x * blockDim.x + threadIdx.x;
    if (j >= NE) return;
    unsigned long long sr = srec[j];
    int s = (int)(sr & 0x1FFFFu);
    int t = (int)((sr >> 17) & 0x1FFFFu);
    float ein[16], h[16], pc[16];
    ldbf16x16(ebuf + (size_t)j*16, ein);
    ldbf16x16(Pa + (size_t)s*16, h);
    ldbf16x16(Pc + (size_t)t*16, pc);
    #pragma unroll
    for (int jj = 0; jj < 16; ++jj) h[jj] = h[jj] + pc[jj] + eb1[jj];
    #pragma unroll
    for (int i = 0; i < 16; ++i) {
        #pragma unroll
        for (int jj = 0; jj < 16; ++jj) h[jj] = fmaf(ein[i], ew1[(16+i)*16+jj], h[jj]);
    }
    #pragma unroll
    for (int jj = 0; jj < 16; ++jj) h[jj] = fmaxf(h[jj], 0.f);
    float h2[16];
    #pragma unroll
    for (int jj = 0; jj < 16; ++jj) {
        float a = eb2[jj];
        #pragma unroll
        for (int i = 0; i < 16; ++i) a = fmaf(h[i], ew2[i*16+jj], a);
        h2[jj] = fmaxf(a, 0.f);
    }
    if (!LAST) {
        stbf16x16(ebuf + (size_t)j*16, h2);
    } else {
        float g[16];
        #pragma unroll
        for (int jj = 0; jj < 16; ++jj) {
            float a = hb1[jj];
            #pragma unroll
            for (int i = 0; i < 16; ++i) a = fmaf(h2[i], hw1[i*16+jj], a);
            g[jj] = fmaxf(a, 0.f);
        }
        int e = (int)(sr >> 34);
        #pragma unroll
        for (int k = 0; k < 3; ++k) {
            float a = hb2[k];
            #pragma unroll
            for (int i = 0; i < 16; ++i) a = fmaf(g[i], hw2[i*3+k], a);
            out_e[(size_t)e*3 + k] = a;
        }
    }
}

extern "C" void kernel_launch(void* const* d_in, const int* in_sizes, int n_in,
                              void* d_out, int out_size, void* d_ws, size_t ws_size,
                              hipStream_t stream) {
    const float* x  = (const float*)d_in[0];
    const float* ea = (const float*)d_in[1];
    const int*   ei = (const int*)d_in[2];
    const float *c1_ew1 = (const float*)d_in[3],  *c1_eb1 = (const float*)d_in[4];
    const float *c1_ew2 = (const float*)d_in[5],  *c1_eb2 = (const float*)d_in[6];
    const float *c1_nw1 = (const float*)d_in[7],  *c1_nb1 = (const float*)d_in[8];
    const float *c1_nw2 = (const float*)d_in[9],  *c1_nb2 = (const float*)d_in[10];
    const float *c2_ew1 = (const float*)d_in[11], *c2_eb1 = (const float*)d_in[12];
    const float *c2_ew2 = (const float*)d_in[13], *c2_eb2 = (const float*)d_in[14];
    const float *c2_nw1 = (const float*)d_in[15], *c2_nb1 = (const float*)d_in[16];
    const float *c2_nw2 = (const float*)d_in[17], *c2_nb2 = (const float*)d_in[18];
    const float *c3_ew1 = (const float*)d_in[19], *c3_eb1 = (const float*)d_in[20];
    const float *c3_ew2 = (const float*)d_in[21], *c3_eb2 = (const float*)d_in[22];
    const float *c3_nw1 = (const float*)d_in[23], *c3_nb1 = (const float*)d_in[24];
    const float *c3_nw2 = (const float*)d_in[25], *c3_nb2 = (const float*)d_in[26];
    const float *node_w1 = (const float*)d_in[27], *node_b1 = (const float*)d_in[28];
    const float *node_w2 = (const float*)d_in[29], *node_b2 = (const float*)d_in[30];
    const float *edge_w1 = (const float*)d_in[31], *edge_b1 = (const float*)d_in[32];
    const float *edge_w2 = (const float*)d_in[33], *edge_b2 = (const float*)d_in[34];

    // ---- ws carve-up (137.6 MB) ----
    char* w = (char*)d_ws;
    unsigned short* ebuf = (unsigned short*)w;               // NE*32; build scratch aliases inside:
    unsigned long long* brec = (unsigned long long*)w;       //   NE*8 = 25.6 MB
    unsigned int* bea = (unsigned int*)(w + (size_t)NE*8);   //   NE*8 = 25.6 MB
    int* hist   = (int*)(w + (size_t)NE*16);                 //   NBKT*NBLK1*4 = 0.8 MB
    int* binsum = hist + NBKT * NBLK1;                       //   391*4
    int* binbase = binsum + NBKT;                            //   392*4
    w += (size_t)NE * 32;
    unsigned long long* srec = (unsigned long long*)w;  w += (size_t)NE * 8;   // 25.6 MB
    unsigned short* Pa   = (unsigned short*)w;          w += (size_t)NN * 32;
    unsigned short* Pc   = (unsigned short*)w;          w += (size_t)NN * 32;
    unsigned short* xnbf = (unsigned short*)w;          w += (size_t)NN * 32;

    // ---- d_out overlays ----
    float* out_n = (float*)d_out;                      // N*3 floats (1.2 MB)
    float* out_e = out_n + (size_t)NN * 3;             // E*3 floats (38.4 MB)
    int* start = (int*)out_n;                          // (NN+1)*4 = 0.4 MB, dead before node_last
    unsigned int* ea_s = (unsigned int*)out_e;                 // NE*8 = 25.6 MB
    float* agg = (float*)((char*)out_e + (size_t)NE * 8);      // N*16 f32 = 6.4 MB

    const int B = 256;
    const int gn = (NN + B - 1) / B;                 // 391
    const int ge = (NE + B - 1) / B;                 // 12500
    const int gq = (NN * 4 + B - 1) / B;             // 1563

    // ---- build (no global atomics) ----
    khist1<<<NBLK1, B, 0, stream>>>(ei, hist);
    kscan_a<<<NBKT, NBLK1, 0, stream>>>(hist, binsum);
    kscan_b<<<1, 512, 0, stream>>>(binsum, binbase, start);
    kscatter1<<<NBLK1, B, 0, stream>>>(ei, ea, hist, binbase, brec, bea);
    kbucket<<<NBKT, B, 0, stream>>>(brec, bea, binbase, srec, ea_s, start);

    // ---- conv1 ----
    prep1<<<gn, B, 0, stream>>>(x, c1_ew1, Pa, Pc);
    kagg3_s<<<gq, B, 0, stream>>>(start, srec, ea_s, x, agg);
    conv1_edge_s2<<<ge, B, 0, stream>>>(srec, ea_s, Pa, Pc,
                                        c1_ew1, c1_eb1, c1_ew2, c1_eb2, ebuf);
    conv1_node<<<gn, B, 0, stream>>>(agg, x, c1_nw1, c1_nb1, c1_nw2, c1_nb2,
                                     c2_ew1, Pa, Pc, xnbf);
    // ---- conv2 ----
    kagg16_s<<<gq, B, 0, stream>>>(start, srec, ebuf, xnbf, agg);
    conv_edge2<false><<<ge, B, 0, stream>>>(srec, ebuf, Pa, Pc,
                                            c2_ew1, c2_eb1, c2_ew2, c2_eb2,
                                            nullptr, nullptr, nullptr, nullptr, nullptr);
    node_mid<<<gn, B, 0, stream>>>(agg, c2_nw1, c2_nb1, c2_nw2, c2_nb2,
                                   c3_ew1, Pa, Pc, xnbf);
    // ---- conv3 (start dead after kagg16_s; node_last then overwrites out_n;
    //      ea_s/agg dead before conv_edge2<true> writes out_e) ----
    kagg16_s<<<gq, B, 0, stream>>>(start, srec, ebuf, xnbf, agg);
    node_last<<<gn, B, 0, stream>>>(agg, xnbf, c3_nw1, c3_nb1, c3_nw2, c3_nb2,
                                    node_w1, node_b1, node_w2, node_b2, out_n);
    conv_edge2<true><<<ge, B, 0, stream>>>(srec, ebuf, Pa, Pc,
                                           c3_ew1, c3_eb1, c3_ew2, c3_eb2,
                                           edge_w1, edge_b1, edge_w2, edge_b2, out_e);
}

// Round 8
// 634.206 us; speedup vs baseline: 9.0761x; 1.0305x over previous
//
#include <hip/hip_runtime.h>
#include <hip/hip_bf16.h>

// GINE 3-conv GNN. Dst-grouped slot layout via zero-global-atomic two-level
// counting sort. This round: 16B single-store scatter records, 1024-block
// pass-1 (occupancy), 782 buckets (dst>>7) for pass-2 parallelism.
// N=100000, E=3200000, H=16. fp32 in/out; edge_index int32 rows [src | dst].
//
// ws (137.6 MB):
//   ebuf [E][16] bf16 (102.4M); build scratch aliases inside (dead before conv1):
//       brec16 [E] uint4 (51.2M) {u64(src:17,dst:17,eid:22), bf16 ea01, ea2},
//       hist [782][1024] int (3.2M), binsum[782], binbase[783]
//   srec [E] u64 (25.6M)  final dst-grouped records
//   Pa, Pc, xnbf [N][16] bf16 (9.6M)
// out_n region: start[N+1] int (dead before node_last writes out_n)
// out_e region: ea_s [E] 8B (25.6M) + agg [N][16] f32 (6.4M)
//   (dead before conv3's edge kernel writes out_e)

#define NN 100000
#define NE 3200000
#define NBKT 782          // ceil(NN/128)
#define BSHIFT 7
#define LMASK 127
#define NBLK1 1024        // pass-1 blocks
#define EPB1 3125         // NE / NBLK1 (exact)

__device__ __forceinline__ float bf2f(unsigned int h) {
    unsigned int u = h << 16;
    float f; __builtin_memcpy(&f, &u, 4); return f;
}
__device__ __forceinline__ unsigned short f2bf(float f) {
    unsigned int u; __builtin_memcpy(&u, &f, 4);
    u += 0x7fffu + ((u >> 16) & 1u);          // RNE
    return (unsigned short)(u >> 16);
}
__device__ __forceinline__ void ldbf16x16(const unsigned short* p, float* r) {
    const uint4* q = reinterpret_cast<const uint4*>(p);
    uint4 a = q[0], b = q[1];
    unsigned int w[8] = {a.x, a.y, a.z, a.w, b.x, b.y, b.z, b.w};
    #pragma unroll
    for (int k = 0; k < 8; ++k) {
        r[2*k]   = bf2f(w[k] & 0xffffu);
        r[2*k+1] = bf2f(w[k] >> 16);
    }
}
__device__ __forceinline__ void stbf16x16(unsigned short* p, const float* r) {
    unsigned int w[8];
    #pragma unroll
    for (int k = 0; k < 8; ++k)
        w[k] = (unsigned int)f2bf(r[2*k]) | ((unsigned int)f2bf(r[2*k+1]) << 16);
    uint4* q = reinterpret_cast<uint4*>(p);
    q[0] = make_uint4(w[0], w[1], w[2], w[3]);
    q[1] = make_uint4(w[4], w[5], w[6], w[7]);
}

// ---------------- build: two-level counting sort (no global atomics) ----------------

// pass-1 histogram: hist[bin][blk] = # edges of block blk with dst>>7 == bin
__global__ void khist1(const int* __restrict__ ei, int* __restrict__ hist) {
    __shared__ int h[NBKT];
    int blk = blockIdx.x, tid = threadIdx.x;
    for (int b = tid; b < NBKT; b += 256) h[b] = 0;
    __syncthreads();
    int e0 = blk * EPB1;
    for (int e = e0 + tid; e < e0 + EPB1; e += 256)
        atomicAdd(&h[ei[NE + e] >> BSHIFT], 1);     // LDS atomic
    __syncthreads();
    for (int b = tid; b < NBKT; b += 256) hist[b * NBLK1 + blk] = h[b];
}

// per-bin exclusive scan over the 1024 blocks; binsum[bin] = total
__global__ void kscan_a(int* __restrict__ hist, int* __restrict__ binsum) {
    __shared__ int s[NBLK1];
    int b = blockIdx.x, t = threadIdx.x;
    int v = hist[b * NBLK1 + t];
    s[t] = v; __syncthreads();
    for (int off = 1; off < NBLK1; off <<= 1) {
        int u = (t >= off) ? s[t - off] : 0;
        __syncthreads();
        s[t] += u;
        __syncthreads();
    }
    hist[b * NBLK1 + t] = s[t] - v;                 // exclusive within bin
    if (t == NBLK1 - 1) binsum[b] = s[t];
}

// exclusive scan over bins -> binbase[0..NBKT]; also start[NN] = NE
__global__ void kscan_b(const int* __restrict__ binsum, int* __restrict__ binbase,
                        int* __restrict__ start) {
    __shared__ int s[1024];
    int t = threadIdx.x;
    int v = (t < NBKT) ? binsum[t] : 0;
    s[t] = v; __syncthreads();
    for (int off = 1; off < 1024; off <<= 1) {
        int u = (t >= off) ? s[t - off] : 0;
        __syncthreads();
        s[t] += u;
        __syncthreads();
    }
    if (t < NBKT) binbase[t] = s[t] - v;
    if (t == NBKT - 1) binbase[NBKT] = s[t];        // == NE
    if (t == 0) start[NN] = NE;
}

// pass-1 scatter into coarse buckets: ONE 16B store per edge.
__global__ void kscatter1(const int* __restrict__ ei, const float* __restrict__ ea,
                          const int* __restrict__ hist, const int* __restrict__ binbase,
                          uint4* __restrict__ brec16) {
    __shared__ int cur[NBKT];
    int blk = blockIdx.x, tid = threadIdx.x;
    for (int b = tid; b < NBKT; b += 256)
        cur[b] = binbase[b] + hist[b * NBLK1 + blk];
    __syncthreads();
    int e0 = blk * EPB1;
    for (int e = e0 + tid; e < e0 + EPB1; e += 256) {
        int s = ei[e], d = ei[NE + e];
        float f0 = ea[(size_t)3*e], f1 = ea[(size_t)3*e+1], f2 = ea[(size_t)3*e+2];
        int pos = atomicAdd(&cur[d >> BSHIFT], 1);  // LDS atomic
        unsigned long long u = (unsigned long long)(unsigned int)s
                             | ((unsigned long long)(unsigned int)d << 17)
                             | ((unsigned long long)(unsigned int)e << 34);
        uint4 r;
        r.x = (unsigned int)u;
        r.y = (unsigned int)(u >> 32);
        r.z = (unsigned int)f2bf(f0) | ((unsigned int)f2bf(f1) << 16);
        r.w = (unsigned int)f2bf(f2);
        brec16[pos] = r;
    }
}

// pass-2: one block per bucket (128 nodes); count, scan, scatter to final
// dst-grouped srec/ea_s; emit CSR start[].
__global__ void kbucket(const uint4* __restrict__ brec16, const int* __restrict__ binbase,
                        unsigned long long* __restrict__ srec, unsigned int* __restrict__ ea_s,
                        int* __restrict__ start) {
    __shared__ int cnt[128];
    __shared__ int off[128];
    __shared__ int cur[128];
    int bkt = blockIdx.x, t = threadIdx.x;
    int base = binbase[bkt], end = binbase[bkt + 1];
    if (t < 128) cnt[t] = 0;
    __syncthreads();
    for (int j = base + t; j < end; j += 256) {
        uint4 r = brec16[j];
        int dl = (int)(((r.x >> 17) | (r.y << 15)) & 0x1FFFFu) & LMASK;
        atomicAdd(&cnt[dl], 1);
    }
    __syncthreads();
    if (t < 128) { off[t] = cnt[t]; }
    __syncthreads();
    for (int o = 1; o < 128; o <<= 1) {
        int u = (t < 128 && t >= o) ? off[t - o] : 0;
        __syncthreads();
        if (t < 128) off[t] += u;
        __syncthreads();
    }
    if (t < 128) {
        int excl = off[t] - cnt[t];
        int node = bkt * 128 + t;
        if (node < NN) start[node] = base + excl;
        cur[t] = base + excl;
    }
    __syncthreads();
    for (int j = base + t; j < end; j += 256) {
        uint4 r = brec16[j];
        int dl = (int)(((r.x >> 17) | (r.y << 15)) & 0x1FFFFu) & LMASK;
        int p = atomicAdd(&cur[dl], 1);
        srec[p] = (unsigned long long)r.x | ((unsigned long long)r.y << 32);
        *reinterpret_cast<uint2*>(&ea_s[(size_t)2*p]) = make_uint2(r.z, r.w);
    }
}

// ---------------- aggregations (CSR streaming) ----------------

// conv1: agg3[n] = sum relu(x[src]+ea); 4 threads/node interleaved + shfl reduce
__global__ void kagg3_s(const int* __restrict__ start, const unsigned long long* __restrict__ srec,
                        const unsigned int* __restrict__ ea_s,
                        const float* __restrict__ x, float* __restrict__ agg) {
    int t = blockIdx.x * blockDim.x + threadIdx.x;
    int n = t >> 2, q = t & 3;
    if (n >= NN) return;
    int j0 = start[n], j1 = start[n + 1];
    float a0 = 0.f, a1 = 0.f, a2 = 0.f;
    for (int j = j0 + q; j < j1; j += 4) {
        int s = (int)(srec[j] & 0x1FFFFu);
        uint2 w = *reinterpret_cast<const uint2*>(&ea_s[(size_t)2*j]);
        a0 += fmaxf(x[3*s  ] + bf2f(w.x & 0xffffu), 0.f);
        a1 += fmaxf(x[3*s+1] + bf2f(w.x >> 16),     0.f);
        a2 += fmaxf(x[3*s+2] + bf2f(w.y & 0xffffu), 0.f);
    }
    a0 += __shfl_xor(a0, 1); a0 += __shfl_xor(a0, 2);
    a1 += __shfl_xor(a1, 1); a1 += __shfl_xor(a1, 2);
    a2 += __shfl_xor(a2, 1); a2 += __shfl_xor(a2, 2);
    if (q == 0) {
        float* p = agg + (size_t)n*16;
        p[0] = a0; p[1] = a1; p[2] = a2;
    }
}

// conv2/3: 4 threads/node, 4 dims each, contiguous segment stream
__global__ void kagg16_s(const int* __restrict__ start, const unsigned long long* __restrict__ srec,
                         const unsigned short* __restrict__ ebuf,
                         const unsigned short* __restrict__ xnbf, float* __restrict__ agg) {
    int tg = blockIdx.x * blockDim.x + threadIdx.x;
    int n = tg >> 2, q = tg & 3;
    if (n >= NN) return;
    int j0 = start[n], j1 = start[n + 1];
    float a0 = 0.f, a1 = 0.f, a2 = 0.f, a3 = 0.f;
    for (int j = j0; j < j1; ++j) {
        int s = (int)(srec[j] & 0x1FFFFu);
        uint2 w  = *reinterpret_cast<const uint2*>(ebuf + (size_t)j*16 + q*4);
        uint2 xw = *reinterpret_cast<const uint2*>(xnbf + (size_t)s*16 + q*4);
        a0 += fmaxf(bf2f(xw.x & 0xffffu) + bf2f(w.x & 0xffffu), 0.f);
        a1 += fmaxf(bf2f(xw.x >> 16)     + bf2f(w.x >> 16),     0.f);
        a2 += fmaxf(bf2f(xw.y & 0xffffu) + bf2f(w.y & 0xffffu), 0.f);
        a3 += fmaxf(bf2f(xw.y >> 16)     + bf2f(w.y >> 16),     0.f);
    }
    *reinterpret_cast<float4*>(agg + (size_t)n*16 + q*4) = make_float4(a0, a1, a2, a3);
}

// ---------------- node-side kernels ----------------

__global__ void prep1(const float* __restrict__ x, const float* __restrict__ ew1,
                      unsigned short* __restrict__ Pa, unsigned short* __restrict__ Pc) {
    int n = blockIdx.x * blockDim.x + threadIdx.x;
    if (n >= NN) return;
    float x0 = x[3*n], x1 = x[3*n+1], x2 = x[3*n+2];
    float pa[16], pc[16];
    #pragma unroll
    for (int j = 0; j < 16; ++j) {
        pa[j] = x0*ew1[0*16+j] + x1*ew1[1*16+j] + x2*ew1[2*16+j];
        pc[j] = x0*ew1[6*16+j] + x1*ew1[7*16+j] + x2*ew1[8*16+j];
    }
    stbf16x16(Pa + (size_t)n*16, pa);
    stbf16x16(Pc + (size_t)n*16, pc);
}

__global__ void conv1_node(const float* __restrict__ agg, const float* __restrict__ x,
                           const float* __restrict__ nw1, const float* __restrict__ nb1,
                           const float* __restrict__ nw2, const float* __restrict__ nb2,
                           const float* __restrict__ next_ew1,
                           unsigned short* __restrict__ Pa, unsigned short* __restrict__ Pc,
                           unsigned short* __restrict__ xnbf) {
    int n = blockIdx.x * blockDim.x + threadIdx.x;
    if (n >= NN) return;
    float o0 = agg[(size_t)n*16+0] + x[3*n];
    float o1 = agg[(size_t)n*16+1] + x[3*n+1];
    float o2 = agg[(size_t)n*16+2] + x[3*n+2];
    float h[16];
    #pragma unroll
    for (int j = 0; j < 16; ++j)
        h[j] = fmaxf(nb1[j] + o0*nw1[0*16+j] + o1*nw1[1*16+j] + o2*nw1[2*16+j], 0.f);
    float xn[16];
    #pragma unroll
    for (int j = 0; j < 16; ++j) {
        float a = nb2[j];
        #pragma unroll
        for (int i = 0; i < 16; ++i) a = fmaf(h[i], nw2[i*16+j], a);
        xn[j] = fmaxf(a, 0.f);
    }
    float pa[16], pc[16];
    #pragma unroll
    for (int j = 0; j < 16; ++j) {
        float sa = 0.f, sc = 0.f;
        #pragma unroll
        for (int i = 0; i < 16; ++i) {
            sa = fmaf(xn[i], next_ew1[i*16+j], sa);
            sc = fmaf(xn[i], next_ew1[(32+i)*16+j], sc);
        }
        pa[j] = sa; pc[j] = sc;
    }
    stbf16x16(xnbf + (size_t)n*16, xn);
    stbf16x16(Pa + (size_t)n*16, pa);
    stbf16x16(Pc + (size_t)n*16, pc);
}

__global__ void node_mid(const float* __restrict__ agg,
                         const float* __restrict__ nw1, const float* __restrict__ nb1,
                         const float* __restrict__ nw2, const float* __restrict__ nb2,
                         const float* __restrict__ next_ew1,
                         unsigned short* __restrict__ Pa, unsigned short* __restrict__ Pc,
                         unsigned short* xnbf) {
    int n = blockIdx.x * blockDim.x + threadIdx.x;
    if (n >= NN) return;
    float o[16];
    ldbf16x16(xnbf + (size_t)n*16, o);
    #pragma unroll
    for (int j = 0; j < 16; ++j) o[j] += agg[(size_t)n*16 + j];
    float h[16];
    #pragma unroll
    for (int j = 0; j < 16; ++j) {
        float a = nb1[j];
        #pragma unroll
        for (int i = 0; i < 16; ++i) a = fmaf(o[i], nw1[i*16+j], a);
        h[j] = fmaxf(a, 0.f);
    }
    float xn[16];
    #pragma unroll
    for (int j = 0; j < 16; ++j) {
        float a = nb2[j];
        #pragma unroll
        for (int i = 0; i < 16; ++i) a = fmaf(h[i], nw2[i*16+j], a);
        xn[j] = fmaxf(a, 0.f);
    }
    float pa[16], pc[16];
    #pragma unroll
    for (int j = 0; j < 16; ++j) {
        float sa = 0.f, sc = 0.f;
        #pragma unroll
        for (int i = 0; i < 16; ++i) {
            sa = fmaf(xn[i], next_ew1[i*16+j], sa);
            sc = fmaf(xn[i], next_ew1[(32+i)*16+j], sc);
        }
        pa[j] = sa; pc[j] = sc;
    }
    stbf16x16(xnbf + (size_t)n*16, xn);
    stbf16x16(Pa + (size_t)n*16, pa);
    stbf16x16(Pc + (size_t)n*16, pc);
}

__global__ void node_last(const float* __restrict__ agg, const unsigned short* __restrict__ xnbf,
                          const float* __restrict__ nw1, const float* __restrict__ nb1,
                          const float* __restrict__ nw2, const float* __restrict__ nb2,
                          const float* __restrict__ hw1, const float* __restrict__ hb1,
                          const float* __restrict__ hw2, const float* __restrict__ hb2,
                          float* __restrict__ out_n) {
    int n = blockIdx.x * blockDim.x + threadIdx.x;
    if (n >= NN) return;
    float o[16];
    ldbf16x16(xnbf + (size_t)n*16, o);
    #pragma unroll
    for (int j = 0; j < 16; ++j) o[j] += agg[(size_t)n*16 + j];
    float h[16];
    #pragma unroll
    for (int j = 0; j < 16; ++j) {
        float a = nb1[j];
        #pragma unroll
        for (int i = 0; i < 16; ++i) a = fmaf(o[i], nw1[i*16+j], a);
        h[j] = fmaxf(a, 0.f);
    }
    float xn[16];
    #pragma unroll
    for (int j = 0; j < 16; ++j) {
        float a = nb2[j];
        #pragma unroll
        for (int i = 0; i < 16; ++i) a = fmaf(h[i], nw2[i*16+j], a);
        xn[j] = fmaxf(a, 0.f);
    }
    float g[16];
    #pragma unroll
    for (int j = 0; j < 16; ++j) {
        float a = hb1[j];
        #pragma unroll
        for (int i = 0; i < 16; ++i) a = fmaf(xn[i], hw1[i*16+j], a);
        g[j] = fmaxf(a, 0.f);
    }
    #pragma unroll
    for (int k = 0; k < 3; ++k) {
        float a = hb2[k];
        #pragma unroll
        for (int i = 0; i < 16; ++i) a = fmaf(g[i], hw2[i*3+k], a);
        out_n[(size_t)n*3 + k] = a;
    }
}

// ---------------- edge kernels (slot space, dst direct from srec) ----------------

__global__ void conv1_edge_s2(const unsigned long long* __restrict__ srec,
                              const unsigned int* __restrict__ ea_s,
                              const unsigned short* __restrict__ Pa, const unsigned short* __restrict__ Pc,
                              const float* __restrict__ ew1, const float* __restrict__ eb1,
                              const float* __restrict__ ew2, const float* __restrict__ eb2,
                              unsigned short* __restrict__ ebuf) {
    int j = blockIdx.x * blockDim.x + threadIdx.x;
    if (j >= NE) return;
    unsigned long long sr = srec[j];
    int s = (int)(sr & 0x1FFFFu);
    int t = (int)((sr >> 17) & 0x1FFFFu);
    uint2 wv = *reinterpret_cast<const uint2*>(&ea_s[(size_t)2*j]);
    float e0 = bf2f(wv.x & 0xffffu), e1 = bf2f(wv.x >> 16), e2 = bf2f(wv.y & 0xffffu);
    float h[16], pc[16];
    ldbf16x16(Pa + (size_t)s*16, h);
    ldbf16x16(Pc + (size_t)t*16, pc);
    #pragma unroll
    for (int jj = 0; jj < 16; ++jj) {
        float a = h[jj] + pc[jj] + eb1[jj]
                + e0*ew1[3*16+jj] + e1*ew1[4*16+jj] + e2*ew1[5*16+jj];
        h[jj] = fmaxf(a, 0.f);
    }
    float h2[16];
    #pragma unroll
    for (int jj = 0; jj < 16; ++jj) {
        float a = eb2[jj];
        #pragma unroll
        for (int i = 0; i < 16; ++i) a = fmaf(h[i], ew2[i*16+jj], a);
        h2[jj] = fmaxf(a, 0.f);
    }
    stbf16x16(ebuf + (size_t)j*16, h2);
}

template <bool LAST>
__global__ void conv_edge2(const unsigned long long* __restrict__ srec,
                           unsigned short* ebuf,          // in-place per slot
                           const unsigned short* __restrict__ Pa, const unsigned short* __restrict__ Pc,
                           const float* __restrict__ ew1, const float* __restrict__ eb1,
                           const float* __restrict__ ew2, const float* __restrict__ eb2,
                           const float* __restrict__ hw1, const float* __restrict__ hb1,
                           const float* __restrict__ hw2, const float* __restrict__ hb2,
                           float* __restrict__ out_e) {
    int j = blockIdx.x * blockDim.x + threadIdx.x;
    if (j >= NE) return;
    unsigned long long sr = srec[j];
    int s = (int)(sr & 0x1FFFFu);
    int t = (int)((sr >> 17) & 0x1FFFFu);
    float ein[16], h[16], pc[16];
    ldbf16x16(ebuf + (size_t)j*16, ein);
    ldbf16x16(Pa + (size_t)s*16, h);
    ldbf16x16(Pc + (size_t)t*16, pc);
    #pragma unroll
    for (int jj = 0; jj < 16; ++jj) h[jj] = h[jj] + pc[jj] + eb1[jj];
    #pragma unroll
    for (int i = 0; i < 16; ++i) {
        #pragma unroll
        for (int jj = 0; jj < 16; ++jj) h[jj] = fmaf(ein[i], ew1[(16+i)*16+jj], h[jj]);
    }
    #pragma unroll
    for (int jj = 0; jj < 16; ++jj) h[jj] = fmaxf(h[jj], 0.f);
    float h2[16];
    #pragma unroll
    for (int jj = 0; jj < 16; ++jj) {
        float a = eb2[jj];
        #pragma unroll
        for (int i = 0; i < 16; ++i) a = fmaf(h[i], ew2[i*16+jj], a);
        h2[jj] = fmaxf(a, 0.f);
    }
    if (!LAST) {
        stbf16x16(ebuf + (size_t)j*16, h2);
    } else {
        float g[16];
        #pragma unroll
        for (int jj = 0; jj < 16; ++jj) {
            float a = hb1[jj];
            #pragma unroll
            for (int i = 0; i < 16; ++i) a = fmaf(h2[i], hw1[i*16+jj], a);
            g[jj] = fmaxf(a, 0.f);
        }
        int e = (int)(sr >> 34);
        #pragma unroll
        for (int k = 0; k < 3; ++k) {
            float a = hb2[k];
            #pragma unroll
            for (int i = 0; i < 16; ++i) a = fmaf(g[i], hw2[i*3+k], a);
            out_e[(size_t)e*3 + k] = a;
        }
    }
}

extern "C" void kernel_launch(void* const* d_in, const int* in_sizes, int n_in,
                              void* d_out, int out_size, void* d_ws, size_t ws_size,
                              hipStream_t stream) {
    const float* x  = (const float*)d_in[0];
    const float* ea = (const float*)d_in[1];
    const int*   ei = (const int*)d_in[2];
    const float *c1_ew1 = (const float*)d_in[3],  *c1_eb1 = (const float*)d_in[4];
    const float *c1_ew2 = (const float*)d_in[5],  *c1_eb2 = (const float*)d_in[6];
    const float *c1_nw1 = (const float*)d_in[7],  *c1_nb1 = (const float*)d_in[8];
    const float *c1_nw2 = (const float*)d_in[9],  *c1_nb2 = (const float*)d_in[10];
    const float *c2_ew1 = (const float*)d_in[11], *c2_eb1 = (const float*)d_in[12];
    const float *c2_ew2 = (const float*)d_in[13], *c2_eb2 = (const float*)d_in[14];
    const float *c2_nw1 = (const float*)d_in[15], *c2_nb1 = (const float*)d_in[16];
    const float *c2_nw2 = (const float*)d_in[17], *c2_nb2 = (const float*)d_in[18];
    const float *c3_ew1 = (const float*)d_in[19], *c3_eb1 = (const float*)d_in[20];
    const float *c3_ew2 = (const float*)d_in[21], *c3_eb2 = (const float*)d_in[22];
    const float *c3_nw1 = (const float*)d_in[23], *c3_nb1 = (const float*)d_in[24];
    const float *c3_nw2 = (const float*)d_in[25], *c3_nb2 = (const float*)d_in[26];
    const float *node_w1 = (const float*)d_in[27], *node_b1 = (const float*)d_in[28];
    const float *node_w2 = (const float*)d_in[29], *node_b2 = (const float*)d_in[30];
    const float *edge_w1 = (const float*)d_in[31], *edge_b1 = (const float*)d_in[32];
    const float *edge_w2 = (const float*)d_in[33], *edge_b2 = (const float*)d_in[34];

    // ---- ws carve-up (137.6 MB) ----
    char* w = (char*)d_ws;
    unsigned short* ebuf = (unsigned short*)w;               // NE*32; build scratch aliases inside:
    uint4* brec16 = (uint4*)w;                               //   NE*16 = 51.2 MB
    int* hist   = (int*)(w + (size_t)NE*16);                 //   NBKT*NBLK1*4 = 3.2 MB
    int* binsum = hist + NBKT * NBLK1;                       //   782*4
    int* binbase = binsum + NBKT;                            //   783*4
    w += (size_t)NE * 32;
    unsigned long long* srec = (unsigned long long*)w;  w += (size_t)NE * 8;   // 25.6 MB
    unsigned short* Pa   = (unsigned short*)w;          w += (size_t)NN * 32;
    unsigned short* Pc   = (unsigned short*)w;          w += (size_t)NN * 32;
    unsigned short* xnbf = (unsigned short*)w;          w += (size_t)NN * 32;

    // ---- d_out overlays ----
    float* out_n = (float*)d_out;                      // N*3 floats (1.2 MB)
    float* out_e = out_n + (size_t)NN * 3;             // E*3 floats (38.4 MB)
    int* start = (int*)out_n;                          // (NN+1)*4, dead before node_last
    unsigned int* ea_s = (unsigned int*)out_e;                 // NE*8 = 25.6 MB
    float* agg = (float*)((char*)out_e + (size_t)NE * 8);      // N*16 f32 = 6.4 MB

    const int B = 256;
    const int gn = (NN + B - 1) / B;                 // 391
    const int ge = (NE + B - 1) / B;                 // 12500
    const int gq = (NN * 4 + B - 1) / B;             // 1563

    // ---- build (no global atomics) ----
    khist1<<<NBLK1, B, 0, stream>>>(ei, hist);
    kscan_a<<<NBKT, NBLK1, 0, stream>>>(hist, binsum);
    kscan_b<<<1, 1024, 0, stream>>>(binsum, binbase, start);
    kscatter1<<<NBLK1, B, 0, stream>>>(ei, ea, hist, binbase, brec16);
    kbucket<<<NBKT, B, 0, stream>>>(brec16, binbase, srec, ea_s, start);

    // ---- conv1 ----
    prep1<<<gn, B, 0, stream>>>(x, c1_ew1, Pa, Pc);
    kagg3_s<<<gq, B, 0, stream>>>(start, srec, ea_s, x, agg);
    conv1_edge_s2<<<ge, B, 0, stream>>>(srec, ea_s, Pa, Pc,
                                        c1_ew1, c1_eb1, c1_ew2, c1_eb2, ebuf);
    conv1_node<<<gn, B, 0, stream>>>(agg, x, c1_nw1, c1_nb1, c1_nw2, c1_nb2,
                                     c2_ew1, Pa, Pc, xnbf);
    // ---- conv2 ----
    kagg16_s<<<gq, B, 0, stream>>>(start, srec, ebuf, xnbf, agg);
    conv_edge2<false><<<ge, B, 0, stream>>>(srec, ebuf, Pa, Pc,
                                            c2_ew1, c2_eb1, c2_ew2, c2_eb2,
                                            nullptr, nullptr, nullptr, nullptr, nullptr);
    node_mid<<<gn, B, 0, stream>>>(agg, c2_nw1, c2_nb1, c2_nw2, c2_nb2,
                                   c3_ew1, Pa, Pc, xnbf);
    // ---- conv3 ----
    kagg16_s<<<gq, B, 0, stream>>>(start, srec, ebuf, xnbf, agg);
    node_last<<<gn, B, 0, stream>>>(agg, xnbf, c3_nw1, c3_nb1, c3_nw2, c3_nb2,
                                    node_w1, node_b1, node_w2, node_b2, out_n);
    conv_edge2<true><<<ge, B, 0, stream>>>(srec, ebuf, Pa, Pc,
                                           c3_ew1, c3_eb1, c3_ew2, c3_eb2,
                                           edge_w1, edge_b1, edge_w2, edge_b2, out_e);
}